// Round 1
// baseline (5369.743 us; speedup 1.0000x reference)
//
#include <hip/hip_runtime.h>
#include <hip/hip_bf16.h>
#include <stdint.h>

#define B_ 32
#define T_ 12
#define N_ 1024
#define D_ 64
#define F_ 16
#define KH_ 8
#define BT_ (B_*T_)
#define NROWS_ (BT_*N_)
#define K3_ 3072

typedef unsigned short u16;
struct __align__(8) u16x4 { u16 x, y, z, w; };

__device__ __forceinline__ float b2f(u16 u) {
  union { float f; unsigned int i; } c; c.i = ((unsigned int)u) << 16; return c.f;
}
__device__ __forceinline__ u16 f2b(float f) {
  union { float f; unsigned int i; } c; c.f = f;
  unsigned int u = c.i;
  unsigned int r = ((u >> 16) & 1u) + 0x7FFFu;
  return (u16)((u + r) >> 16);
}

// ---- K0: FEQ/FEK = relu(feat @ W) for both graphs. fe layout [4][1024][64]
__global__ void k_fe(const float* __restrict__ feat0, const float* __restrict__ feat1,
                     const float* __restrict__ Wq0, const float* __restrict__ Wk0,
                     const float* __restrict__ Wq1, const float* __restrict__ Wk1,
                     float* __restrict__ fe) {
  int r = blockIdx.x;
  int m = blockIdx.y;
  int d = threadIdx.x;
  const float* feat = (m < 2) ? feat0 : feat1;
  const float* W = (m == 0) ? Wq0 : (m == 1) ? Wk0 : (m == 2) ? Wq1 : Wk1;
  float acc = 0.f;
  #pragma unroll
  for (int f = 0; f < F_; ++f) acc += feat[r*F_ + f] * W[f*D_ + d];
  fe[((size_t)m*N_ + r)*D_ + d] = fmaxf(acc, 0.f);
}

// ---- K0b: copy adj into Acat[:, 0:1024] (f32)
__global__ void k_adjcopy(const float* __restrict__ adj, float* __restrict__ Acat) {
  int r = blockIdx.x;
  for (int c = threadIdx.x; c < N_; c += blockDim.x)
    Acat[(size_t)r*K3_ + c] = adj[(size_t)r*N_ + c];
}

// ---- K1: S_g = softmax(FEQ @ FEK^T / 8) rows -> Acat[:, 1024+g*1024 ...]
__global__ __launch_bounds__(256) void k_graph_softmax(const float* __restrict__ fe,
                                                       float* __restrict__ Acat) {
  int r = blockIdx.x, g = blockIdx.y;
  const float* FEQ = fe + (size_t)(g*2 + 0)*N_*D_;
  const float* FEK = fe + (size_t)(g*2 + 1)*N_*D_;
  __shared__ float q[D_];
  __shared__ float red[256];
  int tid = threadIdx.x;
  if (tid < D_) q[tid] = FEQ[(size_t)r*D_ + tid];
  __syncthreads();
  float lg[4];
  float mx = -1e30f;
  #pragma unroll
  for (int j = 0; j < 4; ++j) {
    int c = tid + j*256;
    const float* kr = FEK + (size_t)c*D_;
    float acc = 0.f;
    #pragma unroll
    for (int f = 0; f < D_; ++f) acc += q[f]*kr[f];
    lg[j] = acc * 0.125f;
    mx = fmaxf(mx, lg[j]);
  }
  red[tid] = mx; __syncthreads();
  for (int s = 128; s > 0; s >>= 1) { if (tid < s) red[tid] = fmaxf(red[tid], red[tid+s]); __syncthreads(); }
  mx = red[0]; __syncthreads();
  float sum = 0.f;
  #pragma unroll
  for (int j = 0; j < 4; ++j) { lg[j] = __expf(lg[j]-mx); sum += lg[j]; }
  red[tid] = sum; __syncthreads();
  for (int s = 128; s > 0; s >>= 1) { if (tid < s) red[tid] += red[tid+s]; __syncthreads(); }
  float inv = 1.f / red[0];
  #pragma unroll
  for (int j = 0; j < 4; ++j) {
    int c = tid + j*256;
    Acat[(size_t)r*K3_ + (1+g)*N_ + c] = lg[j]*inv;
  }
}

// ---- K2: [BTN,64] @ Wbig[64,256] -> planes G0 (->HS buf), Y1, Y2, Y3 (bf16)
// Wbig[k][c] = Wgcn[(c>>6)*64 + k][c&63]
__global__ __launch_bounds__(256) void k_xw(
    const float* __restrict__ X, const float* __restrict__ Wgcn,
    u16* __restrict__ G0, u16* __restrict__ Y1, u16* __restrict__ Y2, u16* __restrict__ Y3)
{
  __shared__ float Als[64][65];
  __shared__ float Wls[64][128];
  int t = threadIdx.x;
  int r0 = blockIdx.x * 64;
  int c0 = blockIdx.y * 128;
  #pragma unroll
  for (int i = 0; i < 16; ++i) {
    int idx = t + 256*i;
    int m = idx >> 6, k = idx & 63;
    Als[m][k] = X[(size_t)(r0+m)*64 + k];
  }
  #pragma unroll
  for (int i = 0; i < 32; ++i) {
    int idx = t + 256*i;
    int k = idx >> 7, cc = idx & 127;
    int c = c0 + cc;
    Wls[k][cc] = Wgcn[(size_t)((c >> 6)*64 + k)*64 + (c & 63)];
  }
  __syncthreads();
  int tx = t & 31, ty = t >> 5;
  float acc[8][4] = {};
  #pragma unroll
  for (int k = 0; k < 64; ++k) {
    float4 bv = *(const float4*)&Wls[k][tx*4];
    #pragma unroll
    for (int i = 0; i < 8; ++i) {
      float a = Als[ty*8+i][k];
      acc[i][0] += a*bv.x; acc[i][1] += a*bv.y; acc[i][2] += a*bv.z; acc[i][3] += a*bv.w;
    }
  }
  int c = c0 + tx*4;
  int p = c >> 6, d0 = c & 63;
  u16* dp = (p == 0) ? G0 : (p == 1) ? Y1 : (p == 2) ? Y2 : Y3;
  #pragma unroll
  for (int i = 0; i < 8; ++i) {
    size_t rn = (size_t)r0 + ty*8 + i;
    u16x4 pk{ f2b(acc[i][0]), f2b(acc[i][1]), f2b(acc[i][2]), f2b(acc[i][3]) };
    *(u16x4*)&dp[rn*64 + d0] = pk;
  }
}

// ---- K3: per-bt Z = Acat[1024,3072] @ Ystack[3072,64]; HS = relu(Z + G0 + bgcn)
__global__ __launch_bounds__(256) void k_spatial(
    const float* __restrict__ Acat,
    const u16* __restrict__ Y1, const u16* __restrict__ Y2, const u16* __restrict__ Y3,
    const float* __restrict__ bgcn,
    u16* __restrict__ HS)   // in: G0; out: HS
{
  __shared__ float Als[128][33];
  __shared__ float Bls[32][64];
  int t = threadIdx.x;
  int m0 = blockIdx.x * 128;
  int bt = blockIdx.y;
  int tx = t & 15, ty = t >> 4;
  float acc[8][4] = {};
  for (int k0 = 0; k0 < K3_; k0 += 32) {
    #pragma unroll
    for (int i = 0; i < 16; ++i) {
      int idx = t + 256*i;
      int r = idx >> 5, c = idx & 31;
      Als[r][c] = Acat[(size_t)(m0 + r)*K3_ + k0 + c];
    }
    int pl = k0 >> 10;
    const u16* Yb = ((pl == 0) ? Y1 : (pl == 1) ? Y2 : Y3)
                    + (size_t)bt*N_*64 + (size_t)(k0 & 1023)*64;
    #pragma unroll
    for (int i = 0; i < 8; ++i) {
      int idx = t + 256*i;
      int r = idx >> 6, c = idx & 63;
      Bls[r][c] = b2f(Yb[r*64 + c]);
    }
    __syncthreads();
    #pragma unroll
    for (int kk = 0; kk < 32; ++kk) {
      float4 bv = *(const float4*)&Bls[kk][tx*4];
      #pragma unroll
      for (int i = 0; i < 8; ++i) {
        float a = Als[ty*8+i][kk];
        acc[i][0] += a*bv.x; acc[i][1] += a*bv.y; acc[i][2] += a*bv.z; acc[i][3] += a*bv.w;
      }
    }
    __syncthreads();
  }
  size_t rowbase = (size_t)bt*N_ + m0;
  int d0 = tx*4;
  #pragma unroll
  for (int i = 0; i < 8; ++i) {
    size_t rn = rowbase + ty*8 + i;
    u16x4 g = *(const u16x4*)&HS[rn*64 + d0];
    float v0 = acc[i][0] + b2f(g.x) + bgcn[d0+0];
    float v1 = acc[i][1] + b2f(g.y) + bgcn[d0+1];
    float v2 = acc[i][2] + b2f(g.z) + bgcn[d0+2];
    float v3 = acc[i][3] + b2f(g.w) + bgcn[d0+3];
    u16x4 pk{ f2b(fmaxf(v0,0.f)), f2b(fmaxf(v1,0.f)), f2b(fmaxf(v2,0.f)), f2b(fmaxf(v3,0.f)) };
    *(u16x4*)&HS[rn*64 + d0] = pk;
  }
}

// ---- K4: fused temporal attention + HT = relu(o@Wx1+bx1)@Wx2+bx2, one block per (b,n)
__global__ __launch_bounds__(768) void k_attn(
    const float* __restrict__ X, const float* __restrict__ STE,
    const float* __restrict__ Wq, const float* __restrict__ bq,
    const float* __restrict__ Wk, const float* __restrict__ bk,
    const float* __restrict__ Wv, const float* __restrict__ bv,
    const float* __restrict__ Wx1, const float* __restrict__ bx1,
    const float* __restrict__ Wx2, const float* __restrict__ bx2,
    u16* __restrict__ HT)
{
  int n = blockIdx.x, b = blockIdx.y;
  __shared__ float xc[T_][128];
  __shared__ float qs[T_][64], ks[T_][64], vs[T_][64];
  __shared__ float att[KH_][T_][T_];
  __shared__ float h1s[T_][64];
  int t = threadIdx.x;
  int tt = t >> 6, d = t & 63;
  {
    size_t base = ((size_t)(b*T_ + tt)*N_ + n)*64;
    xc[tt][d]      = X[base + d];
    xc[tt][64 + d] = STE[base + d];
  }
  __syncthreads();
  {
    float aq = bq[d], ak = bk[d], av = bv[d];
    for (int k = 0; k < 128; ++k) {
      float x = xc[tt][k];
      aq += x * Wq[k*64 + d];
      ak += x * Wk[k*64 + d];
      av += x * Wv[k*64 + d];
    }
    qs[tt][d] = fmaxf(aq, 0.f);
    ks[tt][d] = fmaxf(ak, 0.f);
    vs[tt][d] = fmaxf(av, 0.f);
  }
  __syncthreads();
  for (int idx = t; idx < KH_*T_*T_; idx += 768) {
    int h = idx / (T_*T_); int rt = (idx / T_) % T_; int s = idx % T_;
    float a = 0.f;
    #pragma unroll
    for (int e = 0; e < 8; ++e) a += qs[rt][h*8+e]*ks[s][h*8+e];
    att[h][rt][s] = a * 0.3535533906f;  // 1/sqrt(8)
  }
  __syncthreads();
  if (t < KH_*T_) {
    int h = t / T_, rt = t % T_;
    float mx = -1e30f;
    #pragma unroll
    for (int s = 0; s < T_; ++s) mx = fmaxf(mx, att[h][rt][s]);
    float sum = 0.f;
    float e_[T_];
    #pragma unroll
    for (int s = 0; s < T_; ++s) { e_[s] = __expf(att[h][rt][s]-mx); sum += e_[s]; }
    float inv = 1.f/sum;
    #pragma unroll
    for (int s = 0; s < T_; ++s) att[h][rt][s] = e_[s]*inv;
  }
  __syncthreads();
  float o = 0.f;
  {
    int h = d >> 3;
    #pragma unroll
    for (int s = 0; s < T_; ++s) o += att[h][tt][s]*vs[s][d];
  }
  __syncthreads();
  qs[tt][d] = o;   // reuse qs as o-storage (qs dead since pre-softmax barrier)
  __syncthreads();
  float a1 = bx1[d];
  for (int k = 0; k < 64; ++k) a1 += qs[tt][k]*Wx1[k*64 + d];
  h1s[tt][d] = fmaxf(a1, 0.f);
  __syncthreads();
  float a2 = bx2[d];
  for (int k = 0; k < 64; ++k) a2 += h1s[tt][k]*Wx2[k*64 + d];
  HT[((size_t)(b*T_ + tt)*N_ + n)*64 + d] = f2b(a2);
}

// ---- K5: gated fusion + output head, 4 rows per 256-thread block
__global__ __launch_bounds__(256) void k_fusion(
    const float* __restrict__ X, const u16* __restrict__ HS, const u16* __restrict__ HT,
    const float* __restrict__ Ws, const float* __restrict__ Wt, const float* __restrict__ btb,
    const float* __restrict__ Wh1, const float* __restrict__ bh1,
    const float* __restrict__ Wh2, const float* __restrict__ bh2,
    float* __restrict__ out)
{
  __shared__ float hs[4][64], ht[4][64], hh[4][64], h2[4][64];
  int t = threadIdx.x; int r = t >> 6, d = t & 63;
  size_t row = (size_t)blockIdx.x*4 + r;
  size_t gi = row*64 + d;
  float hsv = b2f(HS[gi]), htv = b2f(HT[gi]);
  hs[r][d] = hsv; ht[r][d] = htv;
  __syncthreads();
  float a_s = btb[d];
  for (int k = 0; k < 64; ++k) a_s += hs[r][k]*Ws[k*64+d] + ht[r][k]*Wt[k*64+d];
  float zg = 1.f/(1.f + __expf(-a_s));
  float H = zg*hsv + (1.f - zg)*htv;
  hh[r][d] = H;
  __syncthreads();
  float a1 = bh1[d];
  for (int k = 0; k < 64; ++k) a1 += hh[r][k]*Wh1[k*64+d];
  h2[r][d] = fmaxf(a1, 0.f);
  __syncthreads();
  float a2 = bh2[d];
  for (int k = 0; k < 64; ++k) a2 += h2[r][k]*Wh2[k*64+d];
  out[gi] = X[gi] + a2;
}

extern "C" void kernel_launch(void* const* d_in, const int* in_sizes, int n_in,
                              void* d_out, int out_size, void* d_ws, size_t ws_size,
                              hipStream_t stream) {
  const float* X    = (const float*)d_in[0];
  const float* STE  = (const float*)d_in[1];
  const float* adj  = (const float*)d_in[2];
  const float* feat0= (const float*)d_in[3];
  const float* feat1= (const float*)d_in[4];
  const float* Wq0  = (const float*)d_in[5];
  const float* Wk0  = (const float*)d_in[6];
  const float* Wq1  = (const float*)d_in[7];
  const float* Wk1  = (const float*)d_in[8];
  const float* Wgcn = (const float*)d_in[9];
  const float* bgcn = (const float*)d_in[10];
  const float* Wq   = (const float*)d_in[11];
  const float* bq   = (const float*)d_in[12];
  const float* Wk   = (const float*)d_in[13];
  const float* bk   = (const float*)d_in[14];
  const float* Wv   = (const float*)d_in[15];
  const float* bv   = (const float*)d_in[16];
  const float* Wx1  = (const float*)d_in[17];
  const float* bx1  = (const float*)d_in[18];
  const float* Wx2  = (const float*)d_in[19];
  const float* bx2  = (const float*)d_in[20];
  const float* Ws   = (const float*)d_in[21];
  const float* Wt   = (const float*)d_in[22];
  const float* btb  = (const float*)d_in[23];
  const float* Wh1  = (const float*)d_in[24];
  const float* bh1  = (const float*)d_in[25];
  const float* Wh2  = (const float*)d_in[26];
  const float* bh2  = (const float*)d_in[27];
  (void)in_sizes; (void)n_in; (void)out_size;

  // ws layout (bytes):
  //   fe    @ 0         : 4*1024*64*4   = 1,048,576
  //   Acat  @ 1,048,576 : 1024*3072*4   = 12,582,912
  //   Y2    @ 13,631,488: 384*1024*64*2 = 50,331,648
  //   Y3    @ 63,963,136: 50,331,648
  //   HS/G0 @114,294,784: 50,331,648     (total 164,626,432)
  //   HT reuses Y2's slot (Y2 dead after k_spatial); Y1 lives in d_out (dead before k_fusion).
  const size_t NEEDED = 164626432ull;
  if (ws_size < NEEDED) return;  // fail loudly (output stays poisoned) rather than corrupt

  char* w = (char*)d_ws;
  float* fe   = (float*)(w);
  float* Acat = (float*)(w + 1048576);
  u16*   Y2   = (u16*)(w + 13631488);
  u16*   Y3   = (u16*)(w + 63963136);
  u16*   HSb  = (u16*)(w + 114294784);
  u16*   HTb  = Y2;
  u16*   Y1   = (u16*)d_out;

  k_fe<<<dim3(N_, 4), 64, 0, stream>>>(feat0, feat1, Wq0, Wk0, Wq1, Wk1, fe);
  k_adjcopy<<<N_, 256, 0, stream>>>(adj, Acat);
  k_graph_softmax<<<dim3(N_, 2), 256, 0, stream>>>(fe, Acat);
  k_xw<<<dim3(NROWS_/64, 2), 256, 0, stream>>>(X, Wgcn, HSb, Y1, Y2, Y3);
  k_spatial<<<dim3(N_/128, BT_), 256, 0, stream>>>(Acat, Y1, Y2, Y3, bgcn, HSb);
  k_attn<<<dim3(N_, B_), 768, 0, stream>>>(X, STE, Wq, bq, Wk, bk, Wv, bv,
                                           Wx1, bx1, Wx2, bx2, HTb);
  k_fusion<<<NROWS_/4, 256, 0, stream>>>(X, HSb, HTb, Ws, Wt, btb, Wh1, bh1, Wh2, bh2,
                                         (float*)d_out);
}

// Round 2
// 3387.910 us; speedup vs baseline: 1.5850x; 1.5850x over previous
//
#include <hip/hip_runtime.h>
#include <hip/hip_bf16.h>
#include <stdint.h>

#define B_ 32
#define T_ 12
#define N_ 1024
#define D_ 64
#define F_ 16
#define KH_ 8
#define BT_ (B_*T_)
#define NROWS_ (BT_*N_)
#define K3_ 3072

typedef unsigned short u16;
struct __align__(8) u16x4 { u16 x, y, z, w; };
typedef __attribute__((ext_vector_type(8))) short short8v;
typedef __attribute__((ext_vector_type(4))) float f32x4;

__device__ __forceinline__ float b2f(u16 u) {
  union { float f; unsigned int i; } c; c.i = ((unsigned int)u) << 16; return c.f;
}
__device__ __forceinline__ u16 f2b(float f) {
  union { float f; unsigned int i; } c; c.f = f;
  unsigned int u = c.i;
  unsigned int r = ((u >> 16) & 1u) + 0x7FFFu;
  return (u16)((u + r) >> 16);
}

__device__ __forceinline__ void gload_lds16(const void* g, void* l) {
  __builtin_amdgcn_global_load_lds(
      (const __attribute__((address_space(1))) unsigned int*)g,
      (__attribute__((address_space(3))) unsigned int*)l, 16, 0, 0);
}

// ---- K0: FEQ/FEK = relu(feat @ W) for both graphs. fe layout [4][1024][64]
__global__ void k_fe(const float* __restrict__ feat0, const float* __restrict__ feat1,
                     const float* __restrict__ Wq0, const float* __restrict__ Wk0,
                     const float* __restrict__ Wq1, const float* __restrict__ Wk1,
                     float* __restrict__ fe) {
  int r = blockIdx.x;
  int m = blockIdx.y;
  int d = threadIdx.x;
  const float* feat = (m < 2) ? feat0 : feat1;
  const float* W = (m == 0) ? Wq0 : (m == 1) ? Wk0 : (m == 2) ? Wq1 : Wk1;
  float acc = 0.f;
  #pragma unroll
  for (int f = 0; f < F_; ++f) acc += feat[r*F_ + f] * W[f*D_ + d];
  fe[((size_t)m*N_ + r)*D_ + d] = fmaxf(acc, 0.f);
}

// ---- K0b: copy adj into Acat[:, 0:1024] (bf16)
__global__ void k_adjcopy(const float* __restrict__ adj, u16* __restrict__ Acat) {
  int r = blockIdx.x;
  for (int c = threadIdx.x; c < N_; c += blockDim.x)
    Acat[(size_t)r*K3_ + c] = f2b(adj[(size_t)r*N_ + c]);
}

// ---- K1: S_g = softmax(FEQ @ FEK^T / 8) rows -> Acat[:, 1024+g*1024 ...] (bf16)
__global__ __launch_bounds__(256) void k_graph_softmax(const float* __restrict__ fe,
                                                       u16* __restrict__ Acat) {
  int r = blockIdx.x, g = blockIdx.y;
  const float* FEQ = fe + (size_t)(g*2 + 0)*N_*D_;
  const float* FEK = fe + (size_t)(g*2 + 1)*N_*D_;
  __shared__ float q[D_];
  __shared__ float red[256];
  int tid = threadIdx.x;
  if (tid < D_) q[tid] = FEQ[(size_t)r*D_ + tid];
  __syncthreads();
  float lg[4];
  float mx = -1e30f;
  #pragma unroll
  for (int j = 0; j < 4; ++j) {
    int c = tid + j*256;
    const float* kr = FEK + (size_t)c*D_;
    float acc = 0.f;
    #pragma unroll
    for (int f = 0; f < D_; ++f) acc += q[f]*kr[f];
    lg[j] = acc * 0.125f;
    mx = fmaxf(mx, lg[j]);
  }
  red[tid] = mx; __syncthreads();
  for (int s = 128; s > 0; s >>= 1) { if (tid < s) red[tid] = fmaxf(red[tid], red[tid+s]); __syncthreads(); }
  mx = red[0]; __syncthreads();
  float sum = 0.f;
  #pragma unroll
  for (int j = 0; j < 4; ++j) { lg[j] = __expf(lg[j]-mx); sum += lg[j]; }
  red[tid] = sum; __syncthreads();
  for (int s = 128; s > 0; s >>= 1) { if (tid < s) red[tid] += red[tid+s]; __syncthreads(); }
  float inv = 1.f / red[0];
  #pragma unroll
  for (int j = 0; j < 4; ++j) {
    int c = tid + j*256;
    Acat[(size_t)r*K3_ + (1+g)*N_ + c] = f2b(lg[j]*inv);
  }
}

// ---- K2: [BTN,64] @ Wbig[64,256] -> G0 (row-major, ->HS buf) + Yt1..3 (TRANSPOSED [bt][d][node], bf16)
// Wbig[k][c] = Wgcn[(c>>6)*64 + k][c&63]
__global__ __launch_bounds__(256) void k_xw(
    const float* __restrict__ X, const float* __restrict__ Wgcn,
    u16* __restrict__ G0, u16* __restrict__ Yt1, u16* __restrict__ Yt2, u16* __restrict__ Yt3)
{
  __shared__ float Als[64][65];
  __shared__ float Wls[64][128];
  int t = threadIdx.x;
  int r0 = blockIdx.x * 64;        // flat row base; 64 | 1024 so one bt per block
  int c0 = blockIdx.y * 128;
  #pragma unroll
  for (int i = 0; i < 16; ++i) {
    int idx = t + 256*i;
    int m = idx >> 6, k = idx & 63;
    Als[m][k] = X[(size_t)(r0+m)*64 + k];
  }
  #pragma unroll
  for (int i = 0; i < 32; ++i) {
    int idx = t + 256*i;
    int k = idx >> 7, cc = idx & 127;
    int c = c0 + cc;
    Wls[k][cc] = Wgcn[(size_t)((c >> 6)*64 + k)*64 + (c & 63)];
  }
  __syncthreads();
  int tx = t & 31, ty = t >> 5;
  float acc[8][4] = {};
  #pragma unroll
  for (int k = 0; k < 64; ++k) {
    float4 bv = *(const float4*)&Wls[k][tx*4];
    #pragma unroll
    for (int i = 0; i < 8; ++i) {
      float a = Als[ty*8+i][k];
      acc[i][0] += a*bv.x; acc[i][1] += a*bv.y; acc[i][2] += a*bv.z; acc[i][3] += a*bv.w;
    }
  }
  int c = c0 + tx*4;
  int p = c >> 6, d0 = c & 63;
  if (p == 0) {
    #pragma unroll
    for (int i = 0; i < 8; ++i) {
      size_t rn = (size_t)r0 + ty*8 + i;
      u16x4 pk{ f2b(acc[i][0]), f2b(acc[i][1]), f2b(acc[i][2]), f2b(acc[i][3]) };
      *(u16x4*)&G0[rn*64 + d0] = pk;
    }
  } else {
    u16* Yt = (p == 1) ? Yt1 : (p == 2) ? Yt2 : Yt3;
    int bt = r0 >> 10;
    int n0 = (r0 & 1023) + ty*8;
    #pragma unroll
    for (int jj = 0; jj < 4; ++jj) {
      int d = d0 + jj;
      u16x4 lo{ f2b(acc[0][jj]), f2b(acc[1][jj]), f2b(acc[2][jj]), f2b(acc[3][jj]) };
      u16x4 hi{ f2b(acc[4][jj]), f2b(acc[5][jj]), f2b(acc[6][jj]), f2b(acc[7][jj]) };
      *(u16x4*)&Yt[((size_t)bt*64 + d)*1024 + n0]     = lo;
      *(u16x4*)&Yt[((size_t)bt*64 + d)*1024 + n0 + 4] = hi;
    }
  }
}

// ---- K3 (MFMA): per bt-pair, C[128 node,128 (2bt x 64 d)] = Acat[128,3072] @ Bstack
// HS = relu(C + G0 + bgcn). A linear LDS + pre-swizzled-global source, XOR-swizzled reads.
#define BM 128
#define BK 64
#define NKT (K3_/BK)   // 48
__global__ __launch_bounds__(256) void k_spatial_mfma(
    const u16* __restrict__ Acat,
    const u16* __restrict__ Yt1, const u16* __restrict__ Yt2, const u16* __restrict__ Yt3,
    const float* __restrict__ bgcn,
    u16* __restrict__ HS)   // in: G0; out: HS
{
  __shared__ __align__(16) u16 Als[2][BM*BK];   // [row 0..127][k 0..63], chunk-swizzled
  __shared__ __align__(16) u16 Bls[2][BM*BK];   // B^T tile: [n 0..127][k 0..63], chunk-swizzled

  // XCD-aware swizzle: all 8 m-tiles of one bt-pair on one XCD (B-panel L2 reuse)
  int f = blockIdx.x + 8*blockIdx.y;   // 0..1535
  int u = f & 7, v = f >> 3;           // u ~ XCD, v 0..191
  int btp = u*24 + (v >> 3);           // 0..191
  int m0  = (v & 7) * BM;              // node tile base
  int bt0 = btp * 2;

  int t = threadIdx.x;
  int w = t >> 6, l = t & 63;
  int rsub = l >> 3, pch = l & 7;

  f32x4 acc[4][4] = {};
  int wm = w >> 1, wn = w & 1;
  int lr = l & 15, lk = l >> 4;

  // ---- prologue stage (kt = 0)
  {
    #pragma unroll
    for (int i = 0; i < 4; ++i) {
      int R0 = w*32 + i*8;
      int row = R0 + rsub;
      int q = pch ^ (row & 7);
      gload_lds16(Acat + (size_t)(m0 + row)*K3_ + q*8, &Als[0][R0*64]);
    }
    const u16* Yt = Yt1;   // k0 = 0 -> plane 0
    #pragma unroll
    for (int i = 0; i < 4; ++i) {
      int R0 = w*32 + i*8;
      int n = R0 + rsub;
      int q = pch ^ (n & 7);
      int bt = bt0 + (n >> 6), d = n & 63;
      gload_lds16(Yt + ((size_t)bt*64 + d)*1024 + q*8, &Bls[0][R0*64]);
    }
  }
  __syncthreads();

  int buf = 0;
  for (int kt = 0; kt < NKT; ++kt) {
    // ---- stage next K-slice into buf^1
    if (kt + 1 < NKT) {
      int k0 = (kt + 1) * BK;
      #pragma unroll
      for (int i = 0; i < 4; ++i) {
        int R0 = w*32 + i*8;
        int row = R0 + rsub;
        int q = pch ^ (row & 7);
        gload_lds16(Acat + (size_t)(m0 + row)*K3_ + k0 + q*8, &Als[buf^1][R0*64]);
      }
      int pl = k0 >> 10, kk = k0 & 1023;
      const u16* Yt = (pl == 0) ? Yt1 : (pl == 1) ? Yt2 : Yt3;
      #pragma unroll
      for (int i = 0; i < 4; ++i) {
        int R0 = w*32 + i*8;
        int n = R0 + rsub;
        int q = pch ^ (n & 7);
        int bt = bt0 + (n >> 6), d = n & 63;
        gload_lds16(Yt + ((size_t)bt*64 + d)*1024 + kk + q*8, &Bls[buf^1][R0*64]);
      }
    }
    // ---- compute on buf
    const u16* A = &Als[buf][0];
    const u16* Bp = &Bls[buf][0];
    #pragma unroll
    for (int ks = 0; ks < 2; ++ks) {
      short8v av[4], bv[4];
      #pragma unroll
      for (int fm = 0; fm < 4; ++fm) {
        int r = wm*64 + fm*16 + lr;
        int p = (ks*4 + lk) ^ (r & 7);
        av[fm] = *(const short8v*)(A + r*64 + p*8);
      }
      #pragma unroll
      for (int fn = 0; fn < 4; ++fn) {
        int r = wn*64 + fn*16 + lr;
        int p = (ks*4 + lk) ^ (r & 7);
        bv[fn] = *(const short8v*)(Bp + r*64 + p*8);
      }
      #pragma unroll
      for (int fm = 0; fm < 4; ++fm)
        #pragma unroll
        for (int fn = 0; fn < 4; ++fn)
          acc[fm][fn] = __builtin_amdgcn_mfma_f32_16x16x32_bf16(av[fm], bv[fn], acc[fm][fn], 0, 0, 0);
    }
    __syncthreads();
    buf ^= 1;
  }

  // ---- epilogue: HS = relu(acc + G0 + bgcn)   (C/D: col=lane&15, row=(lane>>4)*4+j)
  #pragma unroll
  for (int fm = 0; fm < 4; ++fm) {
    int nodeb = m0 + wm*64 + fm*16 + lk*4;
    #pragma unroll
    for (int fn = 0; fn < 4; ++fn) {
      int nl = wn*64 + fn*16 + lr;
      int bt = bt0 + (nl >> 6), d = nl & 63;
      float bb = bgcn[d];
      size_t base = (size_t)bt * N_ * 64;
      #pragma unroll
      for (int j = 0; j < 4; ++j) {
        size_t idx = base + (size_t)(nodeb + j)*64 + d;
        float vv = acc[fm][fn][j] + b2f(HS[idx]) + bb;
        HS[idx] = f2b(fmaxf(vv, 0.f));
      }
    }
  }
}

// ---- K4: fused temporal attention + HT = relu(o@Wx1+bx1)@Wx2+bx2, one block per (b,n)
__global__ __launch_bounds__(768) void k_attn(
    const float* __restrict__ X, const float* __restrict__ STE,
    const float* __restrict__ Wq, const float* __restrict__ bq,
    const float* __restrict__ Wk, const float* __restrict__ bk,
    const float* __restrict__ Wv, const float* __restrict__ bv,
    const float* __restrict__ Wx1, const float* __restrict__ bx1,
    const float* __restrict__ Wx2, const float* __restrict__ bx2,
    u16* __restrict__ HT)
{
  int n = blockIdx.x, b = blockIdx.y;
  __shared__ float xc[T_][128];
  __shared__ float qs[T_][64], ks[T_][64], vs[T_][64];
  __shared__ float att[KH_][T_][T_];
  __shared__ float h1s[T_][64];
  int t = threadIdx.x;
  int tt = t >> 6, d = t & 63;
  {
    size_t base = ((size_t)(b*T_ + tt)*N_ + n)*64;
    xc[tt][d]      = X[base + d];
    xc[tt][64 + d] = STE[base + d];
  }
  __syncthreads();
  {
    float aq = bq[d], ak = bk[d], av = bv[d];
    for (int k = 0; k < 128; ++k) {
      float x = xc[tt][k];
      aq += x * Wq[k*64 + d];
      ak += x * Wk[k*64 + d];
      av += x * Wv[k*64 + d];
    }
    qs[tt][d] = fmaxf(aq, 0.f);
    ks[tt][d] = fmaxf(ak, 0.f);
    vs[tt][d] = fmaxf(av, 0.f);
  }
  __syncthreads();
  for (int idx = t; idx < KH_*T_*T_; idx += 768) {
    int h = idx / (T_*T_); int rt = (idx / T_) % T_; int s = idx % T_;
    float a = 0.f;
    #pragma unroll
    for (int e = 0; e < 8; ++e) a += qs[rt][h*8+e]*ks[s][h*8+e];
    att[h][rt][s] = a * 0.3535533906f;  // 1/sqrt(8)
  }
  __syncthreads();
  if (t < KH_*T_) {
    int h = t / T_, rt = t % T_;
    float mx = -1e30f;
    #pragma unroll
    for (int s = 0; s < T_; ++s) mx = fmaxf(mx, att[h][rt][s]);
    float sum = 0.f;
    float e_[T_];
    #pragma unroll
    for (int s = 0; s < T_; ++s) { e_[s] = __expf(att[h][rt][s]-mx); sum += e_[s]; }
    float inv = 1.f/sum;
    #pragma unroll
    for (int s = 0; s < T_; ++s) att[h][rt][s] = e_[s]*inv;
  }
  __syncthreads();
  float o = 0.f;
  {
    int h = d >> 3;
    #pragma unroll
    for (int s = 0; s < T_; ++s) o += att[h][tt][s]*vs[s][d];
  }
  __syncthreads();
  qs[tt][d] = o;   // reuse qs as o-storage
  __syncthreads();
  float a1 = bx1[d];
  for (int k = 0; k < 64; ++k) a1 += qs[tt][k]*Wx1[k*64 + d];
  h1s[tt][d] = fmaxf(a1, 0.f);
  __syncthreads();
  float a2 = bx2[d];
  for (int k = 0; k < 64; ++k) a2 += h1s[tt][k]*Wx2[k*64 + d];
  HT[((size_t)(b*T_ + tt)*N_ + n)*64 + d] = f2b(a2);
}

// ---- K5: gated fusion + output head, 4 rows per 256-thread block
__global__ __launch_bounds__(256) void k_fusion(
    const float* __restrict__ X, const u16* __restrict__ HS, const u16* __restrict__ HT,
    const float* __restrict__ Ws, const float* __restrict__ Wt, const float* __restrict__ btb,
    const float* __restrict__ Wh1, const float* __restrict__ bh1,
    const float* __restrict__ Wh2, const float* __restrict__ bh2,
    float* __restrict__ out)
{
  __shared__ float hs[4][64], ht[4][64], hh[4][64], h2[4][64];
  int t = threadIdx.x; int r = t >> 6, d = t & 63;
  size_t row = (size_t)blockIdx.x*4 + r;
  size_t gi = row*64 + d;
  float hsv = b2f(HS[gi]), htv = b2f(HT[gi]);
  hs[r][d] = hsv; ht[r][d] = htv;
  __syncthreads();
  float a_s = btb[d];
  for (int k = 0; k < 64; ++k) a_s += hs[r][k]*Ws[k*64+d] + ht[r][k]*Wt[k*64+d];
  float zg = 1.f/(1.f + __expf(-a_s));
  float H = zg*hsv + (1.f - zg)*htv;
  hh[r][d] = H;
  __syncthreads();
  float a1 = bh1[d];
  for (int k = 0; k < 64; ++k) a1 += hh[r][k]*Wh1[k*64+d];
  h2[r][d] = fmaxf(a1, 0.f);
  __syncthreads();
  float a2 = bh2[d];
  for (int k = 0; k < 64; ++k) a2 += h2[r][k]*Wh2[k*64+d];
  out[gi] = X[gi] + a2;
}

extern "C" void kernel_launch(void* const* d_in, const int* in_sizes, int n_in,
                              void* d_out, int out_size, void* d_ws, size_t ws_size,
                              hipStream_t stream) {
  const float* X    = (const float*)d_in[0];
  const float* STE  = (const float*)d_in[1];
  const float* adj  = (const float*)d_in[2];
  const float* feat0= (const float*)d_in[3];
  const float* feat1= (const float*)d_in[4];
  const float* Wq0  = (const float*)d_in[5];
  const float* Wk0  = (const float*)d_in[6];
  const float* Wq1  = (const float*)d_in[7];
  const float* Wk1  = (const float*)d_in[8];
  const float* Wgcn = (const float*)d_in[9];
  const float* bgcn = (const float*)d_in[10];
  const float* Wq   = (const float*)d_in[11];
  const float* bq   = (const float*)d_in[12];
  const float* Wk   = (const float*)d_in[13];
  const float* bk   = (const float*)d_in[14];
  const float* Wv   = (const float*)d_in[15];
  const float* bv   = (const float*)d_in[16];
  const float* Wx1  = (const float*)d_in[17];
  const float* bx1  = (const float*)d_in[18];
  const float* Wx2  = (const float*)d_in[19];
  const float* bx2  = (const float*)d_in[20];
  const float* Ws   = (const float*)d_in[21];
  const float* Wt   = (const float*)d_in[22];
  const float* btb  = (const float*)d_in[23];
  const float* Wh1  = (const float*)d_in[24];
  const float* bh1  = (const float*)d_in[25];
  const float* Wh2  = (const float*)d_in[26];
  const float* bh2  = (const float*)d_in[27];
  (void)in_sizes; (void)n_in; (void)out_size;

  // ws layout (bytes):
  //   fe    @ 0         : 4*1024*64*4   = 1,048,576
  //   Acat  @ 1,048,576 : 1024*3072*2   = 6,291,456 (bf16)
  //   Yt2   @ 13,631,488: 384*64*1024*2 = 50,331,648 (transposed plane)
  //   Yt3   @ 63,963,136: 50,331,648
  //   HS/G0 @114,294,784: 50,331,648     (total 164,626,432)
  //   HT reuses Yt2's slot (dead after k_spatial); Yt1 lives in d_out (dead before k_fusion).
  const size_t NEEDED = 164626432ull;
  if (ws_size < NEEDED) return;  // fail loudly rather than corrupt

  char* w = (char*)d_ws;
  float* fe   = (float*)(w);
  u16*   Acat = (u16*)(w + 1048576);
  u16*   Yt2  = (u16*)(w + 13631488);
  u16*   Yt3  = (u16*)(w + 63963136);
  u16*   HSb  = (u16*)(w + 114294784);
  u16*   HTb  = Yt2;
  u16*   Yt1  = (u16*)d_out;

  k_fe<<<dim3(N_, 4), 64, 0, stream>>>(feat0, feat1, Wq0, Wk0, Wq1, Wk1, fe);
  k_adjcopy<<<N_, 256, 0, stream>>>(adj, Acat);
  k_graph_softmax<<<dim3(N_, 2), 256, 0, stream>>>(fe, Acat);
  k_xw<<<dim3(NROWS_/64, 2), 256, 0, stream>>>(X, Wgcn, HSb, Yt1, Yt2, Yt3);
  k_spatial_mfma<<<dim3(8, BT_/2), 256, 0, stream>>>(Acat, Yt1, Yt2, Yt3, bgcn, HSb);
  k_attn<<<dim3(N_, B_), 768, 0, stream>>>(X, STE, Wq, bq, Wk, bk, Wv, bv,
                                           Wx1, bx1, Wx2, bx2, HTb);
  k_fusion<<<NROWS_/4, 256, 0, stream>>>(X, HSb, HTb, Ws, Wt, btb, Wh1, bh1, Wh2, bh2,
                                         (float*)d_out);
}

// Round 3
// 1935.998 us; speedup vs baseline: 2.7736x; 1.7500x over previous
//
#include <hip/hip_runtime.h>
#include <hip/hip_bf16.h>
#include <stdint.h>

#define B_ 32
#define T_ 12
#define N_ 1024
#define D_ 64
#define F_ 16
#define KH_ 8
#define BT_ (B_*T_)
#define NROWS_ (BT_*N_)
#define K3_ 3072

typedef unsigned short u16;
struct __align__(8) u16x4 { u16 x, y, z, w; };
struct __align__(16) u16x8 { u16 v[8]; };
typedef __attribute__((ext_vector_type(8))) short short8v;
typedef __attribute__((ext_vector_type(4))) float f32x4;

__device__ __forceinline__ float b2f(u16 u) {
  union { float f; unsigned int i; } c; c.i = ((unsigned int)u) << 16; return c.f;
}
__device__ __forceinline__ u16 f2b(float f) {
  union { float f; unsigned int i; } c; c.f = f;
  unsigned int u = c.i;
  unsigned int r = ((u >> 16) & 1u) + 0x7FFFu;
  return (u16)((u + r) >> 16);
}

__device__ __forceinline__ void gload_lds16(const void* g, void* l) {
  __builtin_amdgcn_global_load_lds(
      (const __attribute__((address_space(1))) unsigned int*)g,
      (__attribute__((address_space(3))) unsigned int*)l, 16, 0, 0);
}

// ---- K0: FEQ/FEK = relu(feat @ W) for both graphs. fe layout [4][1024][64]
__global__ void k_fe(const float* __restrict__ feat0, const float* __restrict__ feat1,
                     const float* __restrict__ Wq0, const float* __restrict__ Wk0,
                     const float* __restrict__ Wq1, const float* __restrict__ Wk1,
                     float* __restrict__ fe) {
  int r = blockIdx.x;
  int m = blockIdx.y;
  int d = threadIdx.x;
  const float* feat = (m < 2) ? feat0 : feat1;
  const float* W = (m == 0) ? Wq0 : (m == 1) ? Wk0 : (m == 2) ? Wq1 : Wk1;
  float acc = 0.f;
  #pragma unroll
  for (int f = 0; f < F_; ++f) acc += feat[r*F_ + f] * W[f*D_ + d];
  fe[((size_t)m*N_ + r)*D_ + d] = fmaxf(acc, 0.f);
}

// ---- K0b: copy adj into Acat[:, 0:1024] (bf16)
__global__ void k_adjcopy(const float* __restrict__ adj, u16* __restrict__ Acat) {
  int r = blockIdx.x;
  for (int c = threadIdx.x; c < N_; c += blockDim.x)
    Acat[(size_t)r*K3_ + c] = f2b(adj[(size_t)r*N_ + c]);
}

// ---- K0c: transpose small weights to bf16 [n][k] layouts for MFMA B-operands
__global__ void k_prep(const float* __restrict__ Wq, const float* __restrict__ Wk,
                       const float* __restrict__ Wv,
                       const float* __restrict__ Wx1, const float* __restrict__ Wx2,
                       u16* __restrict__ Wqkvt, u16* __restrict__ W1t, u16* __restrict__ W2t) {
  int t = threadIdx.x;
  for (int i = t; i < 192*128; i += 256) {
    int nn = i >> 7, kk = i & 127;
    const float* W = (nn < 64) ? Wq : (nn < 128) ? Wk : Wv;
    Wqkvt[i] = f2b(W[kk*64 + (nn & 63)]);
  }
  for (int i = t; i < 64*64; i += 256) {
    int nn = i >> 6, kk = i & 63;
    W1t[i] = f2b(Wx1[kk*64 + nn]);
    W2t[i] = f2b(Wx2[kk*64 + nn]);
  }
}

// ---- K1: S_g = softmax(FEQ @ FEK^T / 8) rows -> Acat[:, 1024+g*1024 ...] (bf16)
__global__ __launch_bounds__(256) void k_graph_softmax(const float* __restrict__ fe,
                                                       u16* __restrict__ Acat) {
  int r = blockIdx.x, g = blockIdx.y;
  const float* FEQ = fe + (size_t)(g*2 + 0)*N_*D_;
  const float* FEK = fe + (size_t)(g*2 + 1)*N_*D_;
  __shared__ float q[D_];
  __shared__ float red[256];
  int tid = threadIdx.x;
  if (tid < D_) q[tid] = FEQ[(size_t)r*D_ + tid];
  __syncthreads();
  float lg[4];
  float mx = -1e30f;
  #pragma unroll
  for (int j = 0; j < 4; ++j) {
    int c = tid + j*256;
    const float* kr = FEK + (size_t)c*D_;
    float acc = 0.f;
    #pragma unroll
    for (int f = 0; f < D_; ++f) acc += q[f]*kr[f];
    lg[j] = acc * 0.125f;
    mx = fmaxf(mx, lg[j]);
  }
  red[tid] = mx; __syncthreads();
  for (int s = 128; s > 0; s >>= 1) { if (tid < s) red[tid] = fmaxf(red[tid], red[tid+s]); __syncthreads(); }
  mx = red[0]; __syncthreads();
  float sum = 0.f;
  #pragma unroll
  for (int j = 0; j < 4; ++j) { lg[j] = __expf(lg[j]-mx); sum += lg[j]; }
  red[tid] = sum; __syncthreads();
  for (int s = 128; s > 0; s >>= 1) { if (tid < s) red[tid] += red[tid+s]; __syncthreads(); }
  float inv = 1.f / red[0];
  #pragma unroll
  for (int j = 0; j < 4; ++j) {
    int c = tid + j*256;
    Acat[(size_t)r*K3_ + (1+g)*N_ + c] = f2b(lg[j]*inv);
  }
}

// ---- K2: [BTN,64] @ Wbig[64,256] -> G0 (row-major, ->HS buf) + Yt1..3 (TRANSPOSED [bt][d][node], bf16)
__global__ __launch_bounds__(256) void k_xw(
    const float* __restrict__ X, const float* __restrict__ Wgcn,
    u16* __restrict__ G0, u16* __restrict__ Yt1, u16* __restrict__ Yt2, u16* __restrict__ Yt3)
{
  __shared__ float Als[64][65];
  __shared__ float Wls[64][128];
  int t = threadIdx.x;
  int r0 = blockIdx.x * 64;
  int c0 = blockIdx.y * 128;
  #pragma unroll
  for (int i = 0; i < 16; ++i) {
    int idx = t + 256*i;
    int m = idx >> 6, k = idx & 63;
    Als[m][k] = X[(size_t)(r0+m)*64 + k];
  }
  #pragma unroll
  for (int i = 0; i < 32; ++i) {
    int idx = t + 256*i;
    int k = idx >> 7, cc = idx & 127;
    int c = c0 + cc;
    Wls[k][cc] = Wgcn[(size_t)((c >> 6)*64 + k)*64 + (c & 63)];
  }
  __syncthreads();
  int tx = t & 31, ty = t >> 5;
  float acc[8][4] = {};
  #pragma unroll
  for (int k = 0; k < 64; ++k) {
    float4 bv = *(const float4*)&Wls[k][tx*4];
    #pragma unroll
    for (int i = 0; i < 8; ++i) {
      float a = Als[ty*8+i][k];
      acc[i][0] += a*bv.x; acc[i][1] += a*bv.y; acc[i][2] += a*bv.z; acc[i][3] += a*bv.w;
    }
  }
  int c = c0 + tx*4;
  int p = c >> 6, d0 = c & 63;
  if (p == 0) {
    #pragma unroll
    for (int i = 0; i < 8; ++i) {
      size_t rn = (size_t)r0 + ty*8 + i;
      u16x4 pk{ f2b(acc[i][0]), f2b(acc[i][1]), f2b(acc[i][2]), f2b(acc[i][3]) };
      *(u16x4*)&G0[rn*64 + d0] = pk;
    }
  } else {
    u16* Yt = (p == 1) ? Yt1 : (p == 2) ? Yt2 : Yt3;
    int bt = r0 >> 10;
    int n0 = (r0 & 1023) + ty*8;
    #pragma unroll
    for (int jj = 0; jj < 4; ++jj) {
      int d = d0 + jj;
      u16x4 lo{ f2b(acc[0][jj]), f2b(acc[1][jj]), f2b(acc[2][jj]), f2b(acc[3][jj]) };
      u16x4 hi{ f2b(acc[4][jj]), f2b(acc[5][jj]), f2b(acc[6][jj]), f2b(acc[7][jj]) };
      *(u16x4*)&Yt[((size_t)bt*64 + d)*1024 + n0]     = lo;
      *(u16x4*)&Yt[((size_t)bt*64 + d)*1024 + n0 + 4] = hi;
    }
  }
}

// ---- K3 (MFMA): per bt-pair, C[128 node,128 (2bt x 64 d)] = Acat[128,3072] @ Bstack
#define BM 128
#define BK 64
#define NKT (K3_/BK)   // 48
__global__ __launch_bounds__(256) void k_spatial_mfma(
    const u16* __restrict__ Acat,
    const u16* __restrict__ Yt1, const u16* __restrict__ Yt2, const u16* __restrict__ Yt3,
    const float* __restrict__ bgcn,
    u16* __restrict__ HS)
{
  __shared__ __align__(16) u16 Als[2][BM*BK];
  __shared__ __align__(16) u16 Bls[2][BM*BK];

  int f = blockIdx.x + 8*blockIdx.y;
  int u = f & 7, v = f >> 3;
  int btp = u*24 + (v >> 3);
  int m0  = (v & 7) * BM;
  int bt0 = btp * 2;

  int t = threadIdx.x;
  int w = t >> 6, l = t & 63;
  int rsub = l >> 3, pch = l & 7;

  f32x4 acc[4][4] = {};
  int wm = w >> 1, wn = w & 1;
  int lr = l & 15, lk = l >> 4;

  {
    #pragma unroll
    for (int i = 0; i < 4; ++i) {
      int R0 = w*32 + i*8;
      int row = R0 + rsub;
      int q = pch ^ (row & 7);
      gload_lds16(Acat + (size_t)(m0 + row)*K3_ + q*8, &Als[0][R0*64]);
    }
    const u16* Yt = Yt1;
    #pragma unroll
    for (int i = 0; i < 4; ++i) {
      int R0 = w*32 + i*8;
      int n = R0 + rsub;
      int q = pch ^ (n & 7);
      int bt = bt0 + (n >> 6), d = n & 63;
      gload_lds16(Yt + ((size_t)bt*64 + d)*1024 + q*8, &Bls[0][R0*64]);
    }
  }
  __syncthreads();

  int buf = 0;
  for (int kt = 0; kt < NKT; ++kt) {
    if (kt + 1 < NKT) {
      int k0 = (kt + 1) * BK;
      #pragma unroll
      for (int i = 0; i < 4; ++i) {
        int R0 = w*32 + i*8;
        int row = R0 + rsub;
        int q = pch ^ (row & 7);
        gload_lds16(Acat + (size_t)(m0 + row)*K3_ + k0 + q*8, &Als[buf^1][R0*64]);
      }
      int pl = k0 >> 10, kk = k0 & 1023;
      const u16* Yt = (pl == 0) ? Yt1 : (pl == 1) ? Yt2 : Yt3;
      #pragma unroll
      for (int i = 0; i < 4; ++i) {
        int R0 = w*32 + i*8;
        int n = R0 + rsub;
        int q = pch ^ (n & 7);
        int bt = bt0 + (n >> 6), d = n & 63;
        gload_lds16(Yt + ((size_t)bt*64 + d)*1024 + kk + q*8, &Bls[buf^1][R0*64]);
      }
    }
    const u16* A = &Als[buf][0];
    const u16* Bp = &Bls[buf][0];
    #pragma unroll
    for (int ks = 0; ks < 2; ++ks) {
      short8v av[4], bv[4];
      #pragma unroll
      for (int fm = 0; fm < 4; ++fm) {
        int r = wm*64 + fm*16 + lr;
        int p = (ks*4 + lk) ^ (r & 7);
        av[fm] = *(const short8v*)(A + r*64 + p*8);
      }
      #pragma unroll
      for (int fn = 0; fn < 4; ++fn) {
        int r = wn*64 + fn*16 + lr;
        int p = (ks*4 + lk) ^ (r & 7);
        bv[fn] = *(const short8v*)(Bp + r*64 + p*8);
      }
      #pragma unroll
      for (int fm = 0; fm < 4; ++fm)
        #pragma unroll
        for (int fn = 0; fn < 4; ++fn)
          acc[fm][fn] = __builtin_amdgcn_mfma_f32_16x16x32_bf16(av[fm], bv[fn], acc[fm][fn], 0, 0, 0);
    }
    __syncthreads();
    buf ^= 1;
  }

  #pragma unroll
  for (int fm = 0; fm < 4; ++fm) {
    int nodeb = m0 + wm*64 + fm*16 + lk*4;
    #pragma unroll
    for (int fn = 0; fn < 4; ++fn) {
      int nl = wn*64 + fn*16 + lr;
      int bt = bt0 + (nl >> 6), d = nl & 63;
      float bb = bgcn[d];
      size_t base = (size_t)bt * N_ * 64;
      #pragma unroll
      for (int j = 0; j < 4; ++j) {
        size_t idx = base + (size_t)(nodeb + j)*64 + d;
        float vv = acc[fm][fn][j] + b2f(HS[idx]) + bb;
        HS[idx] = f2b(fmaxf(vv, 0.f));
      }
    }
  }
}

// ---- K4a (MFMA): qkv = relu([X|STE] @ Wqkv^T + b) -> q,k,v bf16 [BTN][64]
__global__ __launch_bounds__(256) void k_qkv(
    const float* __restrict__ X, const float* __restrict__ STE,
    const u16* __restrict__ Wqkvt,
    const float* __restrict__ bq, const float* __restrict__ bk, const float* __restrict__ bv,
    u16* __restrict__ qb, u16* __restrict__ kb, u16* __restrict__ vb)
{
  __shared__ __align__(16) u16 Als[128*128];   // [row][k], chunk-swizzled
  __shared__ __align__(16) u16 Bls[192*128];   // W^T [n][k], chunk-swizzled
  int m0 = blockIdx.x * 128;
  int t = threadIdx.x;
  int w = t >> 6, l = t & 63;

  // stage B (weights) via global_load_lds, pre-swizzled source
  {
    int rsub = l >> 4, pch = l & 15;
    #pragma unroll
    for (int i = 0; i < 12; ++i) {
      int R0 = w*48 + i*4;
      int n = R0 + rsub;
      int sq = pch ^ (n & 7);
      gload_lds16(Wqkvt + (size_t)n*128 + sq*8, &Bls[R0*128]);
    }
  }
  // stage A: f32 [X|STE] -> bf16, swizzled ds_write
  #pragma unroll
  for (int i = 0; i < 8; ++i) {
    int flat = t + 256*i;
    int row = flat >> 4, c = flat & 15;
    const float* src = ((c < 8) ? X : STE) + (size_t)(m0+row)*64 + (c & 7)*8;
    float4 f0 = *(const float4*)src;
    float4 f1 = *(const float4*)(src + 4);
    u16x8 pk;
    pk.v[0]=f2b(f0.x); pk.v[1]=f2b(f0.y); pk.v[2]=f2b(f0.z); pk.v[3]=f2b(f0.w);
    pk.v[4]=f2b(f1.x); pk.v[5]=f2b(f1.y); pk.v[6]=f2b(f1.z); pk.v[7]=f2b(f1.w);
    int cs = c ^ (row & 7);
    *(u16x8*)&Als[row*128 + cs*8] = pk;
  }
  __syncthreads();

  int wm = w >> 1, wn = w & 1;
  int lr = l & 15, lk = l >> 4;
  f32x4 acc[4][6] = {};
  #pragma unroll
  for (int ks = 0; ks < 4; ++ks) {
    short8v av[4], bvv[6];
    #pragma unroll
    for (int fm = 0; fm < 4; ++fm) {
      int r = wm*64 + fm*16 + lr;
      int ch = (ks*4 + lk) ^ (r & 7);
      av[fm] = *(const short8v*)&Als[r*128 + ch*8];
    }
    #pragma unroll
    for (int fn = 0; fn < 6; ++fn) {
      int n = wn*96 + fn*16 + lr;
      int ch = (ks*4 + lk) ^ (n & 7);
      bvv[fn] = *(const short8v*)&Bls[n*128 + ch*8];
    }
    #pragma unroll
    for (int fm = 0; fm < 4; ++fm)
      #pragma unroll
      for (int fn = 0; fn < 6; ++fn)
        acc[fm][fn] = __builtin_amdgcn_mfma_f32_16x16x32_bf16(av[fm], bvv[fn], acc[fm][fn], 0, 0, 0);
  }

  // epilogue: bias + relu -> bf16 planes
  #pragma unroll
  for (int fm = 0; fm < 4; ++fm) {
    int rowb = m0 + wm*64 + fm*16 + lk*4;
    #pragma unroll
    for (int fn = 0; fn < 6; ++fn) {
      int col = wn*96 + fn*16 + lr;
      int sel = col >> 6, d = col & 63;
      u16* dst = (sel == 0) ? qb : (sel == 1) ? kb : vb;
      float bias = ((sel == 0) ? bq : (sel == 1) ? bk : bv)[d];
      #pragma unroll
      for (int j = 0; j < 4; ++j) {
        float val = acc[fm][fn][j] + bias;
        dst[(size_t)(rowb + j)*64 + d] = f2b(fmaxf(val, 0.f));
      }
    }
  }
}

// ---- K4b: attention only, one wave per (b,n), all-register, shuffle reduce
__global__ __launch_bounds__(256) void k_attn_lite(
    const u16* __restrict__ qb, const u16* __restrict__ kb, const u16* __restrict__ vb,
    u16* __restrict__ ob)
{
  int w = threadIdx.x >> 6, l = threadIdx.x & 63;
  int flat = blockIdx.x*4 + w;
  int b = flat >> 10, n = flat & 1023;
  float qv[T_], kv[T_], vv[T_];
  #pragma unroll
  for (int tt = 0; tt < T_; ++tt) {
    size_t idx = ((size_t)(b*T_ + tt)*N_ + n)*64 + l;
    qv[tt] = b2f(qb[idx]); kv[tt] = b2f(kb[idx]); vv[tt] = b2f(vb[idx]);
  }
  #pragma unroll
  for (int tt = 0; tt < T_; ++tt) {
    float sc[T_];
    float mx = -1e30f;
    #pragma unroll
    for (int j = 0; j < T_; ++j) {
      float p = qv[tt]*kv[j];
      p += __shfl_xor(p, 1);
      p += __shfl_xor(p, 2);
      p += __shfl_xor(p, 4);
      sc[j] = p * 0.3535533906f;
      mx = fmaxf(mx, sc[j]);
    }
    float sum = 0.f;
    #pragma unroll
    for (int j = 0; j < T_; ++j) { sc[j] = __expf(sc[j]-mx); sum += sc[j]; }
    float o = 0.f;
    #pragma unroll
    for (int j = 0; j < T_; ++j) o += sc[j]*vv[j];
    ob[((size_t)(b*T_ + tt)*N_ + n)*64 + l] = f2b(o / sum);
  }
}

// ---- K4c (MFMA): HT = relu(o@Wx1+bx1)@Wx2+bx2, chained in LDS
__global__ __launch_bounds__(256) void k_ht(
    const u16* __restrict__ ob, const u16* __restrict__ W1t, const u16* __restrict__ W2t,
    const float* __restrict__ bx1, const float* __restrict__ bx2,
    u16* __restrict__ HT)
{
  __shared__ __align__(16) u16 Ols[128*64];
  __shared__ __align__(16) u16 W1ls[64*64];
  __shared__ __align__(16) u16 W2ls[64*64];
  __shared__ __align__(16) u16 H1ls[128*64];
  int m0 = blockIdx.x * 128;
  int t = threadIdx.x;
  int w = t >> 6, l = t & 63;
  int rsub = l >> 3, pch = l & 7;

  #pragma unroll
  for (int i = 0; i < 4; ++i) {
    int R0 = w*32 + i*8;
    int row = R0 + rsub;
    int sq = pch ^ (row & 7);
    gload_lds16(ob + (size_t)(m0 + row)*64 + sq*8, &Ols[R0*64]);
  }
  #pragma unroll
  for (int i = 0; i < 2; ++i) {
    int R0 = w*16 + i*8;
    int row = R0 + rsub;
    int sq = pch ^ (row & 7);
    gload_lds16(W1t + (size_t)row*64 + sq*8, &W1ls[R0*64]);
    gload_lds16(W2t + (size_t)row*64 + sq*8, &W2ls[R0*64]);
  }
  __syncthreads();

  int wm = w >> 1, wn = w & 1;
  int lr = l & 15, lk = l >> 4;
  f32x4 acc1[4][2] = {};
  #pragma unroll
  for (int ks = 0; ks < 2; ++ks) {
    short8v av[4], bvv[2];
    #pragma unroll
    for (int fm = 0; fm < 4; ++fm) {
      int r = wm*64 + fm*16 + lr;
      int ch = (ks*4 + lk) ^ (r & 7);
      av[fm] = *(const short8v*)&Ols[r*64 + ch*8];
    }
    #pragma unroll
    for (int fn = 0; fn < 2; ++fn) {
      int n = wn*32 + fn*16 + lr;
      int ch = (ks*4 + lk) ^ (n & 7);
      bvv[fn] = *(const short8v*)&W1ls[n*64 + ch*8];
    }
    #pragma unroll
    for (int fm = 0; fm < 4; ++fm)
      #pragma unroll
      for (int fn = 0; fn < 2; ++fn)
        acc1[fm][fn] = __builtin_amdgcn_mfma_f32_16x16x32_bf16(av[fm], bvv[fn], acc1[fm][fn], 0, 0, 0);
  }
  // H1 = relu(acc1 + bx1) -> LDS (swizzled scalar writes)
  #pragma unroll
  for (int fm = 0; fm < 4; ++fm) {
    #pragma unroll
    for (int fn = 0; fn < 2; ++fn) {
      int col = wn*32 + fn*16 + lr;
      float bias = bx1[col];
      #pragma unroll
      for (int j = 0; j < 4; ++j) {
        int row = wm*64 + fm*16 + lk*4 + j;
        float val = acc1[fm][fn][j] + bias;
        H1ls[row*64 + (((col >> 3) ^ (row & 7)))*8 + (col & 7)] = f2b(fmaxf(val, 0.f));
      }
    }
  }
  __syncthreads();

  f32x4 acc2[4][2] = {};
  #pragma unroll
  for (int ks = 0; ks < 2; ++ks) {
    short8v av[4], bvv[2];
    #pragma unroll
    for (int fm = 0; fm < 4; ++fm) {
      int r = wm*64 + fm*16 + lr;
      int ch = (ks*4 + lk) ^ (r & 7);
      av[fm] = *(const short8v*)&H1ls[r*64 + ch*8];
    }
    #pragma unroll
    for (int fn = 0; fn < 2; ++fn) {
      int n = wn*32 + fn*16 + lr;
      int ch = (ks*4 + lk) ^ (n & 7);
      bvv[fn] = *(const short8v*)&W2ls[n*64 + ch*8];
    }
    #pragma unroll
    for (int fm = 0; fm < 4; ++fm)
      #pragma unroll
      for (int fn = 0; fn < 2; ++fn)
        acc2[fm][fn] = __builtin_amdgcn_mfma_f32_16x16x32_bf16(av[fm], bvv[fn], acc2[fm][fn], 0, 0, 0);
  }
  #pragma unroll
  for (int fm = 0; fm < 4; ++fm) {
    #pragma unroll
    for (int fn = 0; fn < 2; ++fn) {
      int col = wn*32 + fn*16 + lr;
      float bias = bx2[col];
      #pragma unroll
      for (int j = 0; j < 4; ++j) {
        int row = wm*64 + fm*16 + lk*4 + j;
        HT[(size_t)(m0 + row)*64 + col] = f2b(acc2[fm][fn][j] + bias);
      }
    }
  }
}

// ---- K5: gated fusion + output head, 4 rows per 256-thread block
__global__ __launch_bounds__(256) void k_fusion(
    const float* __restrict__ X, const u16* __restrict__ HS, const u16* __restrict__ HT,
    const float* __restrict__ Ws, const float* __restrict__ Wt, const float* __restrict__ btb,
    const float* __restrict__ Wh1, const float* __restrict__ bh1,
    const float* __restrict__ Wh2, const float* __restrict__ bh2,
    float* __restrict__ out)
{
  __shared__ float hs[4][64], ht[4][64], hh[4][64], h2[4][64];
  int t = threadIdx.x; int r = t >> 6, d = t & 63;
  size_t row = (size_t)blockIdx.x*4 + r;
  size_t gi = row*64 + d;
  float hsv = b2f(HS[gi]), htv = b2f(HT[gi]);
  hs[r][d] = hsv; ht[r][d] = htv;
  __syncthreads();
  float a_s = btb[d];
  for (int k = 0; k < 64; ++k) a_s += hs[r][k]*Ws[k*64+d] + ht[r][k]*Wt[k*64+d];
  float zg = 1.f/(1.f + __expf(-a_s));
  float H = zg*hsv + (1.f - zg)*htv;
  hh[r][d] = H;
  __syncthreads();
  float a1 = bh1[d];
  for (int k = 0; k < 64; ++k) a1 += hh[r][k]*Wh1[k*64+d];
  h2[r][d] = fmaxf(a1, 0.f);
  __syncthreads();
  float a2 = bh2[d];
  for (int k = 0; k < 64; ++k) a2 += h2[r][k]*Wh2[k*64+d];
  out[gi] = X[gi] + a2;
}

extern "C" void kernel_launch(void* const* d_in, const int* in_sizes, int n_in,
                              void* d_out, int out_size, void* d_ws, size_t ws_size,
                              hipStream_t stream) {
  const float* X    = (const float*)d_in[0];
  const float* STE  = (const float*)d_in[1];
  const float* adj  = (const float*)d_in[2];
  const float* feat0= (const float*)d_in[3];
  const float* feat1= (const float*)d_in[4];
  const float* Wq0  = (const float*)d_in[5];
  const float* Wk0  = (const float*)d_in[6];
  const float* Wq1  = (const float*)d_in[7];
  const float* Wk1  = (const float*)d_in[8];
  const float* Wgcn = (const float*)d_in[9];
  const float* bgcn = (const float*)d_in[10];
  const float* Wq   = (const float*)d_in[11];
  const float* bq   = (const float*)d_in[12];
  const float* Wk   = (const float*)d_in[13];
  const float* bk   = (const float*)d_in[14];
  const float* Wv   = (const float*)d_in[15];
  const float* bv   = (const float*)d_in[16];
  const float* Wx1  = (const float*)d_in[17];
  const float* bx1  = (const float*)d_in[18];
  const float* Wx2  = (const float*)d_in[19];
  const float* bx2  = (const float*)d_in[20];
  const float* Ws   = (const float*)d_in[21];
  const float* Wt   = (const float*)d_in[22];
  const float* btb  = (const float*)d_in[23];
  const float* Wh1  = (const float*)d_in[24];
  const float* bh1  = (const float*)d_in[25];
  const float* Wh2  = (const float*)d_in[26];
  const float* bh2  = (const float*)d_in[27];
  (void)in_sizes; (void)n_in; (void)out_size;

  // ws layout (bytes):
  //   fe      @ 0         : 1,048,576
  //   Acat    @ 1,048,576 : 6,291,456 (bf16)
  //   Wqkvt   @ 7,340,032 : 49,152;  W1t @ 7,389,184 : 8,192;  W2t @ 7,397,376 : 8,192
  //   Yt2/q   @13,631,488 : 50,331,648
  //   Yt3/k   @63,963,136 : 50,331,648
  //   HS/G0   @114,294,784: 50,331,648   (total 164,626,432)
  //   v = d_out[0:50MB], o = d_out[50:100MB] (dead before k_fusion writes d_out)
  //   HT reuses q slot (q dead after k_attn_lite); Yt1 lives in d_out (dead before k_qkv).
  const size_t NEEDED = 164626432ull;
  if (ws_size < NEEDED) return;

  char* w = (char*)d_ws;
  float* fe    = (float*)(w);
  u16*   Acat  = (u16*)(w + 1048576);
  u16*   Wqkvt = (u16*)(w + 7340032);
  u16*   W1t   = (u16*)(w + 7389184);
  u16*   W2t   = (u16*)(w + 7397376);
  u16*   Yt2   = (u16*)(w + 13631488);
  u16*   Yt3   = (u16*)(w + 63963136);
  u16*   HSb   = (u16*)(w + 114294784);
  u16*   Yt1   = (u16*)d_out;
  u16*   qb    = Yt2;          // after k_spatial, Yt2 slot -> q
  u16*   kbuf  = Yt3;          // Yt3 slot -> k
  u16*   vbuf  = (u16*)d_out;  // d_out lower half -> v (Yt1 dead)
  u16*   obuf  = (u16*)d_out + (size_t)NROWS_*64;  // d_out upper half -> o
  u16*   HTb   = Yt2;          // after k_attn_lite, q slot -> HT

  k_fe<<<dim3(N_, 4), 64, 0, stream>>>(feat0, feat1, Wq0, Wk0, Wq1, Wk1, fe);
  k_adjcopy<<<N_, 256, 0, stream>>>(adj, Acat);
  k_prep<<<1, 256, 0, stream>>>(Wq, Wk, Wv, Wx1, Wx2, Wqkvt, W1t, W2t);
  k_graph_softmax<<<dim3(N_, 2), 256, 0, stream>>>(fe, Acat);
  k_xw<<<dim3(NROWS_/64, 2), 256, 0, stream>>>(X, Wgcn, HSb, Yt1, Yt2, Yt3);
  k_spatial_mfma<<<dim3(8, BT_/2), 256, 0, stream>>>(Acat, Yt1, Yt2, Yt3, bgcn, HSb);
  k_qkv<<<NROWS_/128, 256, 0, stream>>>(X, STE, Wqkvt, bq, bk, bv, qb, kbuf, vbuf);
  k_attn_lite<<<(B_*N_)/4, 256, 0, stream>>>(qb, kbuf, vbuf, obuf);
  k_ht<<<NROWS_/128, 256, 0, stream>>>(obuf, W1t, W2t, bx1, bx2, HTb);
  k_fusion<<<NROWS_/4, 256, 0, stream>>>(X, HSb, HTb, Ws, Wt, btb, Wh1, bh1, Wh2, bh2,
                                         (float*)d_out);
}

// Round 4
// 904.473 us; speedup vs baseline: 5.9369x; 2.1405x over previous
//
#include <hip/hip_runtime.h>
#include <hip/hip_bf16.h>
#include <stdint.h>

#define B_ 32
#define T_ 12
#define N_ 1024
#define D_ 64
#define F_ 16
#define KH_ 8
#define BT_ (B_*T_)
#define NROWS_ (BT_*N_)
#define K3_ 3072

typedef unsigned short u16;
struct __align__(8) u16x4 { u16 x, y, z, w; };
struct __align__(16) u16x8 { u16 v[8]; };
typedef __attribute__((ext_vector_type(8))) short short8v;
typedef __attribute__((ext_vector_type(4))) float f32x4;

__device__ __forceinline__ float b2f(u16 u) {
  union { float f; unsigned int i; } c; c.i = ((unsigned int)u) << 16; return c.f;
}
__device__ __forceinline__ u16 f2b(float f) {
  union { float f; unsigned int i; } c; c.f = f;
  unsigned int u = c.i;
  unsigned int r = ((u >> 16) & 1u) + 0x7FFFu;
  return (u16)((u + r) >> 16);
}

__device__ __forceinline__ void gload_lds16(const void* g, void* l) {
  __builtin_amdgcn_global_load_lds(
      (const __attribute__((address_space(1))) unsigned int*)g,
      (__attribute__((address_space(3))) unsigned int*)l, 16, 0, 0);
}

// ---- K0: FEQ/FEK = relu(feat @ W) for both graphs. fe layout [4][1024][64]
__global__ void k_fe(const float* __restrict__ feat0, const float* __restrict__ feat1,
                     const float* __restrict__ Wq0, const float* __restrict__ Wk0,
                     const float* __restrict__ Wq1, const float* __restrict__ Wk1,
                     float* __restrict__ fe) {
  int r = blockIdx.x;
  int m = blockIdx.y;
  int d = threadIdx.x;
  const float* feat = (m < 2) ? feat0 : feat1;
  const float* W = (m == 0) ? Wq0 : (m == 1) ? Wk0 : (m == 2) ? Wq1 : Wk1;
  float acc = 0.f;
  #pragma unroll
  for (int f = 0; f < F_; ++f) acc += feat[r*F_ + f] * W[f*D_ + d];
  fe[((size_t)m*N_ + r)*D_ + d] = fmaxf(acc, 0.f);
}

// ---- K0b: copy adj into Acat[:, 0:1024] (bf16)
__global__ void k_adjcopy(const float* __restrict__ adj, u16* __restrict__ Acat) {
  int r = blockIdx.x;
  for (int c = threadIdx.x; c < N_; c += blockDim.x)
    Acat[(size_t)r*K3_ + c] = f2b(adj[(size_t)r*N_ + c]);
}

// ---- K0c: transpose small weights to bf16 [n][k] layouts for MFMA B-operands
__global__ void k_prep(const float* __restrict__ Wq, const float* __restrict__ Wk,
                       const float* __restrict__ Wv,
                       const float* __restrict__ Wx1, const float* __restrict__ Wx2,
                       const float* __restrict__ Ws, const float* __restrict__ Wt,
                       const float* __restrict__ Wh1, const float* __restrict__ Wh2,
                       u16* __restrict__ Wqkvt, u16* __restrict__ W1t, u16* __restrict__ W2t,
                       u16* __restrict__ Wstt, u16* __restrict__ Wh1t, u16* __restrict__ Wh2t) {
  int t = threadIdx.x;
  for (int i = t; i < 192*128; i += 256) {
    int nn = i >> 7, kk = i & 127;
    const float* W = (nn < 64) ? Wq : (nn < 128) ? Wk : Wv;
    Wqkvt[i] = f2b(W[kk*64 + (nn & 63)]);
  }
  for (int i = t; i < 64*64; i += 256) {
    int nn = i >> 6, kk = i & 63;
    W1t[i] = f2b(Wx1[kk*64 + nn]);
    W2t[i] = f2b(Wx2[kk*64 + nn]);
    Wh1t[i] = f2b(Wh1[kk*64 + nn]);
    Wh2t[i] = f2b(Wh2[kk*64 + nn]);
  }
  for (int i = t; i < 64*128; i += 256) {
    int nn = i >> 7, kk = i & 127;
    Wstt[i] = f2b((kk < 64) ? Ws[kk*64 + nn] : Wt[(kk-64)*64 + nn]);
  }
}

// ---- K1: S_g = softmax(FEQ @ FEK^T / 8) rows -> Acat[:, 1024+g*1024 ...] (bf16)
__global__ __launch_bounds__(256) void k_graph_softmax(const float* __restrict__ fe,
                                                       u16* __restrict__ Acat) {
  int r = blockIdx.x, g = blockIdx.y;
  const float* FEQ = fe + (size_t)(g*2 + 0)*N_*D_;
  const float* FEK = fe + (size_t)(g*2 + 1)*N_*D_;
  __shared__ float q[D_];
  __shared__ float red[256];
  int tid = threadIdx.x;
  if (tid < D_) q[tid] = FEQ[(size_t)r*D_ + tid];
  __syncthreads();
  float lg[4];
  float mx = -1e30f;
  #pragma unroll
  for (int j = 0; j < 4; ++j) {
    int c = tid + j*256;
    const float* kr = FEK + (size_t)c*D_;
    float acc = 0.f;
    #pragma unroll
    for (int f = 0; f < D_; ++f) acc += q[f]*kr[f];
    lg[j] = acc * 0.125f;
    mx = fmaxf(mx, lg[j]);
  }
  red[tid] = mx; __syncthreads();
  for (int s = 128; s > 0; s >>= 1) { if (tid < s) red[tid] = fmaxf(red[tid], red[tid+s]); __syncthreads(); }
  mx = red[0]; __syncthreads();
  float sum = 0.f;
  #pragma unroll
  for (int j = 0; j < 4; ++j) { lg[j] = __expf(lg[j]-mx); sum += lg[j]; }
  red[tid] = sum; __syncthreads();
  for (int s = 128; s > 0; s >>= 1) { if (tid < s) red[tid] += red[tid+s]; __syncthreads(); }
  float inv = 1.f / red[0];
  #pragma unroll
  for (int j = 0; j < 4; ++j) {
    int c = tid + j*256;
    Acat[(size_t)r*K3_ + (1+g)*N_ + c] = f2b(lg[j]*inv);
  }
}

// ---- K2: [BTN,64] @ Wbig[64,256] -> G0 (row-major, ->HS buf) + Yt1..3 (TRANSPOSED [bt][d][node], bf16)
__global__ __launch_bounds__(256) void k_xw(
    const float* __restrict__ X, const float* __restrict__ Wgcn,
    u16* __restrict__ G0, u16* __restrict__ Yt1, u16* __restrict__ Yt2, u16* __restrict__ Yt3)
{
  __shared__ float Als[64][65];
  __shared__ float Wls[64][128];
  int t = threadIdx.x;
  int r0 = blockIdx.x * 64;
  int c0 = blockIdx.y * 128;
  #pragma unroll
  for (int i = 0; i < 16; ++i) {
    int idx = t + 256*i;
    int m = idx >> 6, k = idx & 63;
    Als[m][k] = X[(size_t)(r0+m)*64 + k];
  }
  #pragma unroll
  for (int i = 0; i < 32; ++i) {
    int idx = t + 256*i;
    int k = idx >> 7, cc = idx & 127;
    int c = c0 + cc;
    Wls[k][cc] = Wgcn[(size_t)((c >> 6)*64 + k)*64 + (c & 63)];
  }
  __syncthreads();
  int tx = t & 31, ty = t >> 5;
  float acc[8][4] = {};
  #pragma unroll
  for (int k = 0; k < 64; ++k) {
    float4 bv = *(const float4*)&Wls[k][tx*4];
    #pragma unroll
    for (int i = 0; i < 8; ++i) {
      float a = Als[ty*8+i][k];
      acc[i][0] += a*bv.x; acc[i][1] += a*bv.y; acc[i][2] += a*bv.z; acc[i][3] += a*bv.w;
    }
  }
  int c = c0 + tx*4;
  int p = c >> 6, d0 = c & 63;
  if (p == 0) {
    #pragma unroll
    for (int i = 0; i < 8; ++i) {
      size_t rn = (size_t)r0 + ty*8 + i;
      u16x4 pk{ f2b(acc[i][0]), f2b(acc[i][1]), f2b(acc[i][2]), f2b(acc[i][3]) };
      *(u16x4*)&G0[rn*64 + d0] = pk;
    }
  } else {
    u16* Yt = (p == 1) ? Yt1 : (p == 2) ? Yt2 : Yt3;
    int bt = r0 >> 10;
    int n0 = (r0 & 1023) + ty*8;
    #pragma unroll
    for (int jj = 0; jj < 4; ++jj) {
      int d = d0 + jj;
      u16x4 lo{ f2b(acc[0][jj]), f2b(acc[1][jj]), f2b(acc[2][jj]), f2b(acc[3][jj]) };
      u16x4 hi{ f2b(acc[4][jj]), f2b(acc[5][jj]), f2b(acc[6][jj]), f2b(acc[7][jj]) };
      *(u16x4*)&Yt[((size_t)bt*64 + d)*1024 + n0]     = lo;
      *(u16x4*)&Yt[((size_t)bt*64 + d)*1024 + n0 + 4] = hi;
    }
  }
}

// ---- K3 (MFMA): per bt-pair, C[128 node,128 (2bt x 64 d)] = Acat[128,3072] @ Bstack
#define BM 128
#define BK 64
#define NKT (K3_/BK)   // 48
__global__ __launch_bounds__(256) void k_spatial_mfma(
    const u16* __restrict__ Acat,
    const u16* __restrict__ Yt1, const u16* __restrict__ Yt2, const u16* __restrict__ Yt3,
    const float* __restrict__ bgcn,
    u16* __restrict__ HS)
{
  __shared__ __align__(16) u16 Als[2][BM*BK];
  __shared__ __align__(16) u16 Bls[2][BM*BK];

  int f = blockIdx.x + 8*blockIdx.y;
  int u = f & 7, v = f >> 3;
  int btp = u*24 + (v >> 3);
  int m0  = (v & 7) * BM;
  int bt0 = btp * 2;

  int t = threadIdx.x;
  int w = t >> 6, l = t & 63;
  int rsub = l >> 3, pch = l & 7;

  f32x4 acc[4][4] = {};
  int wm = w >> 1, wn = w & 1;
  int lr = l & 15, lk = l >> 4;

  {
    #pragma unroll
    for (int i = 0; i < 4; ++i) {
      int R0 = w*32 + i*8;
      int row = R0 + rsub;
      int q = pch ^ (row & 7);
      gload_lds16(Acat + (size_t)(m0 + row)*K3_ + q*8, &Als[0][R0*64]);
    }
    const u16* Yt = Yt1;
    #pragma unroll
    for (int i = 0; i < 4; ++i) {
      int R0 = w*32 + i*8;
      int n = R0 + rsub;
      int q = pch ^ (n & 7);
      int bt = bt0 + (n >> 6), d = n & 63;
      gload_lds16(Yt + ((size_t)bt*64 + d)*1024 + q*8, &Bls[0][R0*64]);
    }
  }
  __syncthreads();

  int buf = 0;
  for (int kt = 0; kt < NKT; ++kt) {
    if (kt + 1 < NKT) {
      int k0 = (kt + 1) * BK;
      #pragma unroll
      for (int i = 0; i < 4; ++i) {
        int R0 = w*32 + i*8;
        int row = R0 + rsub;
        int q = pch ^ (row & 7);
        gload_lds16(Acat + (size_t)(m0 + row)*K3_ + k0 + q*8, &Als[buf^1][R0*64]);
      }
      int pl = k0 >> 10, kk = k0 & 1023;
      const u16* Yt = (pl == 0) ? Yt1 : (pl == 1) ? Yt2 : Yt3;
      #pragma unroll
      for (int i = 0; i < 4; ++i) {
        int R0 = w*32 + i*8;
        int n = R0 + rsub;
        int q = pch ^ (n & 7);
        int bt = bt0 + (n >> 6), d = n & 63;
        gload_lds16(Yt + ((size_t)bt*64 + d)*1024 + kk + q*8, &Bls[buf^1][R0*64]);
      }
    }
    const u16* A = &Als[buf][0];
    const u16* Bp = &Bls[buf][0];
    #pragma unroll
    for (int ks = 0; ks < 2; ++ks) {
      short8v av[4], bv[4];
      #pragma unroll
      for (int fm = 0; fm < 4; ++fm) {
        int r = wm*64 + fm*16 + lr;
        int p = (ks*4 + lk) ^ (r & 7);
        av[fm] = *(const short8v*)(A + r*64 + p*8);
      }
      #pragma unroll
      for (int fn = 0; fn < 4; ++fn) {
        int r = wn*64 + fn*16 + lr;
        int p = (ks*4 + lk) ^ (r & 7);
        bv[fn] = *(const short8v*)(Bp + r*64 + p*8);
      }
      #pragma unroll
      for (int fm = 0; fm < 4; ++fm)
        #pragma unroll
        for (int fn = 0; fn < 4; ++fn)
          acc[fm][fn] = __builtin_amdgcn_mfma_f32_16x16x32_bf16(av[fm], bv[fn], acc[fm][fn], 0, 0, 0);
    }
    __syncthreads();
    buf ^= 1;
  }

  #pragma unroll
  for (int fm = 0; fm < 4; ++fm) {
    int nodeb = m0 + wm*64 + fm*16 + lk*4;
    #pragma unroll
    for (int fn = 0; fn < 4; ++fn) {
      int nl = wn*64 + fn*16 + lr;
      int bt = bt0 + (nl >> 6), d = nl & 63;
      float bb = bgcn[d];
      size_t base = (size_t)bt * N_ * 64;
      #pragma unroll
      for (int j = 0; j < 4; ++j) {
        size_t idx = base + (size_t)(nodeb + j)*64 + d;
        float vv = acc[fm][fn][j] + b2f(HS[idx]) + bb;
        HS[idx] = f2b(fmaxf(vv, 0.f));
      }
    }
  }
}

// ---- K4a (MFMA): qkv = relu([X|STE] @ Wqkv^T + b) -> q,k,v bf16 [BTN][64]
__global__ __launch_bounds__(256) void k_qkv(
    const float* __restrict__ X, const float* __restrict__ STE,
    const u16* __restrict__ Wqkvt,
    const float* __restrict__ bq, const float* __restrict__ bk, const float* __restrict__ bv,
    u16* __restrict__ qb, u16* __restrict__ kb, u16* __restrict__ vb)
{
  __shared__ __align__(16) u16 Als[128*128];   // [row][k], chunk-swizzled
  __shared__ __align__(16) u16 Bls[192*128];   // W^T [n][k], chunk-swizzled
  int m0 = blockIdx.x * 128;
  int t = threadIdx.x;
  int w = t >> 6, l = t & 63;

  {
    int rsub = l >> 4, pch = l & 15;
    #pragma unroll
    for (int i = 0; i < 12; ++i) {
      int R0 = w*48 + i*4;
      int n = R0 + rsub;
      int sq = pch ^ (n & 7);
      gload_lds16(Wqkvt + (size_t)n*128 + sq*8, &Bls[R0*128]);
    }
  }
  #pragma unroll
  for (int i = 0; i < 8; ++i) {
    int flat = t + 256*i;
    int row = flat >> 4, c = flat & 15;
    const float* src = ((c < 8) ? X : STE) + (size_t)(m0+row)*64 + (c & 7)*8;
    float4 f0 = *(const float4*)src;
    float4 f1 = *(const float4*)(src + 4);
    u16x8 pk;
    pk.v[0]=f2b(f0.x); pk.v[1]=f2b(f0.y); pk.v[2]=f2b(f0.z); pk.v[3]=f2b(f0.w);
    pk.v[4]=f2b(f1.x); pk.v[5]=f2b(f1.y); pk.v[6]=f2b(f1.z); pk.v[7]=f2b(f1.w);
    int cs = c ^ (row & 7);
    *(u16x8*)&Als[row*128 + cs*8] = pk;
  }
  __syncthreads();

  int wm = w >> 1, wn = w & 1;
  int lr = l & 15, lk = l >> 4;
  f32x4 acc[4][6] = {};
  #pragma unroll
  for (int ks = 0; ks < 4; ++ks) {
    short8v av[4], bvv[6];
    #pragma unroll
    for (int fm = 0; fm < 4; ++fm) {
      int r = wm*64 + fm*16 + lr;
      int ch = (ks*4 + lk) ^ (r & 7);
      av[fm] = *(const short8v*)&Als[r*128 + ch*8];
    }
    #pragma unroll
    for (int fn = 0; fn < 6; ++fn) {
      int n = wn*96 + fn*16 + lr;
      int ch = (ks*4 + lk) ^ (n & 7);
      bvv[fn] = *(const short8v*)&Bls[n*128 + ch*8];
    }
    #pragma unroll
    for (int fm = 0; fm < 4; ++fm)
      #pragma unroll
      for (int fn = 0; fn < 6; ++fn)
        acc[fm][fn] = __builtin_amdgcn_mfma_f32_16x16x32_bf16(av[fm], bvv[fn], acc[fm][fn], 0, 0, 0);
  }

  #pragma unroll
  for (int fm = 0; fm < 4; ++fm) {
    int rowb = m0 + wm*64 + fm*16 + lk*4;
    #pragma unroll
    for (int fn = 0; fn < 6; ++fn) {
      int col = wn*96 + fn*16 + lr;
      int sel = col >> 6, d = col & 63;
      u16* dst = (sel == 0) ? qb : (sel == 1) ? kb : vb;
      float bias = ((sel == 0) ? bq : (sel == 1) ? bk : bv)[d];
      #pragma unroll
      for (int j = 0; j < 4; ++j) {
        float val = acc[fm][fn][j] + bias;
        dst[(size_t)(rowb + j)*64 + d] = f2b(fmaxf(val, 0.f));
      }
    }
  }
}

// ---- K4b: attention only, one wave per (b,n), all-register, shuffle reduce
__global__ __launch_bounds__(256) void k_attn_lite(
    const u16* __restrict__ qb, const u16* __restrict__ kb, const u16* __restrict__ vb,
    u16* __restrict__ ob)
{
  int w = threadIdx.x >> 6, l = threadIdx.x & 63;
  int flat = blockIdx.x*4 + w;
  int b = flat >> 10, n = flat & 1023;
  float qv[T_], kv[T_], vv[T_];
  #pragma unroll
  for (int tt = 0; tt < T_; ++tt) {
    size_t idx = ((size_t)(b*T_ + tt)*N_ + n)*64 + l;
    qv[tt] = b2f(qb[idx]); kv[tt] = b2f(kb[idx]); vv[tt] = b2f(vb[idx]);
  }
  #pragma unroll
  for (int tt = 0; tt < T_; ++tt) {
    float sc[T_];
    float mx = -1e30f;
    #pragma unroll
    for (int j = 0; j < T_; ++j) {
      float p = qv[tt]*kv[j];
      p += __shfl_xor(p, 1);
      p += __shfl_xor(p, 2);
      p += __shfl_xor(p, 4);
      sc[j] = p * 0.3535533906f;
      mx = fmaxf(mx, sc[j]);
    }
    float sum = 0.f;
    #pragma unroll
    for (int j = 0; j < T_; ++j) { sc[j] = __expf(sc[j]-mx); sum += sc[j]; }
    float o = 0.f;
    #pragma unroll
    for (int j = 0; j < T_; ++j) o += sc[j]*vv[j];
    ob[((size_t)(b*T_ + tt)*N_ + n)*64 + l] = f2b(o / sum);
  }
}

// ---- K4c (MFMA): HT = relu(o@Wx1+bx1)@Wx2+bx2, chained in LDS
__global__ __launch_bounds__(256) void k_ht(
    const u16* __restrict__ ob, const u16* __restrict__ W1t, const u16* __restrict__ W2t,
    const float* __restrict__ bx1, const float* __restrict__ bx2,
    u16* __restrict__ HT)
{
  __shared__ __align__(16) u16 Ols[128*64];
  __shared__ __align__(16) u16 W1ls[64*64];
  __shared__ __align__(16) u16 W2ls[64*64];
  __shared__ __align__(16) u16 H1ls[128*64];
  int m0 = blockIdx.x * 128;
  int t = threadIdx.x;
  int w = t >> 6, l = t & 63;
  int rsub = l >> 3, pch = l & 7;

  #pragma unroll
  for (int i = 0; i < 4; ++i) {
    int R0 = w*32 + i*8;
    int row = R0 + rsub;
    int sq = pch ^ (row & 7);
    gload_lds16(ob + (size_t)(m0 + row)*64 + sq*8, &Ols[R0*64]);
  }
  #pragma unroll
  for (int i = 0; i < 2; ++i) {
    int R0 = w*16 + i*8;
    int row = R0 + rsub;
    int sq = pch ^ (row & 7);
    gload_lds16(W1t + (size_t)row*64 + sq*8, &W1ls[R0*64]);
    gload_lds16(W2t + (size_t)row*64 + sq*8, &W2ls[R0*64]);
  }
  __syncthreads();

  int wm = w >> 1, wn = w & 1;
  int lr = l & 15, lk = l >> 4;
  f32x4 acc1[4][2] = {};
  #pragma unroll
  for (int ks = 0; ks < 2; ++ks) {
    short8v av[4], bvv[2];
    #pragma unroll
    for (int fm = 0; fm < 4; ++fm) {
      int r = wm*64 + fm*16 + lr;
      int ch = (ks*4 + lk) ^ (r & 7);
      av[fm] = *(const short8v*)&Ols[r*64 + ch*8];
    }
    #pragma unroll
    for (int fn = 0; fn < 2; ++fn) {
      int n = wn*32 + fn*16 + lr;
      int ch = (ks*4 + lk) ^ (n & 7);
      bvv[fn] = *(const short8v*)&W1ls[n*64 + ch*8];
    }
    #pragma unroll
    for (int fm = 0; fm < 4; ++fm)
      #pragma unroll
      for (int fn = 0; fn < 2; ++fn)
        acc1[fm][fn] = __builtin_amdgcn_mfma_f32_16x16x32_bf16(av[fm], bvv[fn], acc1[fm][fn], 0, 0, 0);
  }
  #pragma unroll
  for (int fm = 0; fm < 4; ++fm) {
    #pragma unroll
    for (int fn = 0; fn < 2; ++fn) {
      int col = wn*32 + fn*16 + lr;
      float bias = bx1[col];
      #pragma unroll
      for (int j = 0; j < 4; ++j) {
        int row = wm*64 + fm*16 + lk*4 + j;
        float val = acc1[fm][fn][j] + bias;
        H1ls[row*64 + (((col >> 3) ^ (row & 7)))*8 + (col & 7)] = f2b(fmaxf(val, 0.f));
      }
    }
  }
  __syncthreads();

  f32x4 acc2[4][2] = {};
  #pragma unroll
  for (int ks = 0; ks < 2; ++ks) {
    short8v av[4], bvv[2];
    #pragma unroll
    for (int fm = 0; fm < 4; ++fm) {
      int r = wm*64 + fm*16 + lr;
      int ch = (ks*4 + lk) ^ (r & 7);
      av[fm] = *(const short8v*)&H1ls[r*64 + ch*8];
    }
    #pragma unroll
    for (int fn = 0; fn < 2; ++fn) {
      int n = wn*32 + fn*16 + lr;
      int ch = (ks*4 + lk) ^ (n & 7);
      bvv[fn] = *(const short8v*)&W2ls[n*64 + ch*8];
    }
    #pragma unroll
    for (int fm = 0; fm < 4; ++fm)
      #pragma unroll
      for (int fn = 0; fn < 2; ++fn)
        acc2[fm][fn] = __builtin_amdgcn_mfma_f32_16x16x32_bf16(av[fm], bvv[fn], acc2[fm][fn], 0, 0, 0);
  }
  #pragma unroll
  for (int fm = 0; fm < 4; ++fm) {
    #pragma unroll
    for (int fn = 0; fn < 2; ++fn) {
      int col = wn*32 + fn*16 + lr;
      float bias = bx2[col];
      #pragma unroll
      for (int j = 0; j < 4; ++j) {
        int row = wm*64 + fm*16 + lk*4 + j;
        HT[(size_t)(m0 + row)*64 + col] = f2b(acc2[fm][fn][j] + bias);
      }
    }
  }
}

// ---- K5 (MFMA): gated fusion + output head, 128 rows/block, all-LDS chain
__global__ __launch_bounds__(256) void k_fusion_mfma(
    const float* __restrict__ X,
    const u16* __restrict__ HS, const u16* __restrict__ HT,
    const u16* __restrict__ Wstt, const u16* __restrict__ Wh1t, const u16* __restrict__ Wh2t,
    const float* __restrict__ btb, const float* __restrict__ bh1, const float* __restrict__ bh2,
    float* __restrict__ out)
{
  __shared__ __align__(16) u16 Als[128*128];   // [HS|HT] tile, chunk-swizzled (32 KB)
  __shared__ __align__(16) u16 Wst[64*128];    // [Ws;Wt]^T, later overlaid by H2 [128][64] (16 KB)
  __shared__ __align__(16) u16 W1ls[64*64];    // 8 KB
  __shared__ __align__(16) u16 W2ls[64*64];    // 8 KB
  __shared__ __align__(16) u16 Hls[128*64];    // gated H (16 KB)
  int m0 = blockIdx.x * 128;
  int t = threadIdx.x;
  int w = t >> 6, l = t & 63;

  // stage [HS|HT]: rows m0..m0+127, 16 chunks/row; logical chunk q at LDS slot pch = q ^ (row&7)
  {
    int rsub = l >> 4, pch = l & 15;
    #pragma unroll
    for (int i = 0; i < 8; ++i) {
      int R0 = w*32 + i*4;
      int row = R0 + rsub;
      int q = pch ^ (row & 7);
      const u16* src = (q < 8) ? (HS + (size_t)(m0 + row)*64 + q*8)
                               : (HT + (size_t)(m0 + row)*64 + (q - 8)*8);
      gload_lds16(src, &Als[R0*128]);
    }
    #pragma unroll
    for (int i = 0; i < 4; ++i) {
      int R0 = w*16 + i*4;
      int n = R0 + rsub;
      int q = pch ^ (n & 7);
      gload_lds16(Wstt + (size_t)n*128 + q*8, &Wst[R0*128]);
    }
  }
  {
    int rsub = l >> 3, pch = l & 7;
    #pragma unroll
    for (int i = 0; i < 2; ++i) {
      int R0 = w*16 + i*8;
      int row = R0 + rsub;
      int q = pch ^ (row & 7);
      gload_lds16(Wh1t + (size_t)row*64 + q*8, &W1ls[R0*64]);
      gload_lds16(Wh2t + (size_t)row*64 + q*8, &W2ls[R0*64]);
    }
  }
  __syncthreads();

  int lr = l & 15, lk = l >> 4;
  // GEMM1: a_s = [HS|HT] @ [Ws;Wt]  (K=128); wave w owns rows w*32..w*32+31, cols 0..63
  f32x4 acc1[2][4] = {};
  #pragma unroll
  for (int ks = 0; ks < 4; ++ks) {
    short8v av[2], bvv[4];
    #pragma unroll
    for (int fm = 0; fm < 2; ++fm) {
      int r = w*32 + fm*16 + lr;
      int ch = (ks*4 + lk) ^ (r & 7);
      av[fm] = *(const short8v*)&Als[r*128 + ch*8];
    }
    #pragma unroll
    for (int fn = 0; fn < 4; ++fn) {
      int n = fn*16 + lr;
      int ch = (ks*4 + lk) ^ (n & 7);
      bvv[fn] = *(const short8v*)&Wst[n*128 + ch*8];
    }
    #pragma unroll
    for (int fm = 0; fm < 2; ++fm)
      #pragma unroll
      for (int fn = 0; fn < 4; ++fn)
        acc1[fm][fn] = __builtin_amdgcn_mfma_f32_16x16x32_bf16(av[fm], bvv[fn], acc1[fm][fn], 0, 0, 0);
  }
  // gate: H = zg*hs + (1-zg)*ht -> Hls (swizzled)
  #pragma unroll
  for (int fm = 0; fm < 2; ++fm) {
    #pragma unroll
    for (int fn = 0; fn < 4; ++fn) {
      int col = fn*16 + lr;
      float bb = btb[col];
      #pragma unroll
      for (int j = 0; j < 4; ++j) {
        int row = w*32 + fm*16 + lk*4 + j;
        float a_s = acc1[fm][fn][j] + bb;
        float zg = 1.f/(1.f + __expf(-a_s));
        int cs = (col >> 3) ^ (row & 7);
        float hs = b2f(Als[row*128 + cs*8 + (col & 7)]);
        float ht = b2f(Als[row*128 + (cs + 8)*8 + (col & 7)]);
        float H = zg*hs + (1.f - zg)*ht;
        Hls[row*64 + cs*8 + (col & 7)] = f2b(H);
      }
    }
  }
  __syncthreads();

  // GEMM2: H2 = relu(H @ Wh1 + bh1)  (K=64); H2 overlays Wst as [128][64]
  u16* H2ls = Wst;
  f32x4 acc2[2][4] = {};
  #pragma unroll
  for (int ks = 0; ks < 2; ++ks) {
    short8v av[2], bvv[4];
    #pragma unroll
    for (int fm = 0; fm < 2; ++fm) {
      int r = w*32 + fm*16 + lr;
      int ch = (ks*4 + lk) ^ (r & 7);
      av[fm] = *(const short8v*)&Hls[r*64 + ch*8];
    }
    #pragma unroll
    for (int fn = 0; fn < 4; ++fn) {
      int n = fn*16 + lr;
      int ch = (ks*4 + lk) ^ (n & 7);
      bvv[fn] = *(const short8v*)&W1ls[n*64 + ch*8];
    }
    #pragma unroll
    for (int fm = 0; fm < 2; ++fm)
      #pragma unroll
      for (int fn = 0; fn < 4; ++fn)
        acc2[fm][fn] = __builtin_amdgcn_mfma_f32_16x16x32_bf16(av[fm], bvv[fn], acc2[fm][fn], 0, 0, 0);
  }
  __syncthreads();   // all GEMM1/GEMM2 reads of Wst done before overlay write
  #pragma unroll
  for (int fm = 0; fm < 2; ++fm) {
    #pragma unroll
    for (int fn = 0; fn < 4; ++fn) {
      int col = fn*16 + lr;
      float bias = bh1[col];
      #pragma unroll
      for (int j = 0; j < 4; ++j) {
        int row = w*32 + fm*16 + lk*4 + j;
        float val = acc2[fm][fn][j] + bias;
        int cs = (col >> 3) ^ (row & 7);
        H2ls[row*64 + cs*8 + (col & 7)] = f2b(fmaxf(val, 0.f));
      }
    }
  }
  __syncthreads();

  // GEMM3: out = X + H2 @ Wh2 + bh2  (K=64)
  f32x4 acc3[2][4] = {};
  #pragma unroll
  for (int ks = 0; ks < 2; ++ks) {
    short8v av[2], bvv[4];
    #pragma unroll
    for (int fm = 0; fm < 2; ++fm) {
      int r = w*32 + fm*16 + lr;
      int ch = (ks*4 + lk) ^ (r & 7);
      av[fm] = *(const short8v*)&H2ls[r*64 + ch*8];
    }
    #pragma unroll
    for (int fn = 0; fn < 4; ++fn) {
      int n = fn*16 + lr;
      int ch = (ks*4 + lk) ^ (n & 7);
      bvv[fn] = *(const short8v*)&W2ls[n*64 + ch*8];
    }
    #pragma unroll
    for (int fm = 0; fm < 2; ++fm)
      #pragma unroll
      for (int fn = 0; fn < 4; ++fn)
        acc3[fm][fn] = __builtin_amdgcn_mfma_f32_16x16x32_bf16(av[fm], bvv[fn], acc3[fm][fn], 0, 0, 0);
  }
  #pragma unroll
  for (int fm = 0; fm < 2; ++fm) {
    #pragma unroll
    for (int fn = 0; fn < 4; ++fn) {
      int col = fn*16 + lr;
      float bias = bh2[col];
      #pragma unroll
      for (int j = 0; j < 4; ++j) {
        int row = w*32 + fm*16 + lk*4 + j;
        size_t gi = (size_t)(m0 + row)*64 + col;
        out[gi] = X[gi] + acc3[fm][fn][j] + bias;
      }
    }
  }
}

extern "C" void kernel_launch(void* const* d_in, const int* in_sizes, int n_in,
                              void* d_out, int out_size, void* d_ws, size_t ws_size,
                              hipStream_t stream) {
  const float* X    = (const float*)d_in[0];
  const float* STE  = (const float*)d_in[1];
  const float* adj  = (const float*)d_in[2];
  const float* feat0= (const float*)d_in[3];
  const float* feat1= (const float*)d_in[4];
  const float* Wq0  = (const float*)d_in[5];
  const float* Wk0  = (const float*)d_in[6];
  const float* Wq1  = (const float*)d_in[7];
  const float* Wk1  = (const float*)d_in[8];
  const float* Wgcn = (const float*)d_in[9];
  const float* bgcn = (const float*)d_in[10];
  const float* Wq   = (const float*)d_in[11];
  const float* bq   = (const float*)d_in[12];
  const float* Wk   = (const float*)d_in[13];
  const float* bk   = (const float*)d_in[14];
  const float* Wv   = (const float*)d_in[15];
  const float* bv   = (const float*)d_in[16];
  const float* Wx1  = (const float*)d_in[17];
  const float* bx1  = (const float*)d_in[18];
  const float* Wx2  = (const float*)d_in[19];
  const float* bx2  = (const float*)d_in[20];
  const float* Ws   = (const float*)d_in[21];
  const float* Wt   = (const float*)d_in[22];
  const float* btb  = (const float*)d_in[23];
  const float* Wh1  = (const float*)d_in[24];
  const float* bh1  = (const float*)d_in[25];
  const float* Wh2  = (const float*)d_in[26];
  const float* bh2  = (const float*)d_in[27];
  (void)in_sizes; (void)n_in; (void)out_size;

  // ws layout (bytes):
  //   fe      @ 0         : 1,048,576
  //   Acat    @ 1,048,576 : 6,291,456 (bf16)
  //   Wqkvt   @ 7,340,032 : 49,152;  W1t @ 7,389,184 : 8,192;  W2t @ 7,397,376 : 8,192
  //   Wstt    @ 7,405,568 : 16,384;  Wh1t @ 7,421,952 : 8,192; Wh2t @ 7,430,144 : 8,192
  //   Yt2/q   @13,631,488 : 50,331,648
  //   Yt3/k   @63,963,136 : 50,331,648
  //   HS/G0   @114,294,784: 50,331,648   (total 164,626,432)
  //   v = d_out[0:50MB], o = d_out[50:100MB] (dead before k_fusion writes d_out)
  //   HT reuses q slot (q dead after k_attn_lite); Yt1 lives in d_out (dead before k_qkv).
  const size_t NEEDED = 164626432ull;
  if (ws_size < NEEDED) return;

  char* w = (char*)d_ws;
  float* fe    = (float*)(w);
  u16*   Acat  = (u16*)(w + 1048576);
  u16*   Wqkvt = (u16*)(w + 7340032);
  u16*   W1t   = (u16*)(w + 7389184);
  u16*   W2t   = (u16*)(w + 7397376);
  u16*   Wstt  = (u16*)(w + 7405568);
  u16*   Wh1t  = (u16*)(w + 7421952);
  u16*   Wh2t  = (u16*)(w + 7430144);
  u16*   Yt2   = (u16*)(w + 13631488);
  u16*   Yt3   = (u16*)(w + 63963136);
  u16*   HSb   = (u16*)(w + 114294784);
  u16*   Yt1   = (u16*)d_out;
  u16*   qb    = Yt2;
  u16*   kbuf  = Yt3;
  u16*   vbuf  = (u16*)d_out;
  u16*   obuf  = (u16*)d_out + (size_t)NROWS_*64;
  u16*   HTb   = Yt2;

  k_fe<<<dim3(N_, 4), 64, 0, stream>>>(feat0, feat1, Wq0, Wk0, Wq1, Wk1, fe);
  k_adjcopy<<<N_, 256, 0, stream>>>(adj, Acat);
  k_prep<<<1, 256, 0, stream>>>(Wq, Wk, Wv, Wx1, Wx2, Ws, Wt, Wh1, Wh2,
                                Wqkvt, W1t, W2t, Wstt, Wh1t, Wh2t);
  k_graph_softmax<<<dim3(N_, 2), 256, 0, stream>>>(fe, Acat);
  k_xw<<<dim3(NROWS_/64, 2), 256, 0, stream>>>(X, Wgcn, HSb, Yt1, Yt2, Yt3);
  k_spatial_mfma<<<dim3(8, BT_/2), 256, 0, stream>>>(Acat, Yt1, Yt2, Yt3, bgcn, HSb);
  k_qkv<<<NROWS_/128, 256, 0, stream>>>(X, STE, Wqkvt, bq, bk, bv, qb, kbuf, vbuf);
  k_attn_lite<<<(B_*N_)/4, 256, 0, stream>>>(qb, kbuf, vbuf, obuf);
  k_ht<<<NROWS_/128, 256, 0, stream>>>(obuf, W1t, W2t, bx1, bx2, HTb);
  k_fusion_mfma<<<NROWS_/128, 256, 0, stream>>>(X, HSb, HTb, Wstt, Wh1t, Wh2t,
                                                btb, bh1, bh2, (float*)d_out);
}

// Round 5
// 798.143 us; speedup vs baseline: 6.7278x; 1.1332x over previous
//
#include <hip/hip_runtime.h>
#include <hip/hip_bf16.h>
#include <stdint.h>

#define B_ 32
#define T_ 12
#define N_ 1024
#define D_ 64
#define F_ 16
#define KH_ 8
#define BT_ (B_*T_)
#define NROWS_ (BT_*N_)
#define K3_ 3072

typedef unsigned short u16;
struct __align__(8) u16x4 { u16 x, y, z, w; };
struct __align__(16) u16x8 { u16 v[8]; };
typedef __attribute__((ext_vector_type(8))) short short8v;
typedef __attribute__((ext_vector_type(4))) float f32x4;

__device__ __forceinline__ float b2f(u16 u) {
  union { float f; unsigned int i; } c; c.i = ((unsigned int)u) << 16; return c.f;
}
__device__ __forceinline__ u16 f2b(float f) {
  union { float f; unsigned int i; } c; c.f = f;
  unsigned int u = c.i;
  unsigned int r = ((u >> 16) & 1u) + 0x7FFFu;
  return (u16)((u + r) >> 16);
}

__device__ __forceinline__ void gload_lds16(const void* g, void* l) {
  __builtin_amdgcn_global_load_lds(
      (const __attribute__((address_space(1))) unsigned int*)g,
      (__attribute__((address_space(3))) unsigned int*)l, 16, 0, 0);
}

// ---- K0: FEQ/FEK = relu(feat @ W) for both graphs. fe layout [4][1024][64]
__global__ void k_fe(const float* __restrict__ feat0, const float* __restrict__ feat1,
                     const float* __restrict__ Wq0, const float* __restrict__ Wk0,
                     const float* __restrict__ Wq1, const float* __restrict__ Wk1,
                     float* __restrict__ fe) {
  int r = blockIdx.x;
  int m = blockIdx.y;
  int d = threadIdx.x;
  const float* feat = (m < 2) ? feat0 : feat1;
  const float* W = (m == 0) ? Wq0 : (m == 1) ? Wk0 : (m == 2) ? Wq1 : Wk1;
  float acc = 0.f;
  #pragma unroll
  for (int f = 0; f < F_; ++f) acc += feat[r*F_ + f] * W[f*D_ + d];
  fe[((size_t)m*N_ + r)*D_ + d] = fmaxf(acc, 0.f);
}

// ---- K0b: copy adj into Acat[:, 0:1024] (bf16)
__global__ void k_adjcopy(const float* __restrict__ adj, u16* __restrict__ Acat) {
  int r = blockIdx.x;
  for (int c = threadIdx.x; c < N_; c += blockDim.x)
    Acat[(size_t)r*K3_ + c] = f2b(adj[(size_t)r*N_ + c]);
}

// ---- K0c: transpose small weights to bf16 [n][k] layouts for MFMA B-operands
__global__ void k_prep(const float* __restrict__ Wq, const float* __restrict__ Wk,
                       const float* __restrict__ Wv,
                       const float* __restrict__ Wx1, const float* __restrict__ Wx2,
                       const float* __restrict__ Ws, const float* __restrict__ Wt,
                       const float* __restrict__ Wh1, const float* __restrict__ Wh2,
                       const float* __restrict__ Wgcn,
                       u16* __restrict__ Wqkvt, u16* __restrict__ W1t, u16* __restrict__ W2t,
                       u16* __restrict__ Wstt, u16* __restrict__ Wh1t, u16* __restrict__ Wh2t,
                       u16* __restrict__ Wgcnt) {
  int t = threadIdx.x;
  for (int i = t; i < 192*128; i += 256) {
    int nn = i >> 7, kk = i & 127;
    const float* W = (nn < 64) ? Wq : (nn < 128) ? Wk : Wv;
    Wqkvt[i] = f2b(W[kk*64 + (nn & 63)]);
  }
  for (int i = t; i < 64*64; i += 256) {
    int nn = i >> 6, kk = i & 63;
    W1t[i] = f2b(Wx1[kk*64 + nn]);
    W2t[i] = f2b(Wx2[kk*64 + nn]);
    Wh1t[i] = f2b(Wh1[kk*64 + nn]);
    Wh2t[i] = f2b(Wh2[kk*64 + nn]);
  }
  for (int i = t; i < 64*128; i += 256) {
    int nn = i >> 7, kk = i & 127;
    Wstt[i] = f2b((kk < 64) ? Ws[kk*64 + nn] : Wt[(kk-64)*64 + nn]);
  }
  // Wgcnt[c][k] = Wbig[k][c] = Wgcn[(c>>6)*64 + k][c&63]
  for (int i = t; i < 256*64; i += 256) {
    int cc = i >> 6, kk = i & 63;
    Wgcnt[i] = f2b(Wgcn[(size_t)((cc >> 6)*64 + kk)*64 + (cc & 63)]);
  }
}

// ---- K1: S_g = softmax(FEQ @ FEK^T / 8) rows -> Acat[:, 1024+g*1024 ...] (bf16)
__global__ __launch_bounds__(256) void k_graph_softmax(const float* __restrict__ fe,
                                                       u16* __restrict__ Acat) {
  int r = blockIdx.x, g = blockIdx.y;
  const float* FEQ = fe + (size_t)(g*2 + 0)*N_*D_;
  const float* FEK = fe + (size_t)(g*2 + 1)*N_*D_;
  __shared__ float q[D_];
  __shared__ float red[256];
  int tid = threadIdx.x;
  if (tid < D_) q[tid] = FEQ[(size_t)r*D_ + tid];
  __syncthreads();
  float lg[4];
  float mx = -1e30f;
  #pragma unroll
  for (int j = 0; j < 4; ++j) {
    int c = tid + j*256;
    const float* kr = FEK + (size_t)c*D_;
    float acc = 0.f;
    #pragma unroll
    for (int f = 0; f < D_; ++f) acc += q[f]*kr[f];
    lg[j] = acc * 0.125f;
    mx = fmaxf(mx, lg[j]);
  }
  red[tid] = mx; __syncthreads();
  for (int s = 128; s > 0; s >>= 1) { if (tid < s) red[tid] = fmaxf(red[tid], red[tid+s]); __syncthreads(); }
  mx = red[0]; __syncthreads();
  float sum = 0.f;
  #pragma unroll
  for (int j = 0; j < 4; ++j) { lg[j] = __expf(lg[j]-mx); sum += lg[j]; }
  red[tid] = sum; __syncthreads();
  for (int s = 128; s > 0; s >>= 1) { if (tid < s) red[tid] += red[tid+s]; __syncthreads(); }
  float inv = 1.f / red[0];
  #pragma unroll
  for (int j = 0; j < 4; ++j) {
    int c = tid + j*256;
    Acat[(size_t)r*K3_ + (1+g)*N_ + c] = f2b(lg[j]*inv);
  }
}

// ---- K2 (MFMA): [BTN,64] @ Wgcnt^T[64,256] -> G0 row-major + Yt1..3 transposed [bt][d][node]
__global__ __launch_bounds__(256) void k_xw_mfma(
    const float* __restrict__ X, const u16* __restrict__ Wgcnt,
    u16* __restrict__ G0, u16* __restrict__ Yt1, u16* __restrict__ Yt2, u16* __restrict__ Yt3)
{
  // phase1: Als=SM[0..8191] (X tile 128x64), Bls=SM[8192..24575] (W 256x64)
  // phase2: Tls=SM[0..24575] (transpose tile 192x128)
  // phase3: Gls=SM[0..8191]  (G0 row-major 128x64)
  __shared__ __align__(16) u16 SM[24576];
  u16* Als = SM;
  u16* Bls = SM + 8192;
  u16* Tls = SM;
  u16* Gls = SM;
  int m0 = blockIdx.x * 128;
  int t = threadIdx.x;
  int w = t >> 6, l = t & 63;

  // stage B via global_load_lds (pre-swizzled source, 8 chunks/row)
  {
    int rsub = l >> 3, pch = l & 7;
    #pragma unroll
    for (int i = 0; i < 8; ++i) {
      int R0 = w*64 + i*8;
      int n = R0 + rsub;
      int q = pch ^ (n & 7);
      gload_lds16(Wgcnt + (size_t)n*64 + q*8, &Bls[R0*64]);
    }
  }
  // stage A: f32 X -> bf16, swizzled ds_write
  #pragma unroll
  for (int i = 0; i < 4; ++i) {
    int flat = t + 256*i;
    int row = flat >> 3, c = flat & 7;
    const float* src = X + (size_t)(m0+row)*64 + c*8;
    float4 f0 = *(const float4*)src;
    float4 f1 = *(const float4*)(src + 4);
    u16x8 pk;
    pk.v[0]=f2b(f0.x); pk.v[1]=f2b(f0.y); pk.v[2]=f2b(f0.z); pk.v[3]=f2b(f0.w);
    pk.v[4]=f2b(f1.x); pk.v[5]=f2b(f1.y); pk.v[6]=f2b(f1.z); pk.v[7]=f2b(f1.w);
    int cs = c ^ (row & 7);
    *(u16x8*)&Als[row*64 + cs*8] = pk;
  }
  __syncthreads();

  int wm = w & 1, wn = w >> 1;     // wave: 64 rows x 128 cols
  int lr = l & 15, lk = l >> 4;
  f32x4 acc[4][8] = {};
  #pragma unroll
  for (int ks = 0; ks < 2; ++ks) {
    short8v av[4], bv[8];
    #pragma unroll
    for (int fm = 0; fm < 4; ++fm) {
      int r = wm*64 + fm*16 + lr;
      int ch = (ks*4 + lk) ^ (r & 7);
      av[fm] = *(const short8v*)&Als[r*64 + ch*8];
    }
    #pragma unroll
    for (int fn = 0; fn < 8; ++fn) {
      int n = wn*128 + fn*16 + lr;
      int ch = (ks*4 + lk) ^ (n & 7);
      bv[fn] = *(const short8v*)&Bls[n*64 + ch*8];
    }
    #pragma unroll
    for (int fm = 0; fm < 4; ++fm)
      #pragma unroll
      for (int fn = 0; fn < 8; ++fn)
        acc[fm][fn] = __builtin_amdgcn_mfma_f32_16x16x32_bf16(av[fm], bv[fn], acc[fm][fn], 0, 0, 0);
  }
  __syncthreads();   // all LDS reads done; SM reusable

  // ---- phase2: cols >=64 through transpose tile Tls[d'][node], XOR-swizzled
  #pragma unroll
  for (int fm = 0; fm < 4; ++fm) {
    int row0 = wm*64 + fm*16 + lk*4;
    #pragma unroll
    for (int fn = 0; fn < 8; ++fn) {
      int c = wn*128 + fn*16 + lr;
      if (c >= 64) {
        int dp = c - 64;
        u16x4 pk{ f2b(acc[fm][fn][0]), f2b(acc[fm][fn][1]),
                  f2b(acc[fm][fn][2]), f2b(acc[fm][fn][3]) };
        *(u16x4*)&Tls[dp*128 + (row0 ^ ((dp & 7) << 3))] = pk;
      }
    }
  }
  __syncthreads();
  {
    int bt = m0 >> 10, nb = m0 & 1023;
    #pragma unroll
    for (int i = 0; i < 12; ++i) {
      int cc = t + 256*i;
      int dp = cc >> 4, nc = cc & 15;
      int n0 = nc*8;
      u16x8 vv = *(const u16x8*)&Tls[dp*128 + (n0 ^ ((dp & 7) << 3))];
      int p = dp >> 6, d = dp & 63;
      u16* Yt = (p == 0) ? Yt1 : (p == 1) ? Yt2 : Yt3;
      *(u16x8*)&Yt[((size_t)bt*64 + d)*1024 + nb + n0] = vv;
    }
  }
  __syncthreads();

  // ---- phase3: plane 0 (cols 0..63) re-staged row-major then coalesced store
  if (wn == 0) {
    #pragma unroll
    for (int fm = 0; fm < 4; ++fm) {
      int row0 = wm*64 + fm*16 + lk*4;
      #pragma unroll
      for (int fn = 0; fn < 4; ++fn) {
        int c = fn*16 + lr;
        #pragma unroll
        for (int j = 0; j < 4; ++j) {
          int row = row0 + j;
          Gls[row*64 + (c ^ ((row & 7) << 3))] = f2b(acc[fm][fn][j]);
        }
      }
    }
  }
  __syncthreads();
  #pragma unroll
  for (int i = 0; i < 4; ++i) {
    int cc = t + 256*i;
    int row = cc >> 3, ch = cc & 7;
    u16x8 vv = *(const u16x8*)&Gls[row*64 + ((ch*8) ^ ((row & 7) << 3))];
    *(u16x8*)&G0[(size_t)(m0 + row)*64 + ch*8] = vv;
  }
}

// ---- K3 (MFMA): per bt-pair, C[128 node,128 (2bt x 64 d)] = Acat[128,3072] @ Bstack
#define BM 128
#define BK 64
#define NKT (K3_/BK)   // 48
__global__ __launch_bounds__(256) void k_spatial_mfma(
    const u16* __restrict__ Acat,
    const u16* __restrict__ Yt1, const u16* __restrict__ Yt2, const u16* __restrict__ Yt3,
    const float* __restrict__ bgcn,
    u16* __restrict__ HS)
{
  __shared__ __align__(16) u16 Als[2][BM*BK];
  __shared__ __align__(16) u16 Bls[2][BM*BK];

  int f = blockIdx.x + 8*blockIdx.y;
  int u = f & 7, v = f >> 3;
  int btp = u*24 + (v >> 3);
  int m0  = (v & 7) * BM;
  int bt0 = btp * 2;

  int t = threadIdx.x;
  int w = t >> 6, l = t & 63;
  int rsub = l >> 3, pch = l & 7;

  f32x4 acc[4][4] = {};
  int wm = w >> 1, wn = w & 1;
  int lr = l & 15, lk = l >> 4;

  {
    #pragma unroll
    for (int i = 0; i < 4; ++i) {
      int R0 = w*32 + i*8;
      int row = R0 + rsub;
      int q = pch ^ (row & 7);
      gload_lds16(Acat + (size_t)(m0 + row)*K3_ + q*8, &Als[0][R0*64]);
    }
    const u16* Yt = Yt1;
    #pragma unroll
    for (int i = 0; i < 4; ++i) {
      int R0 = w*32 + i*8;
      int n = R0 + rsub;
      int q = pch ^ (n & 7);
      int bt = bt0 + (n >> 6), d = n & 63;
      gload_lds16(Yt + ((size_t)bt*64 + d)*1024 + q*8, &Bls[0][R0*64]);
    }
  }
  __syncthreads();

  int buf = 0;
  for (int kt = 0; kt < NKT; ++kt) {
    if (kt + 1 < NKT) {
      int k0 = (kt + 1) * BK;
      #pragma unroll
      for (int i = 0; i < 4; ++i) {
        int R0 = w*32 + i*8;
        int row = R0 + rsub;
        int q = pch ^ (row & 7);
        gload_lds16(Acat + (size_t)(m0 + row)*K3_ + k0 + q*8, &Als[buf^1][R0*64]);
      }
      int pl = k0 >> 10, kk = k0 & 1023;
      const u16* Yt = (pl == 0) ? Yt1 : (pl == 1) ? Yt2 : Yt3;
      #pragma unroll
      for (int i = 0; i < 4; ++i) {
        int R0 = w*32 + i*8;
        int n = R0 + rsub;
        int q = pch ^ (n & 7);
        int bt = bt0 + (n >> 6), d = n & 63;
        gload_lds16(Yt + ((size_t)bt*64 + d)*1024 + kk + q*8, &Bls[buf^1][R0*64]);
      }
    }
    const u16* A = &Als[buf][0];
    const u16* Bp = &Bls[buf][0];
    #pragma unroll
    for (int ks = 0; ks < 2; ++ks) {
      short8v av[4], bv[4];
      #pragma unroll
      for (int fm = 0; fm < 4; ++fm) {
        int r = wm*64 + fm*16 + lr;
        int p = (ks*4 + lk) ^ (r & 7);
        av[fm] = *(const short8v*)(A + r*64 + p*8);
      }
      #pragma unroll
      for (int fn = 0; fn < 4; ++fn) {
        int r = wn*64 + fn*16 + lr;
        int p = (ks*4 + lk) ^ (r & 7);
        bv[fn] = *(const short8v*)(Bp + r*64 + p*8);
      }
      #pragma unroll
      for (int fm = 0; fm < 4; ++fm)
        #pragma unroll
        for (int fn = 0; fn < 4; ++fn)
          acc[fm][fn] = __builtin_amdgcn_mfma_f32_16x16x32_bf16(av[fm], bv[fn], acc[fm][fn], 0, 0, 0);
    }
    __syncthreads();
    buf ^= 1;
  }

  #pragma unroll
  for (int fm = 0; fm < 4; ++fm) {
    int nodeb = m0 + wm*64 + fm*16 + lk*4;
    #pragma unroll
    for (int fn = 0; fn < 4; ++fn) {
      int nl = wn*64 + fn*16 + lr;
      int bt = bt0 + (nl >> 6), d = nl & 63;
      float bb = bgcn[d];
      size_t base = (size_t)bt * N_ * 64;
      #pragma unroll
      for (int j = 0; j < 4; ++j) {
        size_t idx = base + (size_t)(nodeb + j)*64 + d;
        float vv = acc[fm][fn][j] + b2f(HS[idx]) + bb;
        HS[idx] = f2b(fmaxf(vv, 0.f));
      }
    }
  }
}

// ---- K4a (MFMA): qkv = relu([X|STE] @ Wqkv^T + b) -> q,k,v bf16 [BTN][64]
__global__ __launch_bounds__(256) void k_qkv(
    const float* __restrict__ X, const float* __restrict__ STE,
    const u16* __restrict__ Wqkvt,
    const float* __restrict__ bq, const float* __restrict__ bk, const float* __restrict__ bv,
    u16* __restrict__ qb, u16* __restrict__ kb, u16* __restrict__ vb)
{
  __shared__ __align__(16) u16 Als[128*128];   // [row][k], chunk-swizzled
  __shared__ __align__(16) u16 Bls[192*128];   // W^T [n][k], chunk-swizzled
  int m0 = blockIdx.x * 128;
  int t = threadIdx.x;
  int w = t >> 6, l = t & 63;

  {
    int rsub = l >> 4, pch = l & 15;
    #pragma unroll
    for (int i = 0; i < 12; ++i) {
      int R0 = w*48 + i*4;
      int n = R0 + rsub;
      int sq = pch ^ (n & 7);
      gload_lds16(Wqkvt + (size_t)n*128 + sq*8, &Bls[R0*128]);
    }
  }
  #pragma unroll
  for (int i = 0; i < 8; ++i) {
    int flat = t + 256*i;
    int row = flat >> 4, c = flat & 15;
    const float* src = ((c < 8) ? X : STE) + (size_t)(m0+row)*64 + (c & 7)*8;
    float4 f0 = *(const float4*)src;
    float4 f1 = *(const float4*)(src + 4);
    u16x8 pk;
    pk.v[0]=f2b(f0.x); pk.v[1]=f2b(f0.y); pk.v[2]=f2b(f0.z); pk.v[3]=f2b(f0.w);
    pk.v[4]=f2b(f1.x); pk.v[5]=f2b(f1.y); pk.v[6]=f2b(f1.z); pk.v[7]=f2b(f1.w);
    int cs = c ^ (row & 7);
    *(u16x8*)&Als[row*128 + cs*8] = pk;
  }
  __syncthreads();

  int wm = w >> 1, wn = w & 1;
  int lr = l & 15, lk = l >> 4;
  f32x4 acc[4][6] = {};
  #pragma unroll
  for (int ks = 0; ks < 4; ++ks) {
    short8v av[4], bvv[6];
    #pragma unroll
    for (int fm = 0; fm < 4; ++fm) {
      int r = wm*64 + fm*16 + lr;
      int ch = (ks*4 + lk) ^ (r & 7);
      av[fm] = *(const short8v*)&Als[r*128 + ch*8];
    }
    #pragma unroll
    for (int fn = 0; fn < 6; ++fn) {
      int n = wn*96 + fn*16 + lr;
      int ch = (ks*4 + lk) ^ (n & 7);
      bvv[fn] = *(const short8v*)&Bls[n*128 + ch*8];
    }
    #pragma unroll
    for (int fm = 0; fm < 4; ++fm)
      #pragma unroll
      for (int fn = 0; fn < 6; ++fn)
        acc[fm][fn] = __builtin_amdgcn_mfma_f32_16x16x32_bf16(av[fm], bvv[fn], acc[fm][fn], 0, 0, 0);
  }

  #pragma unroll
  for (int fm = 0; fm < 4; ++fm) {
    int rowb = m0 + wm*64 + fm*16 + lk*4;
    #pragma unroll
    for (int fn = 0; fn < 6; ++fn) {
      int col = wn*96 + fn*16 + lr;
      int sel = col >> 6, d = col & 63;
      u16* dst = (sel == 0) ? qb : (sel == 1) ? kb : vb;
      float bias = ((sel == 0) ? bq : (sel == 1) ? bk : bv)[d];
      #pragma unroll
      for (int j = 0; j < 4; ++j) {
        float val = acc[fm][fn][j] + bias;
        dst[(size_t)(rowb + j)*64 + d] = f2b(fmaxf(val, 0.f));
      }
    }
  }
}

// ---- K4b: attention only, one wave per (b,n), all-register, shuffle reduce
__global__ __launch_bounds__(256) void k_attn_lite(
    const u16* __restrict__ qb, const u16* __restrict__ kb, const u16* __restrict__ vb,
    u16* __restrict__ ob)
{
  int w = threadIdx.x >> 6, l = threadIdx.x & 63;
  int flat = blockIdx.x*4 + w;
  int b = flat >> 10, n = flat & 1023;
  float qv[T_], kv[T_], vv[T_];
  #pragma unroll
  for (int tt = 0; tt < T_; ++tt) {
    size_t idx = ((size_t)(b*T_ + tt)*N_ + n)*64 + l;
    qv[tt] = b2f(qb[idx]); kv[tt] = b2f(kb[idx]); vv[tt] = b2f(vb[idx]);
  }
  #pragma unroll
  for (int tt = 0; tt < T_; ++tt) {
    float sc[T_];
    float mx = -1e30f;
    #pragma unroll
    for (int j = 0; j < T_; ++j) {
      float p = qv[tt]*kv[j];
      p += __shfl_xor(p, 1);
      p += __shfl_xor(p, 2);
      p += __shfl_xor(p, 4);
      sc[j] = p * 0.3535533906f;
      mx = fmaxf(mx, sc[j]);
    }
    float sum = 0.f;
    #pragma unroll
    for (int j = 0; j < T_; ++j) { sc[j] = __expf(sc[j]-mx); sum += sc[j]; }
    float o = 0.f;
    #pragma unroll
    for (int j = 0; j < T_; ++j) o += sc[j]*vv[j];
    ob[((size_t)(b*T_ + tt)*N_ + n)*64 + l] = f2b(o / sum);
  }
}

// ---- K4c (MFMA): HT = relu(o@Wx1+bx1)@Wx2+bx2, chained in LDS
__global__ __launch_bounds__(256) void k_ht(
    const u16* __restrict__ ob, const u16* __restrict__ W1t, const u16* __restrict__ W2t,
    const float* __restrict__ bx1, const float* __restrict__ bx2,
    u16* __restrict__ HT)
{
  __shared__ __align__(16) u16 Ols[128*64];
  __shared__ __align__(16) u16 W1ls[64*64];
  __shared__ __align__(16) u16 W2ls[64*64];
  __shared__ __align__(16) u16 H1ls[128*64];
  int m0 = blockIdx.x * 128;
  int t = threadIdx.x;
  int w = t >> 6, l = t & 63;
  int rsub = l >> 3, pch = l & 7;

  #pragma unroll
  for (int i = 0; i < 4; ++i) {
    int R0 = w*32 + i*8;
    int row = R0 + rsub;
    int sq = pch ^ (row & 7);
    gload_lds16(ob + (size_t)(m0 + row)*64 + sq*8, &Ols[R0*64]);
  }
  #pragma unroll
  for (int i = 0; i < 2; ++i) {
    int R0 = w*16 + i*8;
    int row = R0 + rsub;
    int sq = pch ^ (row & 7);
    gload_lds16(W1t + (size_t)row*64 + sq*8, &W1ls[R0*64]);
    gload_lds16(W2t + (size_t)row*64 + sq*8, &W2ls[R0*64]);
  }
  __syncthreads();

  int wm = w >> 1, wn = w & 1;
  int lr = l & 15, lk = l >> 4;
  f32x4 acc1[4][2] = {};
  #pragma unroll
  for (int ks = 0; ks < 2; ++ks) {
    short8v av[4], bvv[2];
    #pragma unroll
    for (int fm = 0; fm < 4; ++fm) {
      int r = wm*64 + fm*16 + lr;
      int ch = (ks*4 + lk) ^ (r & 7);
      av[fm] = *(const short8v*)&Ols[r*64 + ch*8];
    }
    #pragma unroll
    for (int fn = 0; fn < 2; ++fn) {
      int n = wn*32 + fn*16 + lr;
      int ch = (ks*4 + lk) ^ (n & 7);
      bvv[fn] = *(const short8v*)&W1ls[n*64 + ch*8];
    }
    #pragma unroll
    for (int fm = 0; fm < 4; ++fm)
      #pragma unroll
      for (int fn = 0; fn < 2; ++fn)
        acc1[fm][fn] = __builtin_amdgcn_mfma_f32_16x16x32_bf16(av[fm], bvv[fn], acc1[fm][fn], 0, 0, 0);
  }
  #pragma unroll
  for (int fm = 0; fm < 4; ++fm) {
    #pragma unroll
    for (int fn = 0; fn < 2; ++fn) {
      int col = wn*32 + fn*16 + lr;
      float bias = bx1[col];
      #pragma unroll
      for (int j = 0; j < 4; ++j) {
        int row = wm*64 + fm*16 + lk*4 + j;
        float val = acc1[fm][fn][j] + bias;
        H1ls[row*64 + (((col >> 3) ^ (row & 7)))*8 + (col & 7)] = f2b(fmaxf(val, 0.f));
      }
    }
  }
  __syncthreads();

  f32x4 acc2[4][2] = {};
  #pragma unroll
  for (int ks = 0; ks < 2; ++ks) {
    short8v av[4], bvv[2];
    #pragma unroll
    for (int fm = 0; fm < 4; ++fm) {
      int r = wm*64 + fm*16 + lr;
      int ch = (ks*4 + lk) ^ (r & 7);
      av[fm] = *(const short8v*)&H1ls[r*64 + ch*8];
    }
    #pragma unroll
    for (int fn = 0; fn < 2; ++fn) {
      int n = wn*32 + fn*16 + lr;
      int ch = (ks*4 + lk) ^ (n & 7);
      bvv[fn] = *(const short8v*)&W2ls[n*64 + ch*8];
    }
    #pragma unroll
    for (int fm = 0; fm < 4; ++fm)
      #pragma unroll
      for (int fn = 0; fn < 2; ++fn)
        acc2[fm][fn] = __builtin_amdgcn_mfma_f32_16x16x32_bf16(av[fm], bvv[fn], acc2[fm][fn], 0, 0, 0);
  }
  #pragma unroll
  for (int fm = 0; fm < 4; ++fm) {
    #pragma unroll
    for (int fn = 0; fn < 2; ++fn) {
      int col = wn*32 + fn*16 + lr;
      float bias = bx2[col];
      #pragma unroll
      for (int j = 0; j < 4; ++j) {
        int row = wm*64 + fm*16 + lk*4 + j;
        HT[(size_t)(m0 + row)*64 + col] = f2b(acc2[fm][fn][j] + bias);
      }
    }
  }
}

// ---- K5 (MFMA): gated fusion + output head, 128 rows/block, all-LDS chain
__global__ __launch_bounds__(256) void k_fusion_mfma(
    const float* __restrict__ X,
    const u16* __restrict__ HS, const u16* __restrict__ HT,
    const u16* __restrict__ Wstt, const u16* __restrict__ Wh1t, const u16* __restrict__ Wh2t,
    const float* __restrict__ btb, const float* __restrict__ bh1, const float* __restrict__ bh2,
    float* __restrict__ out)
{
  __shared__ __align__(16) u16 Als[128*128];
  __shared__ __align__(16) u16 Wst[64*128];
  __shared__ __align__(16) u16 W1ls[64*64];
  __shared__ __align__(16) u16 W2ls[64*64];
  __shared__ __align__(16) u16 Hls[128*64];
  int m0 = blockIdx.x * 128;
  int t = threadIdx.x;
  int w = t >> 6, l = t & 63;

  {
    int rsub = l >> 4, pch = l & 15;
    #pragma unroll
    for (int i = 0; i < 8; ++i) {
      int R0 = w*32 + i*4;
      int row = R0 + rsub;
      int q = pch ^ (row & 7);
      const u16* src = (q < 8) ? (HS + (size_t)(m0 + row)*64 + q*8)
                               : (HT + (size_t)(m0 + row)*64 + (q - 8)*8);
      gload_lds16(src, &Als[R0*128]);
    }
    #pragma unroll
    for (int i = 0; i < 4; ++i) {
      int R0 = w*16 + i*4;
      int n = R0 + rsub;
      int q = pch ^ (n & 7);
      gload_lds16(Wstt + (size_t)n*128 + q*8, &Wst[R0*128]);
    }
  }
  {
    int rsub = l >> 3, pch = l & 7;
    #pragma unroll
    for (int i = 0; i < 2; ++i) {
      int R0 = w*16 + i*8;
      int row = R0 + rsub;
      int q = pch ^ (row & 7);
      gload_lds16(Wh1t + (size_t)row*64 + q*8, &W1ls[R0*64]);
      gload_lds16(Wh2t + (size_t)row*64 + q*8, &W2ls[R0*64]);
    }
  }
  __syncthreads();

  int lr = l & 15, lk = l >> 4;
  f32x4 acc1[2][4] = {};
  #pragma unroll
  for (int ks = 0; ks < 4; ++ks) {
    short8v av[2], bvv[4];
    #pragma unroll
    for (int fm = 0; fm < 2; ++fm) {
      int r = w*32 + fm*16 + lr;
      int ch = (ks*4 + lk) ^ (r & 7);
      av[fm] = *(const short8v*)&Als[r*128 + ch*8];
    }
    #pragma unroll
    for (int fn = 0; fn < 4; ++fn) {
      int n = fn*16 + lr;
      int ch = (ks*4 + lk) ^ (n & 7);
      bvv[fn] = *(const short8v*)&Wst[n*128 + ch*8];
    }
    #pragma unroll
    for (int fm = 0; fm < 2; ++fm)
      #pragma unroll
      for (int fn = 0; fn < 4; ++fn)
        acc1[fm][fn] = __builtin_amdgcn_mfma_f32_16x16x32_bf16(av[fm], bvv[fn], acc1[fm][fn], 0, 0, 0);
  }
  #pragma unroll
  for (int fm = 0; fm < 2; ++fm) {
    #pragma unroll
    for (int fn = 0; fn < 4; ++fn) {
      int col = fn*16 + lr;
      float bb = btb[col];
      #pragma unroll
      for (int j = 0; j < 4; ++j) {
        int row = w*32 + fm*16 + lk*4 + j;
        float a_s = acc1[fm][fn][j] + bb;
        float zg = 1.f/(1.f + __expf(-a_s));
        int cs = (col >> 3) ^ (row & 7);
        float hs = b2f(Als[row*128 + cs*8 + (col & 7)]);
        float ht = b2f(Als[row*128 + (cs + 8)*8 + (col & 7)]);
        float H = zg*hs + (1.f - zg)*ht;
        Hls[row*64 + cs*8 + (col & 7)] = f2b(H);
      }
    }
  }
  __syncthreads();

  u16* H2ls = Wst;
  f32x4 acc2[2][4] = {};
  #pragma unroll
  for (int ks = 0; ks < 2; ++ks) {
    short8v av[2], bvv[4];
    #pragma unroll
    for (int fm = 0; fm < 2; ++fm) {
      int r = w*32 + fm*16 + lr;
      int ch = (ks*4 + lk) ^ (r & 7);
      av[fm] = *(const short8v*)&Hls[r*64 + ch*8];
    }
    #pragma unroll
    for (int fn = 0; fn < 4; ++fn) {
      int n = fn*16 + lr;
      int ch = (ks*4 + lk) ^ (n & 7);
      bvv[fn] = *(const short8v*)&W1ls[n*64 + ch*8];
    }
    #pragma unroll
    for (int fm = 0; fm < 2; ++fm)
      #pragma unroll
      for (int fn = 0; fn < 4; ++fn)
        acc2[fm][fn] = __builtin_amdgcn_mfma_f32_16x16x32_bf16(av[fm], bvv[fn], acc2[fm][fn], 0, 0, 0);
  }
  __syncthreads();
  #pragma unroll
  for (int fm = 0; fm < 2; ++fm) {
    #pragma unroll
    for (int fn = 0; fn < 4; ++fn) {
      int col = fn*16 + lr;
      float bias = bh1[col];
      #pragma unroll
      for (int j = 0; j < 4; ++j) {
        int row = w*32 + fm*16 + lk*4 + j;
        float val = acc2[fm][fn][j] + bias;
        int cs = (col >> 3) ^ (row & 7);
        H2ls[row*64 + cs*8 + (col & 7)] = f2b(fmaxf(val, 0.f));
      }
    }
  }
  __syncthreads();

  f32x4 acc3[2][4] = {};
  #pragma unroll
  for (int ks = 0; ks < 2; ++ks) {
    short8v av[2], bvv[4];
    #pragma unroll
    for (int fm = 0; fm < 2; ++fm) {
      int r = w*32 + fm*16 + lr;
      int ch = (ks*4 + lk) ^ (r & 7);
      av[fm] = *(const short8v*)&H2ls[r*64 + ch*8];
    }
    #pragma unroll
    for (int fn = 0; fn < 4; ++fn) {
      int n = fn*16 + lr;
      int ch = (ks*4 + lk) ^ (n & 7);
      bvv[fn] = *(const short8v*)&W2ls[n*64 + ch*8];
    }
    #pragma unroll
    for (int fm = 0; fm < 2; ++fm)
      #pragma unroll
      for (int fn = 0; fn < 4; ++fn)
        acc3[fm][fn] = __builtin_amdgcn_mfma_f32_16x16x32_bf16(av[fm], bvv[fn], acc3[fm][fn], 0, 0, 0);
  }
  #pragma unroll
  for (int fm = 0; fm < 2; ++fm) {
    #pragma unroll
    for (int fn = 0; fn < 4; ++fn) {
      int col = fn*16 + lr;
      float bias = bh2[col];
      #pragma unroll
      for (int j = 0; j < 4; ++j) {
        int row = w*32 + fm*16 + lk*4 + j;
        size_t gi = (size_t)(m0 + row)*64 + col;
        out[gi] = X[gi] + acc3[fm][fn][j] + bias;
      }
    }
  }
}

extern "C" void kernel_launch(void* const* d_in, const int* in_sizes, int n_in,
                              void* d_out, int out_size, void* d_ws, size_t ws_size,
                              hipStream_t stream) {
  const float* X    = (const float*)d_in[0];
  const float* STE  = (const float*)d_in[1];
  const float* adj  = (const float*)d_in[2];
  const float* feat0= (const float*)d_in[3];
  const float* feat1= (const float*)d_in[4];
  const float* Wq0  = (const float*)d_in[5];
  const float* Wk0  = (const float*)d_in[6];
  const float* Wq1  = (const float*)d_in[7];
  const float* Wk1  = (const float*)d_in[8];
  const float* Wgcn = (const float*)d_in[9];
  const float* bgcn = (const float*)d_in[10];
  const float* Wq   = (const float*)d_in[11];
  const float* bq   = (const float*)d_in[12];
  const float* Wk   = (const float*)d_in[13];
  const float* bk   = (const float*)d_in[14];
  const float* Wv   = (const float*)d_in[15];
  const float* bv   = (const float*)d_in[16];
  const float* Wx1  = (const float*)d_in[17];
  const float* bx1  = (const float*)d_in[18];
  const float* Wx2  = (const float*)d_in[19];
  const float* bx2  = (const float*)d_in[20];
  const float* Ws   = (const float*)d_in[21];
  const float* Wt   = (const float*)d_in[22];
  const float* btb  = (const float*)d_in[23];
  const float* Wh1  = (const float*)d_in[24];
  const float* bh1  = (const float*)d_in[25];
  const float* Wh2  = (const float*)d_in[26];
  const float* bh2  = (const float*)d_in[27];
  (void)in_sizes; (void)n_in; (void)out_size;

  // ws layout (bytes):
  //   fe      @ 0         : 1,048,576
  //   Acat    @ 1,048,576 : 6,291,456 (bf16)
  //   Wqkvt   @ 7,340,032 : 49,152;  W1t @ 7,389,184 : 8,192;  W2t @ 7,397,376 : 8,192
  //   Wstt    @ 7,405,568 : 16,384;  Wh1t @ 7,421,952 : 8,192; Wh2t @ 7,430,144 : 8,192
  //   Wgcnt   @ 7,438,336 : 32,768
  //   Yt2/q   @13,631,488 : 50,331,648
  //   Yt3/k   @63,963,136 : 50,331,648
  //   HS/G0   @114,294,784: 50,331,648   (total 164,626,432)
  //   v = d_out[0:50MB], o = d_out[50:100MB] (dead before k_fusion writes d_out)
  //   HT reuses q slot (q dead after k_attn_lite); Yt1 lives in d_out (dead before k_qkv).
  const size_t NEEDED = 164626432ull;
  if (ws_size < NEEDED) return;

  char* w = (char*)d_ws;
  float* fe    = (float*)(w);
  u16*   Acat  = (u16*)(w + 1048576);
  u16*   Wqkvt = (u16*)(w + 7340032);
  u16*   W1t   = (u16*)(w + 7389184);
  u16*   W2t   = (u16*)(w + 7397376);
  u16*   Wstt  = (u16*)(w + 7405568);
  u16*   Wh1t  = (u16*)(w + 7421952);
  u16*   Wh2t  = (u16*)(w + 7430144);
  u16*   Wgcnt = (u16*)(w + 7438336);
  u16*   Yt2   = (u16*)(w + 13631488);
  u16*   Yt3   = (u16*)(w + 63963136);
  u16*   HSb   = (u16*)(w + 114294784);
  u16*   Yt1   = (u16*)d_out;
  u16*   qb    = Yt2;
  u16*   kbuf  = Yt3;
  u16*   vbuf  = (u16*)d_out;
  u16*   obuf  = (u16*)d_out + (size_t)NROWS_*64;
  u16*   HTb   = Yt2;

  k_fe<<<dim3(N_, 4), 64, 0, stream>>>(feat0, feat1, Wq0, Wk0, Wq1, Wk1, fe);
  k_adjcopy<<<N_, 256, 0, stream>>>(adj, Acat);
  k_prep<<<1, 256, 0, stream>>>(Wq, Wk, Wv, Wx1, Wx2, Ws, Wt, Wh1, Wh2, Wgcn,
                                Wqkvt, W1t, W2t, Wstt, Wh1t, Wh2t, Wgcnt);
  k_graph_softmax<<<dim3(N_, 2), 256, 0, stream>>>(fe, Acat);
  k_xw_mfma<<<NROWS_/128, 256, 0, stream>>>(X, Wgcnt, HSb, Yt1, Yt2, Yt3);
  k_spatial_mfma<<<dim3(8, BT_/2), 256, 0, stream>>>(Acat, Yt1, Yt2, Yt3, bgcn, HSb);
  k_qkv<<<NROWS_/128, 256, 0, stream>>>(X, STE, Wqkvt, bq, bk, bv, qb, kbuf, vbuf);
  k_attn_lite<<<(B_*N_)/4, 256, 0, stream>>>(qb, kbuf, vbuf, obuf);
  k_ht<<<NROWS_/128, 256, 0, stream>>>(obuf, W1t, W2t, bx1, bx2, HTb);
  k_fusion_mfma<<<NROWS_/128, 256, 0, stream>>>(X, HSb, HTb, Wstt, Wh1t, Wh2t,
                                                btb, bh1, bh2, (float*)d_out);
}

// Round 6
// 783.703 us; speedup vs baseline: 6.8518x; 1.0184x over previous
//
#include <hip/hip_runtime.h>
#include <hip/hip_bf16.h>
#include <stdint.h>

#define B_ 32
#define T_ 12
#define N_ 1024
#define D_ 64
#define F_ 16
#define KH_ 8
#define BT_ (B_*T_)
#define NROWS_ (BT_*N_)
#define K3_ 3072

typedef unsigned short u16;
struct __align__(8) u16x4 { u16 x, y, z, w; };
struct __align__(16) u16x8 { u16 v[8]; };
typedef __attribute__((ext_vector_type(8))) short short8v;
typedef __attribute__((ext_vector_type(4))) float f32x4;

__device__ __forceinline__ float b2f(u16 u) {
  union { float f; unsigned int i; } c; c.i = ((unsigned int)u) << 16; return c.f;
}
__device__ __forceinline__ u16 f2b(float f) {
  union { float f; unsigned int i; } c; c.f = f;
  unsigned int u = c.i;
  unsigned int r = ((u >> 16) & 1u) + 0x7FFFu;
  return (u16)((u + r) >> 16);
}

__device__ __forceinline__ void gload_lds16(const void* g, void* l) {
  __builtin_amdgcn_global_load_lds(
      (const __attribute__((address_space(1))) unsigned int*)g,
      (__attribute__((address_space(3))) unsigned int*)l, 16, 0, 0);
}

// ---- K0: FEQ/FEK = relu(feat @ W) for both graphs. fe layout [4][1024][64]
__global__ void k_fe(const float* __restrict__ feat0, const float* __restrict__ feat1,
                     const float* __restrict__ Wq0, const float* __restrict__ Wk0,
                     const float* __restrict__ Wq1, const float* __restrict__ Wk1,
                     float* __restrict__ fe) {
  int r = blockIdx.x;
  int m = blockIdx.y;
  int d = threadIdx.x;
  const float* feat = (m < 2) ? feat0 : feat1;
  const float* W = (m == 0) ? Wq0 : (m == 1) ? Wk0 : (m == 2) ? Wq1 : Wk1;
  float acc = 0.f;
  #pragma unroll
  for (int f = 0; f < F_; ++f) acc += feat[r*F_ + f] * W[f*D_ + d];
  fe[((size_t)m*N_ + r)*D_ + d] = fmaxf(acc, 0.f);
}

// ---- K0b: copy adj into Acat[:, 0:1024] (bf16)
__global__ void k_adjcopy(const float* __restrict__ adj, u16* __restrict__ Acat) {
  int r = blockIdx.x;
  for (int c = threadIdx.x; c < N_; c += blockDim.x)
    Acat[(size_t)r*K3_ + c] = f2b(adj[(size_t)r*N_ + c]);
}

// ---- K0c: transpose small weights to bf16 [n][k] layouts for MFMA B-operands
__global__ void k_prep(const float* __restrict__ Wq, const float* __restrict__ Wk,
                       const float* __restrict__ Wv,
                       const float* __restrict__ Wx1, const float* __restrict__ Wx2,
                       const float* __restrict__ Ws, const float* __restrict__ Wt,
                       const float* __restrict__ Wh1, const float* __restrict__ Wh2,
                       const float* __restrict__ Wgcn,
                       u16* __restrict__ Wqkvt, u16* __restrict__ W1t, u16* __restrict__ W2t,
                       u16* __restrict__ Wstt, u16* __restrict__ Wh1t, u16* __restrict__ Wh2t,
                       u16* __restrict__ Wgcnt) {
  int t = threadIdx.x;
  for (int i = t; i < 192*128; i += 256) {
    int nn = i >> 7, kk = i & 127;
    const float* W = (nn < 64) ? Wq : (nn < 128) ? Wk : Wv;
    Wqkvt[i] = f2b(W[kk*64 + (nn & 63)]);
  }
  for (int i = t; i < 64*64; i += 256) {
    int nn = i >> 6, kk = i & 63;
    W1t[i] = f2b(Wx1[kk*64 + nn]);
    W2t[i] = f2b(Wx2[kk*64 + nn]);
    Wh1t[i] = f2b(Wh1[kk*64 + nn]);
    Wh2t[i] = f2b(Wh2[kk*64 + nn]);
  }
  for (int i = t; i < 64*128; i += 256) {
    int nn = i >> 7, kk = i & 127;
    Wstt[i] = f2b((kk < 64) ? Ws[kk*64 + nn] : Wt[(kk-64)*64 + nn]);
  }
  // Wgcnt[c][k] = Wbig[k][c] = Wgcn[(c>>6)*64 + k][c&63]
  for (int i = t; i < 256*64; i += 256) {
    int cc = i >> 6, kk = i & 63;
    Wgcnt[i] = f2b(Wgcn[(size_t)((cc >> 6)*64 + kk)*64 + (cc & 63)]);
  }
}

// ---- K1: S_g = softmax(FEQ @ FEK^T / 8) rows -> Acat[:, 1024+g*1024 ...] (bf16)
__global__ __launch_bounds__(256) void k_graph_softmax(const float* __restrict__ fe,
                                                       u16* __restrict__ Acat) {
  int r = blockIdx.x, g = blockIdx.y;
  const float* FEQ = fe + (size_t)(g*2 + 0)*N_*D_;
  const float* FEK = fe + (size_t)(g*2 + 1)*N_*D_;
  __shared__ float q[D_];
  __shared__ float red[256];
  int tid = threadIdx.x;
  if (tid < D_) q[tid] = FEQ[(size_t)r*D_ + tid];
  __syncthreads();
  float lg[4];
  float mx = -1e30f;
  #pragma unroll
  for (int j = 0; j < 4; ++j) {
    int c = tid + j*256;
    const float* kr = FEK + (size_t)c*D_;
    float acc = 0.f;
    #pragma unroll
    for (int f = 0; f < D_; ++f) acc += q[f]*kr[f];
    lg[j] = acc * 0.125f;
    mx = fmaxf(mx, lg[j]);
  }
  red[tid] = mx; __syncthreads();
  for (int s = 128; s > 0; s >>= 1) { if (tid < s) red[tid] = fmaxf(red[tid], red[tid+s]); __syncthreads(); }
  mx = red[0]; __syncthreads();
  float sum = 0.f;
  #pragma unroll
  for (int j = 0; j < 4; ++j) { lg[j] = __expf(lg[j]-mx); sum += lg[j]; }
  red[tid] = sum; __syncthreads();
  for (int s = 128; s > 0; s >>= 1) { if (tid < s) red[tid] += red[tid+s]; __syncthreads(); }
  float inv = 1.f / red[0];
  #pragma unroll
  for (int j = 0; j < 4; ++j) {
    int c = tid + j*256;
    Acat[(size_t)r*K3_ + (1+g)*N_ + c] = f2b(lg[j]*inv);
  }
}

// ---- K2 (MFMA): [BTN,64] @ Wgcnt^T[64,256] -> G0 row-major + Yt1..3 transposed [bt][d][node]
__global__ __launch_bounds__(256) void k_xw_mfma(
    const float* __restrict__ X, const u16* __restrict__ Wgcnt,
    u16* __restrict__ G0, u16* __restrict__ Yt1, u16* __restrict__ Yt2, u16* __restrict__ Yt3)
{
  __shared__ __align__(16) u16 SM[24576];
  u16* Als = SM;
  u16* Bls = SM + 8192;
  u16* Tls = SM;
  u16* Gls = SM;
  int m0 = blockIdx.x * 128;
  int t = threadIdx.x;
  int w = t >> 6, l = t & 63;

  {
    int rsub = l >> 3, pch = l & 7;
    #pragma unroll
    for (int i = 0; i < 8; ++i) {
      int R0 = w*64 + i*8;
      int n = R0 + rsub;
      int q = pch ^ (n & 7);
      gload_lds16(Wgcnt + (size_t)n*64 + q*8, &Bls[R0*64]);
    }
  }
  #pragma unroll
  for (int i = 0; i < 4; ++i) {
    int flat = t + 256*i;
    int row = flat >> 3, c = flat & 7;
    const float* src = X + (size_t)(m0+row)*64 + c*8;
    float4 f0 = *(const float4*)src;
    float4 f1 = *(const float4*)(src + 4);
    u16x8 pk;
    pk.v[0]=f2b(f0.x); pk.v[1]=f2b(f0.y); pk.v[2]=f2b(f0.z); pk.v[3]=f2b(f0.w);
    pk.v[4]=f2b(f1.x); pk.v[5]=f2b(f1.y); pk.v[6]=f2b(f1.z); pk.v[7]=f2b(f1.w);
    int cs = c ^ (row & 7);
    *(u16x8*)&Als[row*64 + cs*8] = pk;
  }
  __syncthreads();

  int wm = w & 1, wn = w >> 1;
  int lr = l & 15, lk = l >> 4;
  f32x4 acc[4][8] = {};
  #pragma unroll
  for (int ks = 0; ks < 2; ++ks) {
    short8v av[4], bv[8];
    #pragma unroll
    for (int fm = 0; fm < 4; ++fm) {
      int r = wm*64 + fm*16 + lr;
      int ch = (ks*4 + lk) ^ (r & 7);
      av[fm] = *(const short8v*)&Als[r*64 + ch*8];
    }
    #pragma unroll
    for (int fn = 0; fn < 8; ++fn) {
      int n = wn*128 + fn*16 + lr;
      int ch = (ks*4 + lk) ^ (n & 7);
      bv[fn] = *(const short8v*)&Bls[n*64 + ch*8];
    }
    #pragma unroll
    for (int fm = 0; fm < 4; ++fm)
      #pragma unroll
      for (int fn = 0; fn < 8; ++fn)
        acc[fm][fn] = __builtin_amdgcn_mfma_f32_16x16x32_bf16(av[fm], bv[fn], acc[fm][fn], 0, 0, 0);
  }
  __syncthreads();

  #pragma unroll
  for (int fm = 0; fm < 4; ++fm) {
    int row0 = wm*64 + fm*16 + lk*4;
    #pragma unroll
    for (int fn = 0; fn < 8; ++fn) {
      int c = wn*128 + fn*16 + lr;
      if (c >= 64) {
        int dp = c - 64;
        u16x4 pk{ f2b(acc[fm][fn][0]), f2b(acc[fm][fn][1]),
                  f2b(acc[fm][fn][2]), f2b(acc[fm][fn][3]) };
        *(u16x4*)&Tls[dp*128 + (row0 ^ ((dp & 7) << 3))] = pk;
      }
    }
  }
  __syncthreads();
  {
    int bt = m0 >> 10, nb = m0 & 1023;
    #pragma unroll
    for (int i = 0; i < 12; ++i) {
      int cc = t + 256*i;
      int dp = cc >> 4, nc = cc & 15;
      int n0 = nc*8;
      u16x8 vv = *(const u16x8*)&Tls[dp*128 + (n0 ^ ((dp & 7) << 3))];
      int p = dp >> 6, d = dp & 63;
      u16* Yt = (p == 0) ? Yt1 : (p == 1) ? Yt2 : Yt3;
      *(u16x8*)&Yt[((size_t)bt*64 + d)*1024 + nb + n0] = vv;
    }
  }
  __syncthreads();

  if (wn == 0) {
    #pragma unroll
    for (int fm = 0; fm < 4; ++fm) {
      int row0 = wm*64 + fm*16 + lk*4;
      #pragma unroll
      for (int fn = 0; fn < 4; ++fn) {
        int c = fn*16 + lr;
        #pragma unroll
        for (int j = 0; j < 4; ++j) {
          int row = row0 + j;
          Gls[row*64 + (c ^ ((row & 7) << 3))] = f2b(acc[fm][fn][j]);
        }
      }
    }
  }
  __syncthreads();
  #pragma unroll
  for (int i = 0; i < 4; ++i) {
    int cc = t + 256*i;
    int row = cc >> 3, ch = cc & 7;
    u16x8 vv = *(const u16x8*)&Gls[row*64 + ((ch*8) ^ ((row & 7) << 3))];
    *(u16x8*)&G0[(size_t)(m0 + row)*64 + ch*8] = vv;
  }
}

// ---- K3 (MFMA): per bt-pair, C[128 node,128 (2bt x 64 d)] = Acat[128,3072] @ Bstack
// BK=32 (32 KB LDS -> ~5 blocks/CU) + LDS-transposed coalesced epilogue.
#define BM 128
#define BK2 32
#define NKT2 (K3_/BK2)   // 96
__global__ __launch_bounds__(256) void k_spatial_mfma(
    const u16* __restrict__ Acat,
    const u16* __restrict__ Yt1, const u16* __restrict__ Yt2, const u16* __restrict__ Yt3,
    const float* __restrict__ bgcn,
    u16* __restrict__ HS)
{
  __shared__ __align__(16) u16 SM[16384];   // 32 KB total
  u16* Als = SM;          // [2][128*32]
  u16* Bls = SM + 8192;   // [2][128*32]

  int f = blockIdx.x + 8*blockIdx.y;
  int u = f & 7, v = f >> 3;
  int btp = u*24 + (v >> 3);
  int m0  = (v & 7) * BM;
  int bt0 = btp * 2;

  int t = threadIdx.x;
  int w = t >> 6, l = t & 63;
  int rsub = l >> 2, pch = l & 3;   // 16 rows x 4 chunks per gload

  f32x4 acc[4][4] = {};
  int wm = w >> 1, wn = w & 1;
  int lr = l & 15, lk = l >> 4;

  // hoisted per-thread staging sources (swizzle: slot p holds logical chunk p ^ ((row>>1)&3))
  const u16* aSrc[2];
  size_t bOff[2];
  #pragma unroll
  for (int i = 0; i < 2; ++i) {
    int row = w*32 + i*16 + rsub;
    int q = pch ^ ((row >> 1) & 3);
    aSrc[i] = Acat + (size_t)(m0 + row)*K3_ + q*8;
    int n = row;
    int qb = pch ^ ((n >> 1) & 3);
    int bt = bt0 + (n >> 6), d = n & 63;
    bOff[i] = ((size_t)bt*64 + d)*1024 + qb*8;
  }

  // prologue stage (kt = 0, plane Yt1)
  #pragma unroll
  for (int i = 0; i < 2; ++i) {
    int R0 = w*32 + i*16;
    gload_lds16(aSrc[i], &Als[R0*32]);
    gload_lds16(Yt1 + bOff[i], &Bls[R0*32]);
  }
  __syncthreads();

  int buf = 0;
  for (int kt = 0; kt < NKT2; ++kt) {
    if (kt + 1 < NKT2) {
      int k0 = (kt + 1) * BK2;
      int pl = k0 >> 10, kk = k0 & 1023;
      const u16* Yt = (pl == 0) ? Yt1 : (pl == 1) ? Yt2 : Yt3;
      int bo = (buf ^ 1) * 4096;
      #pragma unroll
      for (int i = 0; i < 2; ++i) {
        int R0 = w*32 + i*16;
        gload_lds16(aSrc[i] + k0, &Als[bo + R0*32]);
        gload_lds16(Yt + bOff[i] + kk, &Bls[bo + R0*32]);
      }
    }
    const u16* A = Als + buf*4096;
    const u16* Bp = Bls + buf*4096;
    short8v av[4], bv[4];
    #pragma unroll
    for (int fm = 0; fm < 4; ++fm) {
      int r = wm*64 + fm*16 + lr;
      int ch = lk ^ ((r >> 1) & 3);
      av[fm] = *(const short8v*)(A + r*32 + ch*8);
    }
    #pragma unroll
    for (int fn = 0; fn < 4; ++fn) {
      int n = wn*64 + fn*16 + lr;
      int ch = lk ^ ((n >> 1) & 3);
      bv[fn] = *(const short8v*)(Bp + n*32 + ch*8);
    }
    #pragma unroll
    for (int fm = 0; fm < 4; ++fm)
      #pragma unroll
      for (int fn = 0; fn < 4; ++fn)
        acc[fm][fn] = __builtin_amdgcn_mfma_f32_16x16x32_bf16(av[fm], bv[fn], acc[fm][fn], 0, 0, 0);
    __syncthreads();
    buf ^= 1;
  }

  // ---- epilogue: acc -> LDS transpose tile [128 node][128 col] (bf16, XOR-swizzled)
  u16* Tls = SM;   // 128*128 = 16384 u16 = entire LDS
  #pragma unroll
  for (int fm = 0; fm < 4; ++fm) {
    #pragma unroll
    for (int fn = 0; fn < 4; ++fn) {
      int col = wn*64 + fn*16 + lr;
      int cc = col >> 3, cw = col & 7;
      #pragma unroll
      for (int j = 0; j < 4; ++j) {
        int node = wm*64 + fm*16 + lk*4 + j;
        int sc = cc ^ (node & 7);
        Tls[node*128 + sc*8 + cw] = f2b(acc[fm][fn][j]);
      }
    }
  }
  __syncthreads();
  // coalesced RMW: HS = relu(Z + G0 + bgcn), u16x8 granularity
  #pragma unroll
  for (int i = 0; i < 8; ++i) {
    int flat = t + 256*i;
    int node = flat >> 4, cc = flat & 15;
    int sc = cc ^ (node & 7);
    u16x8 zv = *(const u16x8*)&Tls[node*128 + sc*8];
    int bt = bt0 + (cc >> 3), d0 = (cc & 7)*8;
    size_t idx = ((size_t)bt*N_ + (m0 + node))*64 + d0;
    u16x8 gv = *(const u16x8*)&HS[idx];
    float4 b0 = *(const float4*)&bgcn[d0];
    float4 b1 = *(const float4*)&bgcn[d0 + 4];
    float bb[8] = { b0.x, b0.y, b0.z, b0.w, b1.x, b1.y, b1.z, b1.w };
    u16x8 ov;
    #pragma unroll
    for (int e = 0; e < 8; ++e) {
      float vv2 = b2f(zv.v[e]) + b2f(gv.v[e]) + bb[e];
      ov.v[e] = f2b(fmaxf(vv2, 0.f));
    }
    *(u16x8*)&HS[idx] = ov;
  }
}

// ---- K4a (MFMA): qkv = relu([X|STE] @ Wqkv^T + b) -> q,k,v bf16 [BTN][64]
__global__ __launch_bounds__(256) void k_qkv(
    const float* __restrict__ X, const float* __restrict__ STE,
    const u16* __restrict__ Wqkvt,
    const float* __restrict__ bq, const float* __restrict__ bk, const float* __restrict__ bv,
    u16* __restrict__ qb, u16* __restrict__ kb, u16* __restrict__ vb)
{
  __shared__ __align__(16) u16 Als[128*128];   // [row][k], chunk-swizzled
  __shared__ __align__(16) u16 Bls[192*128];   // W^T [n][k], chunk-swizzled
  int m0 = blockIdx.x * 128;
  int t = threadIdx.x;
  int w = t >> 6, l = t & 63;

  {
    int rsub = l >> 4, pch = l & 15;
    #pragma unroll
    for (int i = 0; i < 12; ++i) {
      int R0 = w*48 + i*4;
      int n = R0 + rsub;
      int sq = pch ^ (n & 7);
      gload_lds16(Wqkvt + (size_t)n*128 + sq*8, &Bls[R0*128]);
    }
  }
  #pragma unroll
  for (int i = 0; i < 8; ++i) {
    int flat = t + 256*i;
    int row = flat >> 4, c = flat & 15;
    const float* src = ((c < 8) ? X : STE) + (size_t)(m0+row)*64 + (c & 7)*8;
    float4 f0 = *(const float4*)src;
    float4 f1 = *(const float4*)(src + 4);
    u16x8 pk;
    pk.v[0]=f2b(f0.x); pk.v[1]=f2b(f0.y); pk.v[2]=f2b(f0.z); pk.v[3]=f2b(f0.w);
    pk.v[4]=f2b(f1.x); pk.v[5]=f2b(f1.y); pk.v[6]=f2b(f1.z); pk.v[7]=f2b(f1.w);
    int cs = c ^ (row & 7);
    *(u16x8*)&Als[row*128 + cs*8] = pk;
  }
  __syncthreads();

  int wm = w >> 1, wn = w & 1;
  int lr = l & 15, lk = l >> 4;
  f32x4 acc[4][6] = {};
  #pragma unroll
  for (int ks = 0; ks < 4; ++ks) {
    short8v av[4], bvv[6];
    #pragma unroll
    for (int fm = 0; fm < 4; ++fm) {
      int r = wm*64 + fm*16 + lr;
      int ch = (ks*4 + lk) ^ (r & 7);
      av[fm] = *(const short8v*)&Als[r*128 + ch*8];
    }
    #pragma unroll
    for (int fn = 0; fn < 6; ++fn) {
      int n = wn*96 + fn*16 + lr;
      int ch = (ks*4 + lk) ^ (n & 7);
      bvv[fn] = *(const short8v*)&Bls[n*128 + ch*8];
    }
    #pragma unroll
    for (int fm = 0; fm < 4; ++fm)
      #pragma unroll
      for (int fn = 0; fn < 6; ++fn)
        acc[fm][fn] = __builtin_amdgcn_mfma_f32_16x16x32_bf16(av[fm], bvv[fn], acc[fm][fn], 0, 0, 0);
  }

  #pragma unroll
  for (int fm = 0; fm < 4; ++fm) {
    int rowb = m0 + wm*64 + fm*16 + lk*4;
    #pragma unroll
    for (int fn = 0; fn < 6; ++fn) {
      int col = wn*96 + fn*16 + lr;
      int sel = col >> 6, d = col & 63;
      u16* dst = (sel == 0) ? qb : (sel == 1) ? kb : vb;
      float bias = ((sel == 0) ? bq : (sel == 1) ? bk : bv)[d];
      #pragma unroll
      for (int j = 0; j < 4; ++j) {
        float val = acc[fm][fn][j] + bias;
        dst[(size_t)(rowb + j)*64 + d] = f2b(fmaxf(val, 0.f));
      }
    }
  }
}

// ---- K4b: attention only, one wave per (b,n), all-register, shuffle reduce
__global__ __launch_bounds__(256) void k_attn_lite(
    const u16* __restrict__ qb, const u16* __restrict__ kb, const u16* __restrict__ vb,
    u16* __restrict__ ob)
{
  int w = threadIdx.x >> 6, l = threadIdx.x & 63;
  int flat = blockIdx.x*4 + w;
  int b = flat >> 10, n = flat & 1023;
  float qv[T_], kv[T_], vv[T_];
  #pragma unroll
  for (int tt = 0; tt < T_; ++tt) {
    size_t idx = ((size_t)(b*T_ + tt)*N_ + n)*64 + l;
    qv[tt] = b2f(qb[idx]); kv[tt] = b2f(kb[idx]); vv[tt] = b2f(vb[idx]);
  }
  #pragma unroll
  for (int tt = 0; tt < T_; ++tt) {
    float sc[T_];
    float mx = -1e30f;
    #pragma unroll
    for (int j = 0; j < T_; ++j) {
      float p = qv[tt]*kv[j];
      p += __shfl_xor(p, 1);
      p += __shfl_xor(p, 2);
      p += __shfl_xor(p, 4);
      sc[j] = p * 0.3535533906f;
      mx = fmaxf(mx, sc[j]);
    }
    float sum = 0.f;
    #pragma unroll
    for (int j = 0; j < T_; ++j) { sc[j] = __expf(sc[j]-mx); sum += sc[j]; }
    float o = 0.f;
    #pragma unroll
    for (int j = 0; j < T_; ++j) o += sc[j]*vv[j];
    ob[((size_t)(b*T_ + tt)*N_ + n)*64 + l] = f2b(o / sum);
  }
}

// ---- K4c (MFMA): HT = relu(o@Wx1+bx1)@Wx2+bx2, chained in LDS
__global__ __launch_bounds__(256) void k_ht(
    const u16* __restrict__ ob, const u16* __restrict__ W1t, const u16* __restrict__ W2t,
    const float* __restrict__ bx1, const float* __restrict__ bx2,
    u16* __restrict__ HT)
{
  __shared__ __align__(16) u16 Ols[128*64];
  __shared__ __align__(16) u16 W1ls[64*64];
  __shared__ __align__(16) u16 W2ls[64*64];
  __shared__ __align__(16) u16 H1ls[128*64];
  int m0 = blockIdx.x * 128;
  int t = threadIdx.x;
  int w = t >> 6, l = t & 63;
  int rsub = l >> 3, pch = l & 7;

  #pragma unroll
  for (int i = 0; i < 4; ++i) {
    int R0 = w*32 + i*8;
    int row = R0 + rsub;
    int sq = pch ^ (row & 7);
    gload_lds16(ob + (size_t)(m0 + row)*64 + sq*8, &Ols[R0*64]);
  }
  #pragma unroll
  for (int i = 0; i < 2; ++i) {
    int R0 = w*16 + i*8;
    int row = R0 + rsub;
    int sq = pch ^ (row & 7);
    gload_lds16(W1t + (size_t)row*64 + sq*8, &W1ls[R0*64]);
    gload_lds16(W2t + (size_t)row*64 + sq*8, &W2ls[R0*64]);
  }
  __syncthreads();

  int wm = w >> 1, wn = w & 1;
  int lr = l & 15, lk = l >> 4;
  f32x4 acc1[4][2] = {};
  #pragma unroll
  for (int ks = 0; ks < 2; ++ks) {
    short8v av[4], bvv[2];
    #pragma unroll
    for (int fm = 0; fm < 4; ++fm) {
      int r = wm*64 + fm*16 + lr;
      int ch = (ks*4 + lk) ^ (r & 7);
      av[fm] = *(const short8v*)&Ols[r*64 + ch*8];
    }
    #pragma unroll
    for (int fn = 0; fn < 2; ++fn) {
      int n = wn*32 + fn*16 + lr;
      int ch = (ks*4 + lk) ^ (n & 7);
      bvv[fn] = *(const short8v*)&W1ls[n*64 + ch*8];
    }
    #pragma unroll
    for (int fm = 0; fm < 4; ++fm)
      #pragma unroll
      for (int fn = 0; fn < 2; ++fn)
        acc1[fm][fn] = __builtin_amdgcn_mfma_f32_16x16x32_bf16(av[fm], bvv[fn], acc1[fm][fn], 0, 0, 0);
  }
  #pragma unroll
  for (int fm = 0; fm < 4; ++fm) {
    #pragma unroll
    for (int fn = 0; fn < 2; ++fn) {
      int col = wn*32 + fn*16 + lr;
      float bias = bx1[col];
      #pragma unroll
      for (int j = 0; j < 4; ++j) {
        int row = wm*64 + fm*16 + lk*4 + j;
        float val = acc1[fm][fn][j] + bias;
        H1ls[row*64 + (((col >> 3) ^ (row & 7)))*8 + (col & 7)] = f2b(fmaxf(val, 0.f));
      }
    }
  }
  __syncthreads();

  f32x4 acc2[4][2] = {};
  #pragma unroll
  for (int ks = 0; ks < 2; ++ks) {
    short8v av[4], bvv[2];
    #pragma unroll
    for (int fm = 0; fm < 4; ++fm) {
      int r = wm*64 + fm*16 + lr;
      int ch = (ks*4 + lk) ^ (r & 7);
      av[fm] = *(const short8v*)&H1ls[r*64 + ch*8];
    }
    #pragma unroll
    for (int fn = 0; fn < 2; ++fn) {
      int n = wn*32 + fn*16 + lr;
      int ch = (ks*4 + lk) ^ (n & 7);
      bvv[fn] = *(const short8v*)&W2ls[n*64 + ch*8];
    }
    #pragma unroll
    for (int fm = 0; fm < 4; ++fm)
      #pragma unroll
      for (int fn = 0; fn < 2; ++fn)
        acc2[fm][fn] = __builtin_amdgcn_mfma_f32_16x16x32_bf16(av[fm], bvv[fn], acc2[fm][fn], 0, 0, 0);
  }
  #pragma unroll
  for (int fm = 0; fm < 4; ++fm) {
    #pragma unroll
    for (int fn = 0; fn < 2; ++fn) {
      int col = wn*32 + fn*16 + lr;
      float bias = bx2[col];
      #pragma unroll
      for (int j = 0; j < 4; ++j) {
        int row = wm*64 + fm*16 + lk*4 + j;
        HT[(size_t)(m0 + row)*64 + col] = f2b(acc2[fm][fn][j] + bias);
      }
    }
  }
}

// ---- K5 (MFMA): gated fusion + output head, 128 rows/block, all-LDS chain
__global__ __launch_bounds__(256) void k_fusion_mfma(
    const float* __restrict__ X,
    const u16* __restrict__ HS, const u16* __restrict__ HT,
    const u16* __restrict__ Wstt, const u16* __restrict__ Wh1t, const u16* __restrict__ Wh2t,
    const float* __restrict__ btb, const float* __restrict__ bh1, const float* __restrict__ bh2,
    float* __restrict__ out)
{
  __shared__ __align__(16) u16 Als[128*128];
  __shared__ __align__(16) u16 Wst[64*128];
  __shared__ __align__(16) u16 W1ls[64*64];
  __shared__ __align__(16) u16 W2ls[64*64];
  __shared__ __align__(16) u16 Hls[128*64];
  int m0 = blockIdx.x * 128;
  int t = threadIdx.x;
  int w = t >> 6, l = t & 63;

  {
    int rsub = l >> 4, pch = l & 15;
    #pragma unroll
    for (int i = 0; i < 8; ++i) {
      int R0 = w*32 + i*4;
      int row = R0 + rsub;
      int q = pch ^ (row & 7);
      const u16* src = (q < 8) ? (HS + (size_t)(m0 + row)*64 + q*8)
                               : (HT + (size_t)(m0 + row)*64 + (q - 8)*8);
      gload_lds16(src, &Als[R0*128]);
    }
    #pragma unroll
    for (int i = 0; i < 4; ++i) {
      int R0 = w*16 + i*4;
      int n = R0 + rsub;
      int q = pch ^ (n & 7);
      gload_lds16(Wstt + (size_t)n*128 + q*8, &Wst[R0*128]);
    }
  }
  {
    int rsub = l >> 3, pch = l & 7;
    #pragma unroll
    for (int i = 0; i < 2; ++i) {
      int R0 = w*16 + i*8;
      int row = R0 + rsub;
      int q = pch ^ (row & 7);
      gload_lds16(Wh1t + (size_t)row*64 + q*8, &W1ls[R0*64]);
      gload_lds16(Wh2t + (size_t)row*64 + q*8, &W2ls[R0*64]);
    }
  }
  __syncthreads();

  int lr = l & 15, lk = l >> 4;
  f32x4 acc1[2][4] = {};
  #pragma unroll
  for (int ks = 0; ks < 4; ++ks) {
    short8v av[2], bvv[4];
    #pragma unroll
    for (int fm = 0; fm < 2; ++fm) {
      int r = w*32 + fm*16 + lr;
      int ch = (ks*4 + lk) ^ (r & 7);
      av[fm] = *(const short8v*)&Als[r*128 + ch*8];
    }
    #pragma unroll
    for (int fn = 0; fn < 4; ++fn) {
      int n = fn*16 + lr;
      int ch = (ks*4 + lk) ^ (n & 7);
      bvv[fn] = *(const short8v*)&Wst[n*128 + ch*8];
    }
    #pragma unroll
    for (int fm = 0; fm < 2; ++fm)
      #pragma unroll
      for (int fn = 0; fn < 4; ++fn)
        acc1[fm][fn] = __builtin_amdgcn_mfma_f32_16x16x32_bf16(av[fm], bvv[fn], acc1[fm][fn], 0, 0, 0);
  }
  #pragma unroll
  for (int fm = 0; fm < 2; ++fm) {
    #pragma unroll
    for (int fn = 0; fn < 4; ++fn) {
      int col = fn*16 + lr;
      float bb = btb[col];
      #pragma unroll
      for (int j = 0; j < 4; ++j) {
        int row = w*32 + fm*16 + lk*4 + j;
        float a_s = acc1[fm][fn][j] + bb;
        float zg = 1.f/(1.f + __expf(-a_s));
        int cs = (col >> 3) ^ (row & 7);
        float hs = b2f(Als[row*128 + cs*8 + (col & 7)]);
        float ht = b2f(Als[row*128 + (cs + 8)*8 + (col & 7)]);
        float H = zg*hs + (1.f - zg)*ht;
        Hls[row*64 + cs*8 + (col & 7)] = f2b(H);
      }
    }
  }
  __syncthreads();

  u16* H2ls = Wst;
  f32x4 acc2[2][4] = {};
  #pragma unroll
  for (int ks = 0; ks < 2; ++ks) {
    short8v av[2], bvv[4];
    #pragma unroll
    for (int fm = 0; fm < 2; ++fm) {
      int r = w*32 + fm*16 + lr;
      int ch = (ks*4 + lk) ^ (r & 7);
      av[fm] = *(const short8v*)&Hls[r*64 + ch*8];
    }
    #pragma unroll
    for (int fn = 0; fn < 4; ++fn) {
      int n = fn*16 + lr;
      int ch = (ks*4 + lk) ^ (n & 7);
      bvv[fn] = *(const short8v*)&W1ls[n*64 + ch*8];
    }
    #pragma unroll
    for (int fm = 0; fm < 2; ++fm)
      #pragma unroll
      for (int fn = 0; fn < 4; ++fn)
        acc2[fm][fn] = __builtin_amdgcn_mfma_f32_16x16x32_bf16(av[fm], bvv[fn], acc2[fm][fn], 0, 0, 0);
  }
  __syncthreads();
  #pragma unroll
  for (int fm = 0; fm < 2; ++fm) {
    #pragma unroll
    for (int fn = 0; fn < 4; ++fn) {
      int col = fn*16 + lr;
      float bias = bh1[col];
      #pragma unroll
      for (int j = 0; j < 4; ++j) {
        int row = w*32 + fm*16 + lk*4 + j;
        float val = acc2[fm][fn][j] + bias;
        int cs = (col >> 3) ^ (row & 7);
        H2ls[row*64 + cs*8 + (col & 7)] = f2b(fmaxf(val, 0.f));
      }
    }
  }
  __syncthreads();

  f32x4 acc3[2][4] = {};
  #pragma unroll
  for (int ks = 0; ks < 2; ++ks) {
    short8v av[2], bvv[4];
    #pragma unroll
    for (int fm = 0; fm < 2; ++fm) {
      int r = w*32 + fm*16 + lr;
      int ch = (ks*4 + lk) ^ (r & 7);
      av[fm] = *(const short8v*)&H2ls[r*64 + ch*8];
    }
    #pragma unroll
    for (int fn = 0; fn < 4; ++fn) {
      int n = fn*16 + lr;
      int ch = (ks*4 + lk) ^ (n & 7);
      bvv[fn] = *(const short8v*)&W2ls[n*64 + ch*8];
    }
    #pragma unroll
    for (int fm = 0; fm < 2; ++fm)
      #pragma unroll
      for (int fn = 0; fn < 4; ++fn)
        acc3[fm][fn] = __builtin_amdgcn_mfma_f32_16x16x32_bf16(av[fm], bvv[fn], acc3[fm][fn], 0, 0, 0);
  }
  #pragma unroll
  for (int fm = 0; fm < 2; ++fm) {
    #pragma unroll
    for (int fn = 0; fn < 4; ++fn) {
      int col = fn*16 + lr;
      float bias = bh2[col];
      #pragma unroll
      for (int j = 0; j < 4; ++j) {
        int row = w*32 + fm*16 + lk*4 + j;
        size_t gi = (size_t)(m0 + row)*64 + col;
        out[gi] = X[gi] + acc3[fm][fn][j] + bias;
      }
    }
  }
}

extern "C" void kernel_launch(void* const* d_in, const int* in_sizes, int n_in,
                              void* d_out, int out_size, void* d_ws, size_t ws_size,
                              hipStream_t stream) {
  const float* X    = (const float*)d_in[0];
  const float* STE  = (const float*)d_in[1];
  const float* adj  = (const float*)d_in[2];
  const float* feat0= (const float*)d_in[3];
  const float* feat1= (const float*)d_in[4];
  const float* Wq0  = (const float*)d_in[5];
  const float* Wk0  = (const float*)d_in[6];
  const float* Wq1  = (const float*)d_in[7];
  const float* Wk1  = (const float*)d_in[8];
  const float* Wgcn = (const float*)d_in[9];
  const float* bgcn = (const float*)d_in[10];
  const float* Wq   = (const float*)d_in[11];
  const float* bq   = (const float*)d_in[12];
  const float* Wk   = (const float*)d_in[13];
  const float* bk   = (const float*)d_in[14];
  const float* Wv   = (const float*)d_in[15];
  const float* bv   = (const float*)d_in[16];
  const float* Wx1  = (const float*)d_in[17];
  const float* bx1  = (const float*)d_in[18];
  const float* Wx2  = (const float*)d_in[19];
  const float* bx2  = (const float*)d_in[20];
  const float* Ws   = (const float*)d_in[21];
  const float* Wt   = (const float*)d_in[22];
  const float* btb  = (const float*)d_in[23];
  const float* Wh1  = (const float*)d_in[24];
  const float* bh1  = (const float*)d_in[25];
  const float* Wh2  = (const float*)d_in[26];
  const float* bh2  = (const float*)d_in[27];
  (void)in_sizes; (void)n_in; (void)out_size;

  // ws layout: see R5 comment (unchanged)
  const size_t NEEDED = 164626432ull;
  if (ws_size < NEEDED) return;

  char* w = (char*)d_ws;
  float* fe    = (float*)(w);
  u16*   Acat  = (u16*)(w + 1048576);
  u16*   Wqkvt = (u16*)(w + 7340032);
  u16*   W1t   = (u16*)(w + 7389184);
  u16*   W2t   = (u16*)(w + 7397376);
  u16*   Wstt  = (u16*)(w + 7405568);
  u16*   Wh1t  = (u16*)(w + 7421952);
  u16*   Wh2t  = (u16*)(w + 7430144);
  u16*   Wgcnt = (u16*)(w + 7438336);
  u16*   Yt2   = (u16*)(w + 13631488);
  u16*   Yt3   = (u16*)(w + 63963136);
  u16*   HSb   = (u16*)(w + 114294784);
  u16*   Yt1   = (u16*)d_out;
  u16*   qb    = Yt2;
  u16*   kbuf  = Yt3;
  u16*   vbuf  = (u16*)d_out;
  u16*   obuf  = (u16*)d_out + (size_t)NROWS_*64;
  u16*   HTb   = Yt2;

  k_fe<<<dim3(N_, 4), 64, 0, stream>>>(feat0, feat1, Wq0, Wk0, Wq1, Wk1, fe);
  k_adjcopy<<<N_, 256, 0, stream>>>(adj, Acat);
  k_prep<<<1, 256, 0, stream>>>(Wq, Wk, Wv, Wx1, Wx2, Ws, Wt, Wh1, Wh2, Wgcn,
                                Wqkvt, W1t, W2t, Wstt, Wh1t, Wh2t, Wgcnt);
  k_graph_softmax<<<dim3(N_, 2), 256, 0, stream>>>(fe, Acat);
  k_xw_mfma<<<NROWS_/128, 256, 0, stream>>>(X, Wgcnt, HSb, Yt1, Yt2, Yt3);
  k_spatial_mfma<<<dim3(8, BT_/2), 256, 0, stream>>>(Acat, Yt1, Yt2, Yt3, bgcn, HSb);
  k_qkv<<<NROWS_/128, 256, 0, stream>>>(X, STE, Wqkvt, bq, bk, bv, qb, kbuf, vbuf);
  k_attn_lite<<<(B_*N_)/4, 256, 0, stream>>>(qb, kbuf, vbuf, obuf);
  k_ht<<<NROWS_/128, 256, 0, stream>>>(obuf, W1t, W2t, bx1, bx2, HTb);
  k_fusion_mfma<<<NROWS_/128, 256, 0, stream>>>(X, HSb, HTb, Wstt, Wh1t, Wh2t,
                                                btb, bh1, bh2, (float*)d_out);
}

// Round 7
// 750.394 us; speedup vs baseline: 7.1559x; 1.0444x over previous
//
#include <hip/hip_runtime.h>
#include <hip/hip_bf16.h>
#include <stdint.h>

#define B_ 32
#define T_ 12
#define N_ 1024
#define D_ 64
#define F_ 16
#define KH_ 8
#define BT_ (B_*T_)
#define NROWS_ (BT_*N_)
#define K3_ 3072

typedef unsigned short u16;
struct __align__(8) u16x4 { u16 x, y, z, w; };
struct __align__(16) u16x8 { u16 v[8]; };
typedef __attribute__((ext_vector_type(8))) short short8v;
typedef __attribute__((ext_vector_type(4))) float f32x4;

__device__ __forceinline__ float b2f(u16 u) {
  union { float f; unsigned int i; } c; c.i = ((unsigned int)u) << 16; return c.f;
}
__device__ __forceinline__ u16 f2b(float f) {
  union { float f; unsigned int i; } c; c.f = f;
  unsigned int u = c.i;
  unsigned int r = ((u >> 16) & 1u) + 0x7FFFu;
  return (u16)((u + r) >> 16);
}

__device__ __forceinline__ void gload_lds16(const void* g, void* l) {
  __builtin_amdgcn_global_load_lds(
      (const __attribute__((address_space(1))) unsigned int*)g,
      (__attribute__((address_space(3))) unsigned int*)l, 16, 0, 0);
}

// ---- K0: FEQ/FEK = relu(feat @ W) for both graphs. fe layout [4][1024][64]
__global__ void k_fe(const float* __restrict__ feat0, const float* __restrict__ feat1,
                     const float* __restrict__ Wq0, const float* __restrict__ Wk0,
                     const float* __restrict__ Wq1, const float* __restrict__ Wk1,
                     float* __restrict__ fe) {
  int r = blockIdx.x;
  int m = blockIdx.y;
  int d = threadIdx.x;
  const float* feat = (m < 2) ? feat0 : feat1;
  const float* W = (m == 0) ? Wq0 : (m == 1) ? Wk0 : (m == 2) ? Wq1 : Wk1;
  float acc = 0.f;
  #pragma unroll
  for (int f = 0; f < F_; ++f) acc += feat[r*F_ + f] * W[f*D_ + d];
  fe[((size_t)m*N_ + r)*D_ + d] = fmaxf(acc, 0.f);
}

// ---- K0b: copy adj into Acat[:, 0:1024] (bf16)
__global__ void k_adjcopy(const float* __restrict__ adj, u16* __restrict__ Acat) {
  int r = blockIdx.x;
  for (int c = threadIdx.x; c < N_; c += blockDim.x)
    Acat[(size_t)r*K3_ + c] = f2b(adj[(size_t)r*N_ + c]);
}

// ---- K0c: transpose small weights to bf16 [n][k] layouts (gridded, 64 blocks)
__global__ void k_prep(const float* __restrict__ Wq, const float* __restrict__ Wk,
                       const float* __restrict__ Wv,
                       const float* __restrict__ Wx1, const float* __restrict__ Wx2,
                       const float* __restrict__ Ws, const float* __restrict__ Wt,
                       const float* __restrict__ Wh1, const float* __restrict__ Wh2,
                       const float* __restrict__ Wgcn,
                       u16* __restrict__ Wqkvt, u16* __restrict__ W1t, u16* __restrict__ W2t,
                       u16* __restrict__ Wstt, u16* __restrict__ Wh1t, u16* __restrict__ Wh2t,
                       u16* __restrict__ Wgcnt) {
  int g0 = blockIdx.x*256 + threadIdx.x;
  const int stride = 64*256;
  for (int i = g0; i < 192*128; i += stride) {
    int nn = i >> 7, kk = i & 127;
    const float* W = (nn < 64) ? Wq : (nn < 128) ? Wk : Wv;
    Wqkvt[i] = f2b(W[kk*64 + (nn & 63)]);
  }
  for (int i = g0; i < 64*64; i += stride) {
    int nn = i >> 6, kk = i & 63;
    W1t[i] = f2b(Wx1[kk*64 + nn]);
    W2t[i] = f2b(Wx2[kk*64 + nn]);
    Wh1t[i] = f2b(Wh1[kk*64 + nn]);
    Wh2t[i] = f2b(Wh2[kk*64 + nn]);
  }
  for (int i = g0; i < 64*128; i += stride) {
    int nn = i >> 7, kk = i & 127;
    Wstt[i] = f2b((kk < 64) ? Ws[kk*64 + nn] : Wt[(kk-64)*64 + nn]);
  }
  for (int i = g0; i < 256*64; i += stride) {
    int cc = i >> 6, kk = i & 63;
    Wgcnt[i] = f2b(Wgcn[(size_t)((cc >> 6)*64 + kk)*64 + (cc & 63)]);
  }
}

// ---- K1: S_g = softmax(FEQ @ FEK^T / 8) rows -> Acat[:, 1024+g*1024 ...] (bf16)
__global__ __launch_bounds__(256) void k_graph_softmax(const float* __restrict__ fe,
                                                       u16* __restrict__ Acat) {
  int r = blockIdx.x, g = blockIdx.y;
  const float* FEQ = fe + (size_t)(g*2 + 0)*N_*D_;
  const float* FEK = fe + (size_t)(g*2 + 1)*N_*D_;
  __shared__ float q[D_];
  __shared__ float red[256];
  int tid = threadIdx.x;
  if (tid < D_) q[tid] = FEQ[(size_t)r*D_ + tid];
  __syncthreads();
  float lg[4];
  float mx = -1e30f;
  #pragma unroll
  for (int j = 0; j < 4; ++j) {
    int c = tid + j*256;
    const float* kr = FEK + (size_t)c*D_;
    float acc = 0.f;
    #pragma unroll
    for (int f = 0; f < D_; ++f) acc += q[f]*kr[f];
    lg[j] = acc * 0.125f;
    mx = fmaxf(mx, lg[j]);
  }
  red[tid] = mx; __syncthreads();
  for (int s = 128; s > 0; s >>= 1) { if (tid < s) red[tid] = fmaxf(red[tid], red[tid+s]); __syncthreads(); }
  mx = red[0]; __syncthreads();
  float sum = 0.f;
  #pragma unroll
  for (int j = 0; j < 4; ++j) { lg[j] = __expf(lg[j]-mx); sum += lg[j]; }
  red[tid] = sum; __syncthreads();
  for (int s = 128; s > 0; s >>= 1) { if (tid < s) red[tid] += red[tid+s]; __syncthreads(); }
  float inv = 1.f / red[0];
  #pragma unroll
  for (int j = 0; j < 4; ++j) {
    int c = tid + j*256;
    Acat[(size_t)r*K3_ + (1+g)*N_ + c] = f2b(lg[j]*inv);
  }
}

// ---- K2 (MFMA): [BTN,64] @ Wgcnt^T[64,256] -> G0 row-major + Yt1..3 transposed [bt][d][node]
__global__ __launch_bounds__(256) void k_xw_mfma(
    const float* __restrict__ X, const u16* __restrict__ Wgcnt,
    u16* __restrict__ G0, u16* __restrict__ Yt1, u16* __restrict__ Yt2, u16* __restrict__ Yt3)
{
  __shared__ __align__(16) u16 SM[24576];
  u16* Als = SM;
  u16* Bls = SM + 8192;
  u16* Tls = SM;
  u16* Gls = SM;
  int m0 = blockIdx.x * 128;
  int t = threadIdx.x;
  int w = t >> 6, l = t & 63;

  {
    int rsub = l >> 3, pch = l & 7;
    #pragma unroll
    for (int i = 0; i < 8; ++i) {
      int R0 = w*64 + i*8;
      int n = R0 + rsub;
      int q = pch ^ (n & 7);
      gload_lds16(Wgcnt + (size_t)n*64 + q*8, &Bls[R0*64]);
    }
  }
  #pragma unroll
  for (int i = 0; i < 4; ++i) {
    int flat = t + 256*i;
    int row = flat >> 3, c = flat & 7;
    const float* src = X + (size_t)(m0+row)*64 + c*8;
    float4 f0 = *(const float4*)src;
    float4 f1 = *(const float4*)(src + 4);
    u16x8 pk;
    pk.v[0]=f2b(f0.x); pk.v[1]=f2b(f0.y); pk.v[2]=f2b(f0.z); pk.v[3]=f2b(f0.w);
    pk.v[4]=f2b(f1.x); pk.v[5]=f2b(f1.y); pk.v[6]=f2b(f1.z); pk.v[7]=f2b(f1.w);
    int cs = c ^ (row & 7);
    *(u16x8*)&Als[row*64 + cs*8] = pk;
  }
  __syncthreads();

  int wm = w & 1, wn = w >> 1;
  int lr = l & 15, lk = l >> 4;
  f32x4 acc[4][8] = {};
  #pragma unroll
  for (int ks = 0; ks < 2; ++ks) {
    short8v av[4], bv[8];
    #pragma unroll
    for (int fm = 0; fm < 4; ++fm) {
      int r = wm*64 + fm*16 + lr;
      int ch = (ks*4 + lk) ^ (r & 7);
      av[fm] = *(const short8v*)&Als[r*64 + ch*8];
    }
    #pragma unroll
    for (int fn = 0; fn < 8; ++fn) {
      int n = wn*128 + fn*16 + lr;
      int ch = (ks*4 + lk) ^ (n & 7);
      bv[fn] = *(const short8v*)&Bls[n*64 + ch*8];
    }
    #pragma unroll
    for (int fm = 0; fm < 4; ++fm)
      #pragma unroll
      for (int fn = 0; fn < 8; ++fn)
        acc[fm][fn] = __builtin_amdgcn_mfma_f32_16x16x32_bf16(av[fm], bv[fn], acc[fm][fn], 0, 0, 0);
  }
  __syncthreads();

  #pragma unroll
  for (int fm = 0; fm < 4; ++fm) {
    int row0 = wm*64 + fm*16 + lk*4;
    #pragma unroll
    for (int fn = 0; fn < 8; ++fn) {
      int c = wn*128 + fn*16 + lr;
      if (c >= 64) {
        int dp = c - 64;
        u16x4 pk{ f2b(acc[fm][fn][0]), f2b(acc[fm][fn][1]),
                  f2b(acc[fm][fn][2]), f2b(acc[fm][fn][3]) };
        *(u16x4*)&Tls[dp*128 + (row0 ^ ((dp & 7) << 3))] = pk;
      }
    }
  }
  __syncthreads();
  {
    int bt = m0 >> 10, nb = m0 & 1023;
    #pragma unroll
    for (int i = 0; i < 12; ++i) {
      int cc = t + 256*i;
      int dp = cc >> 4, nc = cc & 15;
      int n0 = nc*8;
      u16x8 vv = *(const u16x8*)&Tls[dp*128 + (n0 ^ ((dp & 7) << 3))];
      int p = dp >> 6, d = dp & 63;
      u16* Yt = (p == 0) ? Yt1 : (p == 1) ? Yt2 : Yt3;
      *(u16x8*)&Yt[((size_t)bt*64 + d)*1024 + nb + n0] = vv;
    }
  }
  __syncthreads();

  if (wn == 0) {
    #pragma unroll
    for (int fm = 0; fm < 4; ++fm) {
      int row0 = wm*64 + fm*16 + lk*4;
      #pragma unroll
      for (int fn = 0; fn < 4; ++fn) {
        int c = fn*16 + lr;
        #pragma unroll
        for (int j = 0; j < 4; ++j) {
          int row = row0 + j;
          Gls[row*64 + (c ^ ((row & 7) << 3))] = f2b(acc[fm][fn][j]);
        }
      }
    }
  }
  __syncthreads();
  #pragma unroll
  for (int i = 0; i < 4; ++i) {
    int cc = t + 256*i;
    int row = cc >> 3, ch = cc & 7;
    u16x8 vv = *(const u16x8*)&Gls[row*64 + ((ch*8) ^ ((row & 7) << 3))];
    *(u16x8*)&G0[(size_t)(m0 + row)*64 + ch*8] = vv;
  }
}

// ---- K3 (MFMA): per bt-pair, C[128 node,128 (2bt x 64 d)] = Acat[128,3072] @ Bstack
// 3-buffer, 2-deep pipeline with counted vmcnt (T3/T4 minimum recipe).
#define BM 128
#define BK2 32
#define NKT2 (K3_/BK2)   // 96
__global__ __launch_bounds__(256) void k_spatial_mfma(
    const u16* __restrict__ Acat,
    const u16* __restrict__ Yt1, const u16* __restrict__ Yt2, const u16* __restrict__ Yt3,
    const float* __restrict__ bgcn,
    u16* __restrict__ HS)
{
  __shared__ __align__(16) u16 SM[24576];   // 48 KB: 3 x (A 4096 + B 4096)

  int f = blockIdx.x + 8*blockIdx.y;
  int u = f & 7, v = f >> 3;
  int btp = u*24 + (v >> 3);
  int m0  = (v & 7) * BM;
  int bt0 = btp * 2;

  int t = threadIdx.x;
  int w = t >> 6, l = t & 63;
  int rsub = l >> 2, pch = l & 3;   // 16 rows x 4 chunks per gload

  f32x4 acc[4][4] = {};
  int wm = w >> 1, wn = w & 1;
  int lr = l & 15, lk = l >> 4;

  // hoisted per-thread staging sources (swizzle: slot p holds logical chunk p ^ ((row>>1)&3))
  const u16* aSrc[2];
  size_t bOff[2];
  int R0s[2];
  #pragma unroll
  for (int i = 0; i < 2; ++i) {
    int row = w*32 + i*16 + rsub;
    int q = pch ^ ((row >> 1) & 3);
    aSrc[i] = Acat + (size_t)(m0 + row)*K3_ + q*8;
    int qb = pch ^ ((row >> 1) & 3);
    int bt = bt0 + (row >> 6), d = row & 63;
    bOff[i] = ((size_t)bt*64 + d)*1024 + qb*8;
    R0s[i] = w*32 + i*16;
  }

  // prologue: stage kt=0 -> buf0, kt=1 -> buf1 (8 loads/wave in flight)
  #pragma unroll
  for (int s = 0; s < 2; ++s) {
    int k0 = s * BK2;
    const u16* Yt = Yt1;           // k0 < 1024 for kt=0,1
    #pragma unroll
    for (int i = 0; i < 2; ++i) {
      gload_lds16(aSrc[i] + k0, &SM[s*8192 + R0s[i]*32]);
      gload_lds16(Yt + bOff[i] + k0, &SM[s*8192 + 4096 + R0s[i]*32]);
    }
  }

  for (int kt = 0; kt < NKT2; ++kt) {
    // wait for the OLDEST stage only (counted vmcnt; never 0 in steady state)
    if (kt + 1 < NKT2) asm volatile("s_waitcnt vmcnt(4)" ::: "memory");
    else               asm volatile("s_waitcnt vmcnt(0)" ::: "memory");
    __builtin_amdgcn_s_barrier();

    int s = kt % 3;
    const u16* A  = SM + s*8192;
    const u16* Bp = SM + s*8192 + 4096;
    short8v av[4], bv[4];
    #pragma unroll
    for (int fm = 0; fm < 4; ++fm) {
      int r = wm*64 + fm*16 + lr;
      int ch = lk ^ ((r >> 1) & 3);
      av[fm] = *(const short8v*)(A + r*32 + ch*8);
    }
    #pragma unroll
    for (int fn = 0; fn < 4; ++fn) {
      int n = wn*64 + fn*16 + lr;
      int ch = lk ^ ((n >> 1) & 3);
      bv[fn] = *(const short8v*)(Bp + n*32 + ch*8);
    }
    #pragma unroll
    for (int fm = 0; fm < 4; ++fm)
      #pragma unroll
      for (int fn = 0; fn < 4; ++fn)
        acc[fm][fn] = __builtin_amdgcn_mfma_f32_16x16x32_bf16(av[fm], bv[fn], acc[fm][fn], 0, 0, 0);

    // stage kt+2 into buf (kt+2)%3 (safe: buf (kt-1)%3 fully consumed before this barrier)
    if (kt + 2 < NKT2) {
      int k0 = (kt + 2) * BK2;
      int pl = k0 >> 10, kk = k0 & 1023;
      const u16* Yt = (pl == 0) ? Yt1 : (pl == 1) ? Yt2 : Yt3;
      int so = ((kt + 2) % 3) * 8192;
      #pragma unroll
      for (int i = 0; i < 2; ++i) {
        gload_lds16(aSrc[i] + k0, &SM[so + R0s[i]*32]);
        gload_lds16(Yt + bOff[i] + kk, &SM[so + 4096 + R0s[i]*32]);
      }
    }
  }
  __syncthreads();

  // ---- epilogue: acc -> LDS transpose tile [128 node][128 col] (bf16, XOR-swizzled)
  u16* Tls = SM;   // first 16384 u16 = 32 KB
  #pragma unroll
  for (int fm = 0; fm < 4; ++fm) {
    #pragma unroll
    for (int fn = 0; fn < 4; ++fn) {
      int col = wn*64 + fn*16 + lr;
      int cc = col >> 3, cw = col & 7;
      #pragma unroll
      for (int j = 0; j < 4; ++j) {
        int node = wm*64 + fm*16 + lk*4 + j;
        int sc = cc ^ (node & 7);
        Tls[node*128 + sc*8 + cw] = f2b(acc[fm][fn][j]);
      }
    }
  }
  __syncthreads();
  // coalesced RMW: HS = relu(Z + G0 + bgcn), u16x8 granularity
  #pragma unroll
  for (int i = 0; i < 8; ++i) {
    int flat = t + 256*i;
    int node = flat >> 4, cc = flat & 15;
    int sc = cc ^ (node & 7);
    u16x8 zv = *(const u16x8*)&Tls[node*128 + sc*8];
    int bt = bt0 + (cc >> 3), d0 = (cc & 7)*8;
    size_t idx = ((size_t)bt*N_ + (m0 + node))*64 + d0;
    u16x8 gv = *(const u16x8*)&HS[idx];
    float4 b0 = *(const float4*)&bgcn[d0];
    float4 b1 = *(const float4*)&bgcn[d0 + 4];
    float bb[8] = { b0.x, b0.y, b0.z, b0.w, b1.x, b1.y, b1.z, b1.w };
    u16x8 ov;
    #pragma unroll
    for (int e = 0; e < 8; ++e) {
      float vv2 = b2f(zv.v[e]) + b2f(gv.v[e]) + bb[e];
      ov.v[e] = f2b(fmaxf(vv2, 0.f));
    }
    *(u16x8*)&HS[idx] = ov;
  }
}

// ---- K4a (MFMA): qkv = relu([X|STE] @ Wqkv^T + b) -> q,k,v bf16 [BTN][64]
__global__ __launch_bounds__(256) void k_qkv(
    const float* __restrict__ X, const float* __restrict__ STE,
    const u16* __restrict__ Wqkvt,
    const float* __restrict__ bq, const float* __restrict__ bk, const float* __restrict__ bv,
    u16* __restrict__ qb, u16* __restrict__ kb, u16* __restrict__ vb)
{
  __shared__ __align__(16) u16 Als[128*128];   // [row][k], chunk-swizzled
  __shared__ __align__(16) u16 Bls[192*128];   // W^T [n][k], chunk-swizzled
  int m0 = blockIdx.x * 128;
  int t = threadIdx.x;
  int w = t >> 6, l = t & 63;

  {
    int rsub = l >> 4, pch = l & 15;
    #pragma unroll
    for (int i = 0; i < 12; ++i) {
      int R0 = w*48 + i*4;
      int n = R0 + rsub;
      int sq = pch ^ (n & 7);
      gload_lds16(Wqkvt + (size_t)n*128 + sq*8, &Bls[R0*128]);
    }
  }
  #pragma unroll
  for (int i = 0; i < 8; ++i) {
    int flat = t + 256*i;
    int row = flat >> 4, c = flat & 15;
    const float* src = ((c < 8) ? X : STE) + (size_t)(m0+row)*64 + (c & 7)*8;
    float4 f0 = *(const float4*)src;
    float4 f1 = *(const float4*)(src + 4);
    u16x8 pk;
    pk.v[0]=f2b(f0.x); pk.v[1]=f2b(f0.y); pk.v[2]=f2b(f0.z); pk.v[3]=f2b(f0.w);
    pk.v[4]=f2b(f1.x); pk.v[5]=f2b(f1.y); pk.v[6]=f2b(f1.z); pk.v[7]=f2b(f1.w);
    int cs = c ^ (row & 7);
    *(u16x8*)&Als[row*128 + cs*8] = pk;
  }
  __syncthreads();

  int wm = w >> 1, wn = w & 1;
  int lr = l & 15, lk = l >> 4;
  f32x4 acc[4][6] = {};
  #pragma unroll
  for (int ks = 0; ks < 4; ++ks) {
    short8v av[4], bvv[6];
    #pragma unroll
    for (int fm = 0; fm < 4; ++fm) {
      int r = wm*64 + fm*16 + lr;
      int ch = (ks*4 + lk) ^ (r & 7);
      av[fm] = *(const short8v*)&Als[r*128 + ch*8];
    }
    #pragma unroll
    for (int fn = 0; fn < 6; ++fn) {
      int n = wn*96 + fn*16 + lr;
      int ch = (ks*4 + lk) ^ (n & 7);
      bvv[fn] = *(const short8v*)&Bls[n*128 + ch*8];
    }
    #pragma unroll
    for (int fm = 0; fm < 4; ++fm)
      #pragma unroll
      for (int fn = 0; fn < 6; ++fn)
        acc[fm][fn] = __builtin_amdgcn_mfma_f32_16x16x32_bf16(av[fm], bvv[fn], acc[fm][fn], 0, 0, 0);
  }

  #pragma unroll
  for (int fm = 0; fm < 4; ++fm) {
    int rowb = m0 + wm*64 + fm*16 + lk*4;
    #pragma unroll
    for (int fn = 0; fn < 6; ++fn) {
      int col = wn*96 + fn*16 + lr;
      int sel = col >> 6, d = col & 63;
      u16* dst = (sel == 0) ? qb : (sel == 1) ? kb : vb;
      float bias = ((sel == 0) ? bq : (sel == 1) ? bk : bv)[d];
      #pragma unroll
      for (int j = 0; j < 4; ++j) {
        float val = acc[fm][fn][j] + bias;
        dst[(size_t)(rowb + j)*64 + d] = f2b(fmaxf(val, 0.f));
      }
    }
  }
}

// ---- K4b: attention only, one wave per (b,n), all-register, shuffle reduce
__global__ __launch_bounds__(256) void k_attn_lite(
    const u16* __restrict__ qb, const u16* __restrict__ kb, const u16* __restrict__ vb,
    u16* __restrict__ ob)
{
  int w = threadIdx.x >> 6, l = threadIdx.x & 63;
  int flat = blockIdx.x*4 + w;
  int b = flat >> 10, n = flat & 1023;
  float qv[T_], kv[T_], vv[T_];
  #pragma unroll
  for (int tt = 0; tt < T_; ++tt) {
    size_t idx = ((size_t)(b*T_ + tt)*N_ + n)*64 + l;
    qv[tt] = b2f(qb[idx]); kv[tt] = b2f(kb[idx]); vv[tt] = b2f(vb[idx]);
  }
  #pragma unroll
  for (int tt = 0; tt < T_; ++tt) {
    float sc[T_];
    float mx = -1e30f;
    #pragma unroll
    for (int j = 0; j < T_; ++j) {
      float p = qv[tt]*kv[j];
      p += __shfl_xor(p, 1);
      p += __shfl_xor(p, 2);
      p += __shfl_xor(p, 4);
      sc[j] = p * 0.3535533906f;
      mx = fmaxf(mx, sc[j]);
    }
    float sum = 0.f;
    #pragma unroll
    for (int j = 0; j < T_; ++j) { sc[j] = __expf(sc[j]-mx); sum += sc[j]; }
    float o = 0.f;
    #pragma unroll
    for (int j = 0; j < T_; ++j) o += sc[j]*vv[j];
    ob[((size_t)(b*T_ + tt)*N_ + n)*64 + l] = f2b(o / sum);
  }
}

// ---- K4c (MFMA): HT = relu(o@Wx1+bx1)@Wx2+bx2, chained in LDS
__global__ __launch_bounds__(256) void k_ht(
    const u16* __restrict__ ob, const u16* __restrict__ W1t, const u16* __restrict__ W2t,
    const float* __restrict__ bx1, const float* __restrict__ bx2,
    u16* __restrict__ HT)
{
  __shared__ __align__(16) u16 Ols[128*64];
  __shared__ __align__(16) u16 W1ls[64*64];
  __shared__ __align__(16) u16 W2ls[64*64];
  __shared__ __align__(16) u16 H1ls[128*64];
  int m0 = blockIdx.x * 128;
  int t = threadIdx.x;
  int w = t >> 6, l = t & 63;
  int rsub = l >> 3, pch = l & 7;

  #pragma unroll
  for (int i = 0; i < 4; ++i) {
    int R0 = w*32 + i*8;
    int row = R0 + rsub;
    int sq = pch ^ (row & 7);
    gload_lds16(ob + (size_t)(m0 + row)*64 + sq*8, &Ols[R0*64]);
  }
  #pragma unroll
  for (int i = 0; i < 2; ++i) {
    int R0 = w*16 + i*8;
    int row = R0 + rsub;
    int sq = pch ^ (row & 7);
    gload_lds16(W1t + (size_t)row*64 + sq*8, &W1ls[R0*64]);
    gload_lds16(W2t + (size_t)row*64 + sq*8, &W2ls[R0*64]);
  }
  __syncthreads();

  int wm = w >> 1, wn = w & 1;
  int lr = l & 15, lk = l >> 4;
  f32x4 acc1[4][2] = {};
  #pragma unroll
  for (int ks = 0; ks < 2; ++ks) {
    short8v av[4], bvv[2];
    #pragma unroll
    for (int fm = 0; fm < 4; ++fm) {
      int r = wm*64 + fm*16 + lr;
      int ch = (ks*4 + lk) ^ (r & 7);
      av[fm] = *(const short8v*)&Ols[r*64 + ch*8];
    }
    #pragma unroll
    for (int fn = 0; fn < 2; ++fn) {
      int n = wn*32 + fn*16 + lr;
      int ch = (ks*4 + lk) ^ (n & 7);
      bvv[fn] = *(const short8v*)&W1ls[n*64 + ch*8];
    }
    #pragma unroll
    for (int fm = 0; fm < 4; ++fm)
      #pragma unroll
      for (int fn = 0; fn < 2; ++fn)
        acc1[fm][fn] = __builtin_amdgcn_mfma_f32_16x16x32_bf16(av[fm], bvv[fn], acc1[fm][fn], 0, 0, 0);
  }
  #pragma unroll
  for (int fm = 0; fm < 4; ++fm) {
    #pragma unroll
    for (int fn = 0; fn < 2; ++fn) {
      int col = wn*32 + fn*16 + lr;
      float bias = bx1[col];
      #pragma unroll
      for (int j = 0; j < 4; ++j) {
        int row = wm*64 + fm*16 + lk*4 + j;
        float val = acc1[fm][fn][j] + bias;
        H1ls[row*64 + (((col >> 3) ^ (row & 7)))*8 + (col & 7)] = f2b(fmaxf(val, 0.f));
      }
    }
  }
  __syncthreads();

  f32x4 acc2[4][2] = {};
  #pragma unroll
  for (int ks = 0; ks < 2; ++ks) {
    short8v av[4], bvv[2];
    #pragma unroll
    for (int fm = 0; fm < 4; ++fm) {
      int r = wm*64 + fm*16 + lr;
      int ch = (ks*4 + lk) ^ (r & 7);
      av[fm] = *(const short8v*)&H1ls[r*64 + ch*8];
    }
    #pragma unroll
    for (int fn = 0; fn < 2; ++fn) {
      int n = wn*32 + fn*16 + lr;
      int ch = (ks*4 + lk) ^ (n & 7);
      bvv[fn] = *(const short8v*)&W2ls[n*64 + ch*8];
    }
    #pragma unroll
    for (int fm = 0; fm < 4; ++fm)
      #pragma unroll
      for (int fn = 0; fn < 2; ++fn)
        acc2[fm][fn] = __builtin_amdgcn_mfma_f32_16x16x32_bf16(av[fm], bvv[fn], acc2[fm][fn], 0, 0, 0);
  }
  #pragma unroll
  for (int fm = 0; fm < 4; ++fm) {
    #pragma unroll
    for (int fn = 0; fn < 2; ++fn) {
      int col = wn*32 + fn*16 + lr;
      float bias = bx2[col];
      #pragma unroll
      for (int j = 0; j < 4; ++j) {
        int row = wm*64 + fm*16 + lk*4 + j;
        HT[(size_t)(m0 + row)*64 + col] = f2b(acc2[fm][fn][j] + bias);
      }
    }
  }
}

// ---- K5 (MFMA): gated fusion + output head, 128 rows/block, all-LDS chain
__global__ __launch_bounds__(256) void k_fusion_mfma(
    const float* __restrict__ X,
    const u16* __restrict__ HS, const u16* __restrict__ HT,
    const u16* __restrict__ Wstt, const u16* __restrict__ Wh1t, const u16* __restrict__ Wh2t,
    const float* __restrict__ btb, const float* __restrict__ bh1, const float* __restrict__ bh2,
    float* __restrict__ out)
{
  __shared__ __align__(16) u16 Als[128*128];
  __shared__ __align__(16) u16 Wst[64*128];
  __shared__ __align__(16) u16 W1ls[64*64];
  __shared__ __align__(16) u16 W2ls[64*64];
  __shared__ __align__(16) u16 Hls[128*64];
  int m0 = blockIdx.x * 128;
  int t = threadIdx.x;
  int w = t >> 6, l = t & 63;

  {
    int rsub = l >> 4, pch = l & 15;
    #pragma unroll
    for (int i = 0; i < 8; ++i) {
      int R0 = w*32 + i*4;
      int row = R0 + rsub;
      int q = pch ^ (row & 7);
      const u16* src = (q < 8) ? (HS + (size_t)(m0 + row)*64 + q*8)
                               : (HT + (size_t)(m0 + row)*64 + (q - 8)*8);
      gload_lds16(src, &Als[R0*128]);
    }
    #pragma unroll
    for (int i = 0; i < 4; ++i) {
      int R0 = w*16 + i*4;
      int n = R0 + rsub;
      int q = pch ^ (n & 7);
      gload_lds16(Wstt + (size_t)n*128 + q*8, &Wst[R0*128]);
    }
  }
  {
    int rsub = l >> 3, pch = l & 7;
    #pragma unroll
    for (int i = 0; i < 2; ++i) {
      int R0 = w*16 + i*8;
      int row = R0 + rsub;
      int q = pch ^ (row & 7);
      gload_lds16(Wh1t + (size_t)row*64 + q*8, &W1ls[R0*64]);
      gload_lds16(Wh2t + (size_t)row*64 + q*8, &W2ls[R0*64]);
    }
  }
  __syncthreads();

  int lr = l & 15, lk = l >> 4;
  f32x4 acc1[2][4] = {};
  #pragma unroll
  for (int ks = 0; ks < 4; ++ks) {
    short8v av[2], bvv[4];
    #pragma unroll
    for (int fm = 0; fm < 2; ++fm) {
      int r = w*32 + fm*16 + lr;
      int ch = (ks*4 + lk) ^ (r & 7);
      av[fm] = *(const short8v*)&Als[r*128 + ch*8];
    }
    #pragma unroll
    for (int fn = 0; fn < 4; ++fn) {
      int n = fn*16 + lr;
      int ch = (ks*4 + lk) ^ (n & 7);
      bvv[fn] = *(const short8v*)&Wst[n*128 + ch*8];
    }
    #pragma unroll
    for (int fm = 0; fm < 2; ++fm)
      #pragma unroll
      for (int fn = 0; fn < 4; ++fn)
        acc1[fm][fn] = __builtin_amdgcn_mfma_f32_16x16x32_bf16(av[fm], bvv[fn], acc1[fm][fn], 0, 0, 0);
  }
  #pragma unroll
  for (int fm = 0; fm < 2; ++fm) {
    #pragma unroll
    for (int fn = 0; fn < 4; ++fn) {
      int col = fn*16 + lr;
      float bb = btb[col];
      #pragma unroll
      for (int j = 0; j < 4; ++j) {
        int row = w*32 + fm*16 + lk*4 + j;
        float a_s = acc1[fm][fn][j] + bb;
        float zg = 1.f/(1.f + __expf(-a_s));
        int cs = (col >> 3) ^ (row & 7);
        float hs = b2f(Als[row*128 + cs*8 + (col & 7)]);
        float ht = b2f(Als[row*128 + (cs + 8)*8 + (col & 7)]);
        float H = zg*hs + (1.f - zg)*ht;
        Hls[row*64 + cs*8 + (col & 7)] = f2b(H);
      }
    }
  }
  __syncthreads();

  u16* H2ls = Wst;
  f32x4 acc2[2][4] = {};
  #pragma unroll
  for (int ks = 0; ks < 2; ++ks) {
    short8v av[2], bvv[4];
    #pragma unroll
    for (int fm = 0; fm < 2; ++fm) {
      int r = w*32 + fm*16 + lr;
      int ch = (ks*4 + lk) ^ (r & 7);
      av[fm] = *(const short8v*)&Hls[r*64 + ch*8];
    }
    #pragma unroll
    for (int fn = 0; fn < 4; ++fn) {
      int n = fn*16 + lr;
      int ch = (ks*4 + lk) ^ (n & 7);
      bvv[fn] = *(const short8v*)&W1ls[n*64 + ch*8];
    }
    #pragma unroll
    for (int fm = 0; fm < 2; ++fm)
      #pragma unroll
      for (int fn = 0; fn < 4; ++fn)
        acc2[fm][fn] = __builtin_amdgcn_mfma_f32_16x16x32_bf16(av[fm], bvv[fn], acc2[fm][fn], 0, 0, 0);
  }
  __syncthreads();
  #pragma unroll
  for (int fm = 0; fm < 2; ++fm) {
    #pragma unroll
    for (int fn = 0; fn < 4; ++fn) {
      int col = fn*16 + lr;
      float bias = bh1[col];
      #pragma unroll
      for (int j = 0; j < 4; ++j) {
        int row = w*32 + fm*16 + lk*4 + j;
        float val = acc2[fm][fn][j] + bias;
        int cs = (col >> 3) ^ (row & 7);
        H2ls[row*64 + cs*8 + (col & 7)] = f2b(fmaxf(val, 0.f));
      }
    }
  }
  __syncthreads();

  f32x4 acc3[2][4] = {};
  #pragma unroll
  for (int ks = 0; ks < 2; ++ks) {
    short8v av[2], bvv[4];
    #pragma unroll
    for (int fm = 0; fm < 2; ++fm) {
      int r = w*32 + fm*16 + lr;
      int ch = (ks*4 + lk) ^ (r & 7);
      av[fm] = *(const short8v*)&H2ls[r*64 + ch*8];
    }
    #pragma unroll
    for (int fn = 0; fn < 4; ++fn) {
      int n = fn*16 + lr;
      int ch = (ks*4 + lk) ^ (n & 7);
      bvv[fn] = *(const short8v*)&W2ls[n*64 + ch*8];
    }
    #pragma unroll
    for (int fm = 0; fm < 2; ++fm)
      #pragma unroll
      for (int fn = 0; fn < 4; ++fn)
        acc3[fm][fn] = __builtin_amdgcn_mfma_f32_16x16x32_bf16(av[fm], bvv[fn], acc3[fm][fn], 0, 0, 0);
  }
  #pragma unroll
  for (int fm = 0; fm < 2; ++fm) {
    #pragma unroll
    for (int fn = 0; fn < 4; ++fn) {
      int col = fn*16 + lr;
      float bias = bh2[col];
      #pragma unroll
      for (int j = 0; j < 4; ++j) {
        int row = w*32 + fm*16 + lk*4 + j;
        size_t gi = (size_t)(m0 + row)*64 + col;
        out[gi] = X[gi] + acc3[fm][fn][j] + bias;
      }
    }
  }
}

extern "C" void kernel_launch(void* const* d_in, const int* in_sizes, int n_in,
                              void* d_out, int out_size, void* d_ws, size_t ws_size,
                              hipStream_t stream) {
  const float* X    = (const float*)d_in[0];
  const float* STE  = (const float*)d_in[1];
  const float* adj  = (const float*)d_in[2];
  const float* feat0= (const float*)d_in[3];
  const float* feat1= (const float*)d_in[4];
  const float* Wq0  = (const float*)d_in[5];
  const float* Wk0  = (const float*)d_in[6];
  const float* Wq1  = (const float*)d_in[7];
  const float* Wk1  = (const float*)d_in[8];
  const float* Wgcn = (const float*)d_in[9];
  const float* bgcn = (const float*)d_in[10];
  const float* Wq   = (const float*)d_in[11];
  const float* bq   = (const float*)d_in[12];
  const float* Wk   = (const float*)d_in[13];
  const float* bk   = (const float*)d_in[14];
  const float* Wv   = (const float*)d_in[15];
  const float* bv   = (const float*)d_in[16];
  const float* Wx1  = (const float*)d_in[17];
  const float* bx1  = (const float*)d_in[18];
  const float* Wx2  = (const float*)d_in[19];
  const float* bx2  = (const float*)d_in[20];
  const float* Ws   = (const float*)d_in[21];
  const float* Wt   = (const float*)d_in[22];
  const float* btb  = (const float*)d_in[23];
  const float* Wh1  = (const float*)d_in[24];
  const float* bh1  = (const float*)d_in[25];
  const float* Wh2  = (const float*)d_in[26];
  const float* bh2  = (const float*)d_in[27];
  (void)in_sizes; (void)n_in; (void)out_size;

  // ws layout: see R5 comment (unchanged)
  const size_t NEEDED = 164626432ull;
  if (ws_size < NEEDED) return;

  char* w = (char*)d_ws;
  float* fe    = (float*)(w);
  u16*   Acat  = (u16*)(w + 1048576);
  u16*   Wqkvt = (u16*)(w + 7340032);
  u16*   W1t   = (u16*)(w + 7389184);
  u16*   W2t   = (u16*)(w + 7397376);
  u16*   Wstt  = (u16*)(w + 7405568);
  u16*   Wh1t  = (u16*)(w + 7421952);
  u16*   Wh2t  = (u16*)(w + 7430144);
  u16*   Wgcnt = (u16*)(w + 7438336);
  u16*   Yt2   = (u16*)(w + 13631488);
  u16*   Yt3   = (u16*)(w + 63963136);
  u16*   HSb   = (u16*)(w + 114294784);
  u16*   Yt1   = (u16*)d_out;
  u16*   qb    = Yt2;
  u16*   kbuf  = Yt3;
  u16*   vbuf  = (u16*)d_out;
  u16*   obuf  = (u16*)d_out + (size_t)NROWS_*64;
  u16*   HTb   = Yt2;

  k_fe<<<dim3(N_, 4), 64, 0, stream>>>(feat0, feat1, Wq0, Wk0, Wq1, Wk1, fe);
  k_adjcopy<<<N_, 256, 0, stream>>>(adj, Acat);
  k_prep<<<64, 256, 0, stream>>>(Wq, Wk, Wv, Wx1, Wx2, Ws, Wt, Wh1, Wh2, Wgcn,
                                 Wqkvt, W1t, W2t, Wstt, Wh1t, Wh2t, Wgcnt);
  k_graph_softmax<<<dim3(N_, 2), 256, 0, stream>>>(fe, Acat);
  k_xw_mfma<<<NROWS_/128, 256, 0, stream>>>(X, Wgcnt, HSb, Yt1, Yt2, Yt3);
  k_spatial_mfma<<<dim3(8, BT_/2), 256, 0, stream>>>(Acat, Yt1, Yt2, Yt3, bgcn, HSb);
  k_qkv<<<NROWS_/128, 256, 0, stream>>>(X, STE, Wqkvt, bq, bk, bv, qb, kbuf, vbuf);
  k_attn_lite<<<(B_*N_)/4, 256, 0, stream>>>(qb, kbuf, vbuf, obuf);
  k_ht<<<NROWS_/128, 256, 0, stream>>>(obuf, W1t, W2t, bx1, bx2, HTb);
  k_fusion_mfma<<<NROWS_/128, 256, 0, stream>>>(X, HSb, HTb, Wstt, Wh1t, Wh2t,
                                                btb, bh1, bh2, (float*)d_out);
}